// Round 2
// baseline (314.598 us; speedup 1.0000x reference)
//
#include <hip/hip_runtime.h>
#include <stdint.h>

// Problem constants (fixed by the harness)
#define NB 8
#define NN 8192
#define NE 128
#define NH 8
#define NHD 16
#define NKH 32
#define NFF 128
#define NG 32
#define NM 1024          // NG*NG
#define NP 32
#define NT 8192          // NB*NM
#define NPTS 65536       // NB*NN

typedef __attribute__((ext_vector_type(8))) short bf16x8_t;
typedef __attribute__((ext_vector_type(4))) float f32x4_t;

// ---- workspace layout (bytes) ----
// total ~37.2 MB
#define WS_MM      0         // 4 x u32 ordered-encoded min/max (min0,min1,max0,max1)
#define WS_D0      64        // 8 f32: grid-token dots (q.kg/4 + kb0)
#define WS_Q       128       // 128 f32
#define WS_VG      640       // 128 f32
#define WS_CNT     2048      // 8192 i32
#define WS_CELL    34816     // 65536 i32
#define WS_PIDX    296960    // 8192*32 i32
#define WS_WKVT    1345536   // 256*128 ushort (bf16), [n][k], n<128 = Wk cols, else Wv
#define WS_WOT     1411072   // 128*128 ushort
#define WS_FW1T    1443840   // 128*128 ushort
#define WS_FW2T    1476608   // 128*128 ushort
#define WS_OUTA    1509376   // 8192*128 ushort (attention out, bf16 row-major)
#define WS_KV      3606528   // 65536*256 ushort ([point][0:128]=k,[128:256]=v)

__device__ __forceinline__ unsigned f2u_ord(float f) {
    unsigned u = __float_as_uint(f);
    return u ^ (unsigned)(((int)u >> 31) | 0x80000000);
}
__device__ __forceinline__ float u2f_ord(unsigned u) {
    unsigned b = (u & 0x80000000u) ? (u ^ 0x80000000u) : ~u;
    return __uint_as_float(b);
}
__device__ __forceinline__ unsigned short f2bf(float f) {  // RNE
    unsigned u = __float_as_uint(f);
    u += 0x7FFFu + ((u >> 16) & 1u);
    return (unsigned short)(u >> 16);
}
__device__ __forceinline__ float bf2f(unsigned short h) {
    return __uint_as_float(((unsigned)h) << 16);
}

// ---------------- K0: init ----------------
__global__ __launch_bounds__(256) void k_init(int* cnt, unsigned* mm) {
    int i = blockIdx.x * 256 + threadIdx.x;
    if (i < NT) cnt[i] = 0;
    if (i < 2) mm[i] = 0xFFFFFFFFu;
    else if (i < 4) mm[i] = 0u;
}

// ---------------- K1: exact global min/max of x per dim ----------------
__global__ __launch_bounds__(256) void k_minmax(const float* __restrict__ x, unsigned* mm) {
    float mn0 = 1e30f, mx0 = -1e30f, mn1 = 1e30f, mx1 = -1e30f;
    int i = blockIdx.x * 256 + threadIdx.x;   // 65536 threads, one point each
    float a = x[i * 2], b = x[i * 2 + 1];
    mn0 = a; mx0 = a; mn1 = b; mx1 = b;
    for (int m = 32; m > 0; m >>= 1) {
        mn0 = fminf(mn0, __shfl_xor(mn0, m));
        mx0 = fmaxf(mx0, __shfl_xor(mx0, m));
        mn1 = fminf(mn1, __shfl_xor(mn1, m));
        mx1 = fmaxf(mx1, __shfl_xor(mx1, m));
    }
    if ((threadIdx.x & 63) == 0) {
        atomicMin(&mm[0], f2u_ord(mn0));
        atomicMin(&mm[1], f2u_ord(mn1));
        atomicMax(&mm[2], f2u_ord(mx0));
        atomicMax(&mm[3], f2u_ord(mx1));
    }
}

// ---------------- K2: cell assignment + unordered binning ----------------
__global__ __launch_bounds__(256) void k_bin(const float* __restrict__ x,
        const unsigned* __restrict__ mm, int* __restrict__ cell,
        int* __restrict__ cnt, int* __restrict__ ptIdx) {
    int i = blockIdx.x * 256 + threadIdx.x;  // 65536
    float mn0 = u2f_ord(mm[0]), mn1 = u2f_ord(mm[1]);
    float mx0 = u2f_ord(mm[2]), mx1 = u2f_ord(mm[3]);
    float st0 = (mx0 - mn0) / 31.0f, st1 = (mx1 - mn1) / 31.0f;  // matches jnp exactly
    float a = x[i * 2], b = x[i * 2 + 1];
    int i0 = (int)rintf((a - mn0) / st0); i0 = min(max(i0, 0), 31);
    int i1 = (int)rintf((b - mn1) / st1); i1 = min(max(i1, 0), 31);
    int c = i0 * 32 + i1;
    cell[i] = c;
    int bb = i >> 13;
    int slot = atomicAdd(&cnt[bb * NM + c], 1);
    if (slot < NP) ptIdx[(bb * NM + c) * NP + slot] = i & (NN - 1);
}

// ---------------- K3: overflow fixup (keep first 32 by index) ----------------
__global__ __launch_bounds__(256) void k_fixup(const int* __restrict__ cell,
        int* __restrict__ cnt, int* __restrict__ ptIdx) {
    int wid = (blockIdx.x * 256 + threadIdx.x) >> 6;   // one wave per (b,cell)
    int lane = threadIdx.x & 63;
    int c0 = cnt[wid];
    if (c0 <= NP) return;      // almost always
    int b = wid >> 10, mycell = wid & 1023;
    const int* cb = cell + b * NN;
    int run = 0;
    for (int ch = 0; ch < NN / 64 && run < NP; ++ch) {
        int n = ch * 64 + lane;
        bool match = (cb[n] == mycell);
        unsigned long long mask = __ballot(match);
        if (match) {
            int rank = run + __popcll(mask & ((1ull << lane) - 1ull));
            if (rank < NP) ptIdx[wid * NP + rank] = n;
        }
        run += __popcll(mask);
    }
    if (lane == 0) cnt[wid] = NP;
}

// ---------------- K4: pack transposed bf16 weights ----------------
__global__ __launch_bounds__(256) void k_pack(const float* __restrict__ Wk,
        const float* __restrict__ Wv, const float* __restrict__ Wo,
        const float* __restrict__ fW1, const float* __restrict__ fW2,
        unsigned short* __restrict__ WkvT, unsigned short* __restrict__ WoT,
        unsigned short* __restrict__ fW1T, unsigned short* __restrict__ fW2T) {
    int idx = blockIdx.x * 256 + threadIdx.x;   // 81920
    if (idx < 32768) {
        int n = idx >> 7, k = idx & 127;
        float v = (n < 128) ? Wk[k * 128 + n] : Wv[k * 128 + (n - 128)];
        WkvT[idx] = f2bf(v);
    } else if (idx < 49152) {
        int j = idx - 32768; int n = j >> 7, k = j & 127;
        WoT[j] = f2bf(Wo[k * 128 + n]);
    } else if (idx < 65536) {
        int j = idx - 49152; int n = j >> 7, k = j & 127;
        fW1T[j] = f2bf(fW1[k * 128 + n]);
    } else if (idx < 81920) {
        int j = idx - 65536; int n = j >> 7, k = j & 127;
        fW2T[j] = f2bf(fW2[k * 128 + n]);
    }
}

// ---------------- K5: shared precompute (q, kg, vg, dots0) ----------------
__global__ __launch_bounds__(128) void k_small(const float* __restrict__ latent,
        const float* __restrict__ Wq, const float* __restrict__ Wk, const float* __restrict__ Wv,
        const float* __restrict__ lnq_g, const float* __restrict__ lnq_b,
        const float* __restrict__ lnk_g, const float* __restrict__ lnk_b,
        const float* __restrict__ kb1, const float* __restrict__ kW2, const float* __restrict__ kb2,
        float* __restrict__ ws_q, float* __restrict__ ws_vg, float* __restrict__ ws_d0) {
    __shared__ float s_qn[128], s_kn[128], s_q[128], s_kg[128];
    __shared__ float s_mu, s_rstd;
    int t = threadIdx.x;
    if (t < 64) {
        float v0 = latent[t], v1 = latent[t + 64];
        float s = v0 + v1;
        for (int m = 32; m > 0; m >>= 1) s += __shfl_xor(s, m);
        float mu = s * (1.0f / 128.0f);
        float d0 = v0 - mu, d1 = v1 - mu;
        float q = d0 * d0 + d1 * d1;
        for (int m = 32; m > 0; m >>= 1) q += __shfl_xor(q, m);
        if (t == 0) { s_mu = mu; s_rstd = rsqrtf(q * (1.0f / 128.0f) + 1e-5f); }
    }
    __syncthreads();
    float nv = (latent[t] - s_mu) * s_rstd;
    s_qn[t] = nv * lnq_g[t] + lnq_b[t];
    s_kn[t] = nv * lnk_g[t] + lnk_b[t];
    __syncthreads();
    float aq = 0.f, ak = 0.f, av = 0.f;
    for (int e = 0; e < 128; ++e) {
        aq += s_qn[e] * Wq[e * 128 + t];
        ak += s_kn[e] * Wk[e * 128 + t];
        av += s_kn[e] * Wv[e * 128 + t];
    }
    s_q[t] = aq; s_kg[t] = ak;
    ws_q[t] = aq; ws_vg[t] = av;
    __syncthreads();
    if (t < 8) {
        float acc = 0.f;
        for (int d = 0; d < 16; ++d) acc += s_q[t * 16 + d] * s_kg[t * 16 + d];
        float kb0 = kb2[t];
        for (int j = 0; j < 32; ++j) kb0 += fmaxf(kb1[j], 0.f) * kW2[j * 8 + t];
        ws_d0[t] = acc * 0.25f + kb0;
    }
}

// ---------------- K6: LN(z) + K/V projection via MFMA ----------------
__global__ __launch_bounds__(256) void k_kv(const float* __restrict__ z,
        const float* __restrict__ lnk_g, const float* __restrict__ lnk_b,
        const unsigned short* __restrict__ WkvT, unsigned short* __restrict__ kv) {
    __shared__ unsigned short s_zn[64][136];   // +8 pad breaks 256B-stride conflicts
    __shared__ unsigned short s_out[64][256];
    __shared__ float s_g[128], s_b[128];
    int t = threadIdx.x;
    if (t < 128) { s_g[t] = lnk_g[t]; s_b[t] = lnk_b[t]; }
    __syncthreads();
    int w = t >> 6, lane = t & 63;
    long base = (long)blockIdx.x * 64;
    for (int i = 0; i < 16; ++i) {
        int pl = w * 16 + i;
        long g = base + pl;
        float v0 = z[g * 128 + lane];
        float v1 = z[g * 128 + 64 + lane];
        float s = v0 + v1;
        for (int m = 32; m > 0; m >>= 1) s += __shfl_xor(s, m);
        float mu = s * (1.0f / 128.0f);
        float d0 = v0 - mu, d1 = v1 - mu;
        float q = d0 * d0 + d1 * d1;
        for (int m = 32; m > 0; m >>= 1) q += __shfl_xor(q, m);
        float rstd = rsqrtf(q * (1.0f / 128.0f) + 1e-5f);
        s_zn[pl][lane]      = f2bf(d0 * rstd * s_g[lane] + s_b[lane]);
        s_zn[pl][lane + 64] = f2bf(d1 * rstd * s_g[lane + 64] + s_b[lane + 64]);
    }
    __syncthreads();
    // wave w computes rows w*16..w*16+15 over all 256 output features, K=128
    int mrow = lane & 15, quad = lane >> 4;
    bf16x8_t a[4];
    for (int kc = 0; kc < 4; ++kc)
        a[kc] = *(const bf16x8_t*)&s_zn[w * 16 + mrow][kc * 32 + quad * 8];
    for (int ct = 0; ct < 16; ++ct) {
        f32x4_t acc = {0.f, 0.f, 0.f, 0.f};
        const unsigned short* bp = WkvT + (ct * 16 + mrow) * 128 + quad * 8;
        for (int kc = 0; kc < 4; ++kc) {
            bf16x8_t bb = *(const bf16x8_t*)(bp + kc * 32);
            acc = __builtin_amdgcn_mfma_f32_16x16x32_bf16(a[kc], bb, acc, 0, 0, 0);
        }
        for (int r = 0; r < 4; ++r)
            s_out[w * 16 + quad * 4 + r][ct * 16 + mrow] = f2bf(acc[r]);
    }
    __syncthreads();
    const uint4* src4 = (const uint4*)&s_out[0][0];
    uint4* dst4 = (uint4*)((uint32_t*)kv + base * 128);
    for (int i = t; i < 2048; i += 256) dst4[i] = src4[i];   // FIX: 64 rows * 256 ushort = 2048 uint4 (was 1024 — half of kv stayed poisoned)
}

// ---------------- K7: per-cell attention ----------------
__global__ __launch_bounds__(256) void k_attn(const float* __restrict__ x,
        const int* __restrict__ cnt, const int* __restrict__ ptIdx,
        const unsigned* __restrict__ mm, const unsigned short* __restrict__ kv,
        const float* __restrict__ ws_q, const float* __restrict__ ws_vg,
        const float* __restrict__ ws_d0,
        const float* __restrict__ kW1, const float* __restrict__ kb1,
        const float* __restrict__ kW2, const float* __restrict__ kb2,
        unsigned short* __restrict__ outA, float* __restrict__ xout) {
    __shared__ unsigned short s_k[33][128], s_v[33][128];
    __shared__ float s_kb[33][8], s_jx[33][2], s_A[8 * 33], s_Am[33];
    __shared__ float s_q[128], s_vg[128], s_xg[2];
    __shared__ int s_idx[32], s_cnt;
    int t = threadIdx.x;
    int bm = blockIdx.x;
    int b = bm >> 10;
    if (t == 0) {
        float mn0 = u2f_ord(mm[0]), mn1 = u2f_ord(mm[1]);
        float mx0 = u2f_ord(mm[2]), mx1 = u2f_ord(mm[3]);
        int i0 = (bm & 1023) >> 5, i1 = bm & 31;
        float st0 = (mx0 - mn0) / 31.0f, st1 = (mx1 - mn1) / 31.0f;
        s_xg[0] = (i0 == 31) ? mx0 : mn0 + i0 * st0;
        s_xg[1] = (i1 == 31) ? mx1 : mn1 + i1 * st1;
        s_cnt = min(cnt[bm], NP);
    }
    if (t < 128) { s_q[t] = ws_q[t]; s_vg[t] = ws_vg[t]; }
    if (t < 8) s_A[t * 33] = ws_d0[t];
    __syncthreads();
    int c = s_cnt;
    if (t < c) s_idx[t] = ptIdx[bm * NP + t];
    __syncthreads();
    if (t == 0) { s_jx[0][0] = s_xg[0]; s_jx[0][1] = s_xg[1]; }
    if (t < c) {
        int n = s_idx[t];
        long pi = (long)(b * NN + n);
        float x0 = x[pi * 2], x1 = x[pi * 2 + 1];
        s_jx[t + 1][0] = x0; s_jx[t + 1][1] = x1;
        // kernel-bias MLP: relu(diff@kW1+kb1)@kW2+kb2
        float d0 = x0 - s_xg[0], d1 = x1 - s_xg[1];
        float acch[8];
        for (int h = 0; h < 8; ++h) acch[h] = kb2[h];
        for (int j = 0; j < 32; ++j) {
            float hj = d0 * kW1[j] + d1 * kW1[32 + j] + kb1[j];
            if (hj > 0.f)
                for (int h = 0; h < 8; ++h) acch[h] += hj * kW2[j * 8 + h];
        }
        for (int h = 0; h < 8; ++h) s_kb[t + 1][h] = acch[h];
    }
    for (int lin = t; lin < c * 128; lin += 256) {   // gather kv rows
        int key = lin >> 7, u = lin & 127;
        unsigned val = ((const unsigned*)kv)[(long)(b * NN + s_idx[key]) * 128 + u];
        if (u < 64) ((unsigned*)&s_k[key + 1][0])[u] = val;
        else        ((unsigned*)&s_v[key + 1][0])[u - 64] = val;
    }
    __syncthreads();
    for (int task = t; task < c * 8; task += 256) {
        int key = (task >> 3) + 1, h = task & 7;
        float acc = 0.f;
        int fb = h * 16;
        for (int d = 0; d < 16; ++d) acc += s_q[fb + d] * bf2f(s_k[key][fb + d]);
        s_A[h * 33 + key] = acc * 0.25f + s_kb[key][h];
    }
    __syncthreads();
    if (t < 8) {                         // softmax over keys 0..c
        float mx = s_A[t * 33];
        for (int key = 1; key <= c; ++key) mx = fmaxf(mx, s_A[t * 33 + key]);
        float sum = 0.f;
        for (int key = 0; key <= c; ++key) {
            float e = __expf(s_A[t * 33 + key] - mx);
            s_A[t * 33 + key] = e; sum += e;
        }
        float inv = 1.0f / sum;
        for (int key = 0; key <= c; ++key) s_A[t * 33 + key] *= inv;
    }
    __syncthreads();
    if (t <= c) {
        float s = 0.f;
        for (int h = 0; h < 8; ++h) s += s_A[h * 33 + t];
        s_Am[t] = s * 0.125f;
    }
    __syncthreads();
    if (t < 128) {                       // out = A @ v
        int h = t >> 4;
        float acc = s_A[h * 33] * s_vg[t];
        for (int key = 1; key <= c; ++key) acc += s_A[h * 33 + key] * bf2f(s_v[key][t]);
        outA[(long)bm * 128 + t] = f2bf(acc);
    }
    if (t < 2) {                         // x_new = mean_h(A) @ joint_x
        float acc = 0.f;
        for (int key = 0; key <= c; ++key) acc += s_Am[key] * s_jx[key][t];
        xout[bm * 2 + t] = acc;
    }
}

// ---------------- K8: z_new = zq + out@Wo + bo; + FFN(LN2) ----------------
__global__ __launch_bounds__(256) void k_ffn(const unsigned short* __restrict__ outA,
        const float* __restrict__ latent, const float* __restrict__ bo,
        const float* __restrict__ ln2_g, const float* __restrict__ ln2_b,
        const float* __restrict__ fb1, const float* __restrict__ fb2,
        const unsigned short* __restrict__ WoT, const unsigned short* __restrict__ fW1T,
        const unsigned short* __restrict__ fW2T, float* __restrict__ zout) {
    __shared__ unsigned short s_a[32][136];
    __shared__ unsigned short s_a2[32][136];
    __shared__ float s_z[32][128];
    __shared__ float s_lat[128], s_g2[128], s_b2[128], s_fb1v[128], s_fb2v[128];
    int t = threadIdx.x;
    long base = (long)blockIdx.x * 32;
    if (t < 128) {
        s_lat[t] = latent[t] + bo[t];
        s_g2[t] = ln2_g[t]; s_b2[t] = ln2_b[t];
        s_fb1v[t] = fb1[t]; s_fb2v[t] = fb2[t];
    }
    {
        const uint4* src4 = (const uint4*)((const uint32_t*)outA + base * 64);
        for (int i = t; i < 512; i += 256) {
            int row = i >> 4, off = (i & 15) * 8;
            *(uint4*)&s_a[row][off] = src4[i];
        }
    }
    __syncthreads();
    int w = t >> 6, lane = t & 63;
    int mrow = lane & 15, quad = lane >> 4;
    int rt = w >> 1;
    int ct0 = (w & 1) * 4;
    { // GEMM1: out @ Wo  (+ latent + bo)
        bf16x8_t a[4];
        for (int kc = 0; kc < 4; ++kc)
            a[kc] = *(const bf16x8_t*)&s_a[rt * 16 + mrow][kc * 32 + quad * 8];
        for (int cc = 0; cc < 4; ++cc) {
            int ct = ct0 + cc;
            f32x4_t acc = {0.f, 0.f, 0.f, 0.f};
            const unsigned short* bp = WoT + (ct * 16 + mrow) * 128 + quad * 8;
            for (int kc = 0; kc < 4; ++kc)
                acc = __builtin_amdgcn_mfma_f32_16x16x32_bf16(a[kc], *(const bf16x8_t*)(bp + kc * 32), acc, 0, 0, 0);
            for (int r = 0; r < 4; ++r) {
                int row = rt * 16 + quad * 4 + r, f = ct * 16 + mrow;
                s_z[row][f] = acc[r] + s_lat[f];
            }
        }
    }
    __syncthreads();
    for (int i = 0; i < 8; ++i) {   // LN2 per row
        int row = w * 8 + i;
        float v0 = s_z[row][lane], v1 = s_z[row][lane + 64];
        float s = v0 + v1;
        for (int m = 32; m > 0; m >>= 1) s += __shfl_xor(s, m);
        float mu = s * (1.0f / 128.0f);
        float d0 = v0 - mu, d1 = v1 - mu;
        float q = d0 * d0 + d1 * d1;
        for (int m = 32; m > 0; m >>= 1) q += __shfl_xor(q, m);
        float rstd = rsqrtf(q * (1.0f / 128.0f) + 1e-5f);
        s_a2[row][lane]      = f2bf(d0 * rstd * s_g2[lane] + s_b2[lane]);
        s_a2[row][lane + 64] = f2bf(d1 * rstd * s_g2[lane + 64] + s_b2[lane + 64]);
    }
    __syncthreads();
    { // GEMM2: relu(LN2 @ fW1 + fb1) -> s_a (reuse)
        bf16x8_t a[4];
        for (int kc = 0; kc < 4; ++kc)
            a[kc] = *(const bf16x8_t*)&s_a2[rt * 16 + mrow][kc * 32 + quad * 8];
        for (int cc = 0; cc < 4; ++cc) {
            int ct = ct0 + cc;
            f32x4_t acc = {0.f, 0.f, 0.f, 0.f};
            const unsigned short* bp = fW1T + (ct * 16 + mrow) * 128 + quad * 8;
            for (int kc = 0; kc < 4; ++kc)
                acc = __builtin_amdgcn_mfma_f32_16x16x32_bf16(a[kc], *(const bf16x8_t*)(bp + kc * 32), acc, 0, 0, 0);
            for (int r = 0; r < 4; ++r) {
                int row = rt * 16 + quad * 4 + r, f = ct * 16 + mrow;
                s_a[row][f] = f2bf(fmaxf(acc[r] + s_fb1v[f], 0.f));
            }
        }
    }
    __syncthreads();
    { // GEMM3: z + h1 @ fW2 + fb2 -> d_out
        bf16x8_t a[4];
        for (int kc = 0; kc < 4; ++kc)
            a[kc] = *(const bf16x8_t*)&s_a[rt * 16 + mrow][kc * 32 + quad * 8];
        for (int cc = 0; cc < 4; ++cc) {
            int ct = ct0 + cc;
            f32x4_t acc = {0.f, 0.f, 0.f, 0.f};
            const unsigned short* bp = fW2T + (ct * 16 + mrow) * 128 + quad * 8;
            for (int kc = 0; kc < 4; ++kc)
                acc = __builtin_amdgcn_mfma_f32_16x16x32_bf16(a[kc], *(const bf16x8_t*)(bp + kc * 32), acc, 0, 0, 0);
            for (int r = 0; r < 4; ++r) {
                int row = rt * 16 + quad * 4 + r, f = ct * 16 + mrow;
                zout[(base + row) * 128 + f] = s_z[row][f] + acc[r] + s_fb2v[f];
            }
        }
    }
}

extern "C" void kernel_launch(void* const* d_in, const int* in_sizes, int n_in,
                              void* d_out, int out_size, void* d_ws, size_t ws_size,
                              hipStream_t stream) {
    const float* x     = (const float*)d_in[0];
    const float* z     = (const float*)d_in[1];
    const float* latent= (const float*)d_in[6];
    const float* Wq    = (const float*)d_in[7];
    const float* Wk    = (const float*)d_in[8];
    const float* Wv    = (const float*)d_in[9];
    const float* Wo    = (const float*)d_in[10];
    const float* bo    = (const float*)d_in[11];
    const float* kW1   = (const float*)d_in[12];
    const float* kb1   = (const float*)d_in[13];
    const float* kW2   = (const float*)d_in[14];
    const float* kb2   = (const float*)d_in[15];
    const float* lnq_g = (const float*)d_in[16];
    const float* lnq_b = (const float*)d_in[17];
    const float* lnk_g = (const float*)d_in[18];
    const float* lnk_b = (const float*)d_in[19];
    const float* ln2_g = (const float*)d_in[20];
    const float* ln2_b = (const float*)d_in[21];
    const float* fW1   = (const float*)d_in[22];
    const float* fb1   = (const float*)d_in[23];
    const float* fW2   = (const float*)d_in[24];
    const float* fb2   = (const float*)d_in[25];

    uint8_t* ws = (uint8_t*)d_ws;
    unsigned* mm  = (unsigned*)(ws + WS_MM);
    float* ws_d0  = (float*)(ws + WS_D0);
    float* ws_q   = (float*)(ws + WS_Q);
    float* ws_vg  = (float*)(ws + WS_VG);
    int* cnt      = (int*)(ws + WS_CNT);
    int* cell     = (int*)(ws + WS_CELL);
    int* ptIdx    = (int*)(ws + WS_PIDX);
    unsigned short* WkvT = (unsigned short*)(ws + WS_WKVT);
    unsigned short* WoT  = (unsigned short*)(ws + WS_WOT);
    unsigned short* fW1T = (unsigned short*)(ws + WS_FW1T);
    unsigned short* fW2T = (unsigned short*)(ws + WS_FW2T);
    unsigned short* outA = (unsigned short*)(ws + WS_OUTA);
    unsigned short* kv   = (unsigned short*)(ws + WS_KV);

    float* xout = (float*)d_out;            // [B,32,32,2]  = 16384
    float* zout = (float*)d_out + 16384;    // [B,32,32,128]

    k_init  <<<32,   256, 0, stream>>>(cnt, mm);
    k_minmax<<<256,  256, 0, stream>>>(x, mm);
    k_bin   <<<256,  256, 0, stream>>>(x, mm, cell, cnt, ptIdx);
    k_fixup <<<128,  256, 0, stream>>>(cell, cnt, ptIdx);
    k_pack  <<<320,  256, 0, stream>>>(Wk, Wv, Wo, fW1, fW2, WkvT, WoT, fW1T, fW2T);
    k_small <<<1,    128, 0, stream>>>(latent, Wq, Wk, Wv, lnq_g, lnq_b, lnk_g, lnk_b,
                                       kb1, kW2, kb2, ws_q, ws_vg, ws_d0);
    k_kv    <<<1024, 256, 0, stream>>>(z, lnk_g, lnk_b, WkvT, kv);
    k_attn  <<<8192, 256, 0, stream>>>(x, cnt, ptIdx, mm, kv, ws_q, ws_vg, ws_d0,
                                       kW1, kb1, kW2, kb2, outA, xout);
    k_ffn   <<<256,  256, 0, stream>>>(outA, latent, bo, ln2_g, ln2_b, fb1, fb2,
                                       WoT, fW1T, fW2T, zout);
}

// Round 3
// 267.442 us; speedup vs baseline: 1.1763x; 1.1763x over previous
//
#include <hip/hip_runtime.h>
#include <stdint.h>

// Problem constants (fixed by the harness)
#define NB 8
#define NN 8192
#define NE 128
#define NH 8
#define NHD 16
#define NKH 32
#define NFF 128
#define NG 32
#define NM 1024          // NG*NG
#define NP 32
#define NT 8192          // NB*NM
#define NPTS 65536       // NB*NN

typedef __attribute__((ext_vector_type(8))) short bf16x8_t;
typedef __attribute__((ext_vector_type(4))) float f32x4_t;

// ---- workspace layout (bytes) ----
#define WS_MM      0         // 4 x u32 ordered-encoded min/max (min0,min1,max0,max1)
#define WS_D0      64        // 8 f32: grid-token dots (q.kg/4 + kb0)
#define WS_Q       128       // 128 f32
#define WS_VG      640       // 128 f32
#define WS_CNT     2048      // 8192 i32
#define WS_CELL    34816     // 65536 i32
#define WS_PIDX    296960    // 8192*32 i32
#define WS_WKVT    1345536   // 256*128 ushort (bf16), [n][k], n<128 = Wk cols, else Wv
#define WS_WOT     1411072   // 128*128 ushort
#define WS_FW1T    1443840   // 128*128 ushort
#define WS_FW2T    1476608   // 128*128 ushort
#define WS_OUTA    1509376   // 8192*128 ushort (attention out, bf16 row-major)
#define WS_KV      3606528   // 65536*256 ushort ([point][0:128]=k,[128:256]=v)

__device__ __forceinline__ unsigned f2u_ord(float f) {
    unsigned u = __float_as_uint(f);
    return u ^ (unsigned)(((int)u >> 31) | 0x80000000);
}
__device__ __forceinline__ float u2f_ord(unsigned u) {
    unsigned b = (u & 0x80000000u) ? (u ^ 0x80000000u) : ~u;
    return __uint_as_float(b);
}
__device__ __forceinline__ unsigned short f2bf(float f) {  // RNE
    unsigned u = __float_as_uint(f);
    u += 0x7FFFu + ((u >> 16) & 1u);
    return (unsigned short)(u >> 16);
}
__device__ __forceinline__ float bf2f(unsigned short h) {
    return __uint_as_float(((unsigned)h) << 16);
}
__device__ __forceinline__ float bflo(unsigned w) { return __uint_as_float(w << 16); }
__device__ __forceinline__ float bfhi(unsigned w) { return __uint_as_float(w & 0xFFFF0000u); }

// ---------------- K1: exact global min/max of x per dim ----------------
__global__ __launch_bounds__(256) void k_minmax(const float* __restrict__ x, unsigned* mm) {
    int i = blockIdx.x * 256 + threadIdx.x;   // 65536 threads, one point each
    float a = x[i * 2], b = x[i * 2 + 1];
    float mn0 = a, mx0 = a, mn1 = b, mx1 = b;
    for (int m = 32; m > 0; m >>= 1) {
        mn0 = fminf(mn0, __shfl_xor(mn0, m));
        mx0 = fmaxf(mx0, __shfl_xor(mx0, m));
        mn1 = fminf(mn1, __shfl_xor(mn1, m));
        mx1 = fmaxf(mx1, __shfl_xor(mx1, m));
    }
    if ((threadIdx.x & 63) == 0) {
        atomicMin(&mm[0], f2u_ord(mn0));
        atomicMin(&mm[1], f2u_ord(mn1));
        atomicMax(&mm[2], f2u_ord(mx0));
        atomicMax(&mm[3], f2u_ord(mx1));
    }
}

// ---------------- K2: cell assignment + unordered binning ----------------
__global__ __launch_bounds__(256) void k_bin(const float* __restrict__ x,
        const unsigned* __restrict__ mm, int* __restrict__ cell,
        int* __restrict__ cnt, int* __restrict__ ptIdx) {
    int i = blockIdx.x * 256 + threadIdx.x;  // 65536
    float mn0 = u2f_ord(mm[0]), mn1 = u2f_ord(mm[1]);
    float mx0 = u2f_ord(mm[2]), mx1 = u2f_ord(mm[3]);
    float st0 = (mx0 - mn0) / 31.0f, st1 = (mx1 - mn1) / 31.0f;  // matches jnp exactly
    float a = x[i * 2], b = x[i * 2 + 1];
    int i0 = (int)rintf((a - mn0) / st0); i0 = min(max(i0, 0), 31);
    int i1 = (int)rintf((b - mn1) / st1); i1 = min(max(i1, 0), 31);
    int c = i0 * 32 + i1;
    cell[i] = c;
    int bb = i >> 13;
    int slot = atomicAdd(&cnt[bb * NM + c], 1);
    if (slot < NP) ptIdx[(bb * NM + c) * NP + slot] = i & (NN - 1);
}

// ---------------- K3: overflow fixup (keep first 32 by index) ----------------
__global__ __launch_bounds__(256) void k_fixup(const int* __restrict__ cell,
        int* __restrict__ cnt, int* __restrict__ ptIdx) {
    int wid = (blockIdx.x * 256 + threadIdx.x) >> 6;   // one wave per (b,cell)
    int lane = threadIdx.x & 63;
    int c0 = cnt[wid];
    if (c0 <= NP) return;      // almost always
    int b = wid >> 10, mycell = wid & 1023;
    const int* cb = cell + b * NN;
    int run = 0;
    for (int ch = 0; ch < NN / 64 && run < NP; ++ch) {
        int n = ch * 64 + lane;
        bool match = (cb[n] == mycell);
        unsigned long long mask = __ballot(match);
        if (match) {
            int rank = run + __popcll(mask & ((1ull << lane) - 1ull));
            if (rank < NP) ptIdx[wid * NP + rank] = n;
        }
        run += __popcll(mask);
    }
    if (lane == 0) cnt[wid] = NP;
}

// ---------------- K_setup: init + weight pack + shared precompute (merged) ----------------
__global__ __launch_bounds__(256) void k_setup(
        const float* __restrict__ Wk, const float* __restrict__ Wv, const float* __restrict__ Wo,
        const float* __restrict__ fW1, const float* __restrict__ fW2,
        const float* __restrict__ latent, const float* __restrict__ Wq,
        const float* __restrict__ lnq_g, const float* __restrict__ lnq_b,
        const float* __restrict__ lnk_g, const float* __restrict__ lnk_b,
        const float* __restrict__ kb1, const float* __restrict__ kW2, const float* __restrict__ kb2,
        int* __restrict__ cnt, unsigned* __restrict__ mm,
        unsigned short* __restrict__ WkvT, unsigned short* __restrict__ WoT,
        unsigned short* __restrict__ fW1T, unsigned short* __restrict__ fW2T,
        float* __restrict__ ws_q, float* __restrict__ ws_vg, float* __restrict__ ws_d0) {
    int blk = blockIdx.x;
    int t = threadIdx.x;
    if (blk < 320) {
        int idx = blk * 256 + t;   // 81920
        if (idx < NT) cnt[idx] = 0;
        if (idx < 2) mm[idx] = 0xFFFFFFFFu;
        else if (idx < 4) mm[idx] = 0u;
        if (idx < 32768) {
            int n = idx >> 7, k = idx & 127;
            float v = (n < 128) ? Wk[k * 128 + n] : Wv[k * 128 + (n - 128)];
            WkvT[idx] = f2bf(v);
        } else if (idx < 49152) {
            int j = idx - 32768; int n = j >> 7, k = j & 127;
            WoT[j] = f2bf(Wo[k * 128 + n]);
        } else if (idx < 65536) {
            int j = idx - 49152; int n = j >> 7, k = j & 127;
            fW1T[j] = f2bf(fW1[k * 128 + n]);
        } else {
            int j = idx - 65536; int n = j >> 7, k = j & 127;
            fW2T[j] = f2bf(fW2[k * 128 + n]);
        }
    } else {
        // shared precompute: q, kg, vg, dots0 (one block, first 128 threads)
        __shared__ float s_qn[128], s_kn[128], s_q[128], s_kg[128];
        __shared__ float s_mu, s_rstd;
        if (t < 64) {
            float v0 = latent[t], v1 = latent[t + 64];
            float s = v0 + v1;
            for (int m = 32; m > 0; m >>= 1) s += __shfl_xor(s, m);
            float mu = s * (1.0f / 128.0f);
            float d0 = v0 - mu, d1 = v1 - mu;
            float q = d0 * d0 + d1 * d1;
            for (int m = 32; m > 0; m >>= 1) q += __shfl_xor(q, m);
            if (t == 0) { s_mu = mu; s_rstd = rsqrtf(q * (1.0f / 128.0f) + 1e-5f); }
        }
        __syncthreads();
        if (t < 128) {
            float nv = (latent[t] - s_mu) * s_rstd;
            s_qn[t] = nv * lnq_g[t] + lnq_b[t];
            s_kn[t] = nv * lnk_g[t] + lnk_b[t];
        }
        __syncthreads();
        if (t < 128) {
            float aq = 0.f, ak = 0.f, av = 0.f;
            for (int e = 0; e < 128; ++e) {
                aq += s_qn[e] * Wq[e * 128 + t];
                ak += s_kn[e] * Wk[e * 128 + t];
                av += s_kn[e] * Wv[e * 128 + t];
            }
            s_q[t] = aq; s_kg[t] = ak;
            ws_q[t] = aq; ws_vg[t] = av;
        }
        __syncthreads();
        if (t < 8) {
            float acc = 0.f;
            for (int d = 0; d < 16; ++d) acc += s_q[t * 16 + d] * s_kg[t * 16 + d];
            float kb0 = kb2[t];
            for (int j = 0; j < 32; ++j) kb0 += fmaxf(kb1[j], 0.f) * kW2[j * 8 + t];
            ws_d0[t] = acc * 0.25f + kb0;
        }
    }
}

// ---------------- K6: LN(z) + K/V projection via MFMA ----------------
__global__ __launch_bounds__(256) void k_kv(const float* __restrict__ z,
        const float* __restrict__ lnk_g, const float* __restrict__ lnk_b,
        const unsigned short* __restrict__ WkvT, unsigned short* __restrict__ kv) {
    __shared__ unsigned short s_zn[64][136];   // +8 pad breaks 256B-stride conflicts
    __shared__ unsigned short s_out[64][256];
    __shared__ float s_g[128], s_b[128];
    int t = threadIdx.x;
    if (t < 128) { s_g[t] = lnk_g[t]; s_b[t] = lnk_b[t]; }
    __syncthreads();
    int w = t >> 6, lane = t & 63;
    long base = (long)blockIdx.x * 64;
    for (int i = 0; i < 16; ++i) {
        int pl = w * 16 + i;
        long g = base + pl;
        float v0 = z[g * 128 + lane];
        float v1 = z[g * 128 + 64 + lane];
        float s = v0 + v1;
        for (int m = 32; m > 0; m >>= 1) s += __shfl_xor(s, m);
        float mu = s * (1.0f / 128.0f);
        float d0 = v0 - mu, d1 = v1 - mu;
        float q = d0 * d0 + d1 * d1;
        for (int m = 32; m > 0; m >>= 1) q += __shfl_xor(q, m);
        float rstd = rsqrtf(q * (1.0f / 128.0f) + 1e-5f);
        s_zn[pl][lane]      = f2bf(d0 * rstd * s_g[lane] + s_b[lane]);
        s_zn[pl][lane + 64] = f2bf(d1 * rstd * s_g[lane + 64] + s_b[lane + 64]);
    }
    __syncthreads();
    // wave w computes rows w*16..w*16+15 over all 256 output features, K=128
    int mrow = lane & 15, quad = lane >> 4;
    bf16x8_t a[4];
    for (int kc = 0; kc < 4; ++kc)
        a[kc] = *(const bf16x8_t*)&s_zn[w * 16 + mrow][kc * 32 + quad * 8];
    for (int ct = 0; ct < 16; ++ct) {
        f32x4_t acc = {0.f, 0.f, 0.f, 0.f};
        const unsigned short* bp = WkvT + (ct * 16 + mrow) * 128 + quad * 8;
        for (int kc = 0; kc < 4; ++kc) {
            bf16x8_t bb = *(const bf16x8_t*)(bp + kc * 32);
            acc = __builtin_amdgcn_mfma_f32_16x16x32_bf16(a[kc], bb, acc, 0, 0, 0);
        }
        for (int r = 0; r < 4; ++r)
            s_out[w * 16 + quad * 4 + r][ct * 16 + mrow] = f2bf(acc[r]);
    }
    __syncthreads();
    const uint4* src4 = (const uint4*)&s_out[0][0];
    uint4* dst4 = (uint4*)((uint32_t*)kv + base * 128);
    for (int i = t; i < 2048; i += 256) dst4[i] = src4[i];   // 64 rows * 256 ushort = 2048 uint4
}

// ---------------- K7: per-cell attention — wave-per-token, no LDS, no barriers ----------------
// Lane layout: lane l -> head h=l>>3, sub j'=l&7, features f=2l,2l+1 (h*16+2j' == 2l).
__global__ __launch_bounds__(256) void k_attn(const float* __restrict__ x,
        const int* __restrict__ cnt, const int* __restrict__ ptIdx,
        const unsigned* __restrict__ mm, const unsigned short* __restrict__ kv,
        const float* __restrict__ ws_q, const float* __restrict__ ws_vg,
        const float* __restrict__ ws_d0,
        const float* __restrict__ kW1, const float* __restrict__ kb1,
        const float* __restrict__ kW2, const float* __restrict__ kb2,
        unsigned short* __restrict__ outA, float* __restrict__ xout) {
    int t = threadIdx.x;
    int l = t & 63;
    int bm = blockIdx.x * 4 + (t >> 6);   // one wave per (b,cell) token
    int b = bm >> 10;
    int h = l >> 3, jp = l & 7;

    float mn0 = u2f_ord(mm[0]), mn1 = u2f_ord(mm[1]);
    float mx0 = u2f_ord(mm[2]), mx1 = u2f_ord(mm[3]);
    int i0 = (bm & 1023) >> 5, i1 = bm & 31;
    float st0 = (mx0 - mn0) / 31.0f, st1 = (mx1 - mn1) / 31.0f;
    float xg0 = (i0 == 31) ? mx0 : mn0 + i0 * st0;
    float xg1 = (i1 == 31) ? mx1 : mn1 + i1 * st1;
    int c = min(cnt[bm], NP);

    // per-lane constants
    float q0 = ws_q[2 * l] * 0.25f, q1 = ws_q[2 * l + 1] * 0.25f;  // fold 1/sqrt(hd)
    float vg0 = ws_vg[2 * l], vg1 = ws_vg[2 * l + 1];
    float ag = ws_d0[h];          // grid-token score (already scaled + kb)
    float kb2h = kb2[h];
    float w1a[4], w1b[4], b1v[4], w2v[4];
    #pragma unroll
    for (int m = 0; m < 4; ++m) {
        int j = jp + 8 * m;
        w1a[m] = kW1[j]; w1b[m] = kW1[32 + j]; b1v[m] = kb1[j]; w2v[m] = kW2[j * 8 + h];
    }

    // per-key lane-resident data (lane k holds key k's idx and coords)
    int idxreg = 0; float x0r = 0.f, x1r = 0.f;
    if (l < c) {
        idxreg = ptIdx[bm * NP + l];
        float2 xv = ((const float2*)x)[(size_t)b * NN + idxreg];
        x0r = xv.x; x1r = xv.y;
    }

    unsigned vreg[NP];
    float areg[4];
    #pragma unroll
    for (int k = 0; k < NP; ++k) vreg[k] = 0u;
    areg[0] = areg[1] = areg[2] = areg[3] = -1e30f;

    #pragma unroll
    for (int key = 0; key < NP; ++key) {
        if (key < c) {                       // wave-uniform branch
            int idxk = __shfl(idxreg, key);
            const unsigned* rowp = (const unsigned*)kv + ((size_t)(b * NN + idxk) << 7);
            unsigned kw = rowp[l];           // k features 2l,2l+1  (coalesced 256B)
            vreg[key] = rowp[64 + l];        // v features 2l,2l+1
            float d0 = __shfl(x0r, key) - xg0;
            float d1 = __shfl(x1r, key) - xg1;
            float part = q0 * bflo(kw) + q1 * bfhi(kw);
            #pragma unroll
            for (int m = 0; m < 4; ++m) {    // kernel-bias MLP partial (j = jp+8m)
                float hj = fmaf(d0, w1a[m], fmaf(d1, w1b[m], b1v[m]));
                hj = fmaxf(hj, 0.f);
                part = fmaf(hj, w2v[m], part);
            }
            part += __shfl_xor(part, 1);
            part += __shfl_xor(part, 2);
            part += __shfl_xor(part, 4);     // sum over j' -> full dot + kb
            float score = part + kb2h;
            if (jp == (key & 7)) areg[key >> 3] = score;
        }
    }

    // softmax over {grid, keys} per head (within 8-lane group)
    float mx = fmaxf(fmaxf(areg[0], areg[1]), fmaxf(areg[2], areg[3]));
    mx = fmaxf(mx, ag);
    mx = fmaxf(mx, __shfl_xor(mx, 1));
    mx = fmaxf(mx, __shfl_xor(mx, 2));
    mx = fmaxf(mx, __shfl_xor(mx, 4));
    float e0 = __expf(areg[0] - mx), e1 = __expf(areg[1] - mx);
    float e2 = __expf(areg[2] - mx), e3 = __expf(areg[3] - mx);
    float eg = __expf(ag - mx);
    float s = e0 + e1 + e2 + e3;
    s += __shfl_xor(s, 1);
    s += __shfl_xor(s, 2);
    s += __shfl_xor(s, 4);
    s += eg;                                  // eg uniform within group
    float inv = 1.0f / s;

    // out = A @ v   (lane owns features 2l,2l+1 of head h)
    float accA = eg * inv * vg0, accB = eg * inv * vg1;
    #pragma unroll
    for (int key = 0; key < NP; ++key) {
        if (key < c) {
            int src = (l & 56) | (key & 7);
            float em = (key >> 3) == 0 ? e0 : (key >> 3) == 1 ? e1 : (key >> 3) == 2 ? e2 : e3;
            float a = __shfl(em, src) * inv;
            unsigned vw = vreg[key];
            accA = fmaf(a, bflo(vw), accA);
            accB = fmaf(a, bfhi(vw), accB);
        }
    }
    unsigned ow = ((unsigned)f2bf(accB) << 16) | (unsigned)f2bf(accA);
    ((unsigned*)outA)[(size_t)bm * 64 + l] = ow;

    // x_new = mean_h(A) @ joint_x
    float s0 = e0 * inv, s1 = e1 * inv, s2 = e2 * inv, s3 = e3 * inv, sg = eg * inv;
    #pragma unroll
    for (int m = 8; m <= 32; m <<= 1) {       // reduce over heads
        s0 += __shfl_xor(s0, m); s1 += __shfl_xor(s1, m);
        s2 += __shfl_xor(s2, m); s3 += __shfl_xor(s3, m);
        sg += __shfl_xor(sg, m);
    }
    float px0 = 0.f, px1 = 0.f;
    {
        float xx0, xx1;
        xx0 = __shfl(x0r, jp);      xx1 = __shfl(x1r, jp);
        px0 = fmaf(s0, xx0, px0);   px1 = fmaf(s0, xx1, px1);
        xx0 = __shfl(x0r, jp + 8);  xx1 = __shfl(x1r, jp + 8);
        px0 = fmaf(s1, xx0, px0);   px1 = fmaf(s1, xx1, px1);
        xx0 = __shfl(x0r, jp + 16); xx1 = __shfl(x1r, jp + 16);
        px0 = fmaf(s2, xx0, px0);   px1 = fmaf(s2, xx1, px1);
        xx0 = __shfl(x0r, jp + 24); xx1 = __shfl(x1r, jp + 24);
        px0 = fmaf(s3, xx0, px0);   px1 = fmaf(s3, xx1, px1);
    }
    px0 += __shfl_xor(px0, 1); px1 += __shfl_xor(px1, 1);
    px0 += __shfl_xor(px0, 2); px1 += __shfl_xor(px1, 2);
    px0 += __shfl_xor(px0, 4); px1 += __shfl_xor(px1, 4);
    if (l == 0) {
        xout[bm * 2]     = (px0 + sg * xg0) * 0.125f;
        xout[bm * 2 + 1] = (px1 + sg * xg1) * 0.125f;
    }
}

// ---------------- K8: z_new = zq + out@Wo + bo; + FFN(LN2) ----------------
__global__ __launch_bounds__(256) void k_ffn(const unsigned short* __restrict__ outA,
        const float* __restrict__ latent, const float* __restrict__ bo,
        const float* __restrict__ ln2_g, const float* __restrict__ ln2_b,
        const float* __restrict__ fb1, const float* __restrict__ fb2,
        const unsigned short* __restrict__ WoT, const unsigned short* __restrict__ fW1T,
        const unsigned short* __restrict__ fW2T, float* __restrict__ zout) {
    __shared__ unsigned short s_a[32][136];
    __shared__ unsigned short s_a2[32][136];
    __shared__ float s_z[32][128];
    __shared__ float s_lat[128], s_g2[128], s_b2[128], s_fb1v[128], s_fb2v[128];
    int t = threadIdx.x;
    long base = (long)blockIdx.x * 32;
    if (t < 128) {
        s_lat[t] = latent[t] + bo[t];
        s_g2[t] = ln2_g[t]; s_b2[t] = ln2_b[t];
        s_fb1v[t] = fb1[t]; s_fb2v[t] = fb2[t];
    }
    {
        const uint4* src4 = (const uint4*)((const uint32_t*)outA + base * 64);
        for (int i = t; i < 512; i += 256) {
            int row = i >> 4, off = (i & 15) * 8;
            *(uint4*)&s_a[row][off] = src4[i];
        }
    }
    __syncthreads();
    int w = t >> 6, lane = t & 63;
    int mrow = lane & 15, quad = lane >> 4;
    int rt = w >> 1;
    int ct0 = (w & 1) * 4;
    { // GEMM1: out @ Wo  (+ latent + bo)
        bf16x8_t a[4];
        for (int kc = 0; kc < 4; ++kc)
            a[kc] = *(const bf16x8_t*)&s_a[rt * 16 + mrow][kc * 32 + quad * 8];
        for (int cc = 0; cc < 4; ++cc) {
            int ct = ct0 + cc;
            f32x4_t acc = {0.f, 0.f, 0.f, 0.f};
            const unsigned short* bp = WoT + (ct * 16 + mrow) * 128 + quad * 8;
            for (int kc = 0; kc < 4; ++kc)
                acc = __builtin_amdgcn_mfma_f32_16x16x32_bf16(a[kc], *(const bf16x8_t*)(bp + kc * 32), acc, 0, 0, 0);
            for (int r = 0; r < 4; ++r) {
                int row = rt * 16 + quad * 4 + r, f = ct * 16 + mrow;
                s_z[row][f] = acc[r] + s_lat[f];
            }
        }
    }
    __syncthreads();
    for (int i = 0; i < 8; ++i) {   // LN2 per row
        int row = w * 8 + i;
        float v0 = s_z[row][lane], v1 = s_z[row][lane + 64];
        float s = v0 + v1;
        for (int m = 32; m > 0; m >>= 1) s += __shfl_xor(s, m);
        float mu = s * (1.0f / 128.0f);
        float d0 = v0 - mu, d1 = v1 - mu;
        float q = d0 * d0 + d1 * d1;
        for (int m = 32; m > 0; m >>= 1) q += __shfl_xor(q, m);
        float rstd = rsqrtf(q * (1.0f / 128.0f) + 1e-5f);
        s_a2[row][lane]      = f2bf(d0 * rstd * s_g2[lane] + s_b2[lane]);
        s_a2[row][lane + 64] = f2bf(d1 * rstd * s_g2[lane + 64] + s_b2[lane + 64]);
    }
    __syncthreads();
    { // GEMM2: relu(LN2 @ fW1 + fb1) -> s_a (reuse)
        bf16x8_t a[4];
        for (int kc = 0; kc < 4; ++kc)
            a[kc] = *(const bf16x8_t*)&s_a2[rt * 16 + mrow][kc * 32 + quad * 8];
        for (int cc = 0; cc < 4; ++cc) {
            int ct = ct0 + cc;
            f32x4_t acc = {0.f, 0.f, 0.f, 0.f};
            const unsigned short* bp = fW1T + (ct * 16 + mrow) * 128 + quad * 8;
            for (int kc = 0; kc < 4; ++kc)
                acc = __builtin_amdgcn_mfma_f32_16x16x32_bf16(a[kc], *(const bf16x8_t*)(bp + kc * 32), acc, 0, 0, 0);
            for (int r = 0; r < 4; ++r) {
                int row = rt * 16 + quad * 4 + r, f = ct * 16 + mrow;
                s_a[row][f] = f2bf(fmaxf(acc[r] + s_fb1v[f], 0.f));
            }
        }
    }
    __syncthreads();
    { // GEMM3: z + h1 @ fW2 + fb2 -> d_out
        bf16x8_t a[4];
        for (int kc = 0; kc < 4; ++kc)
            a[kc] = *(const bf16x8_t*)&s_a[rt * 16 + mrow][kc * 32 + quad * 8];
        for (int cc = 0; cc < 4; ++cc) {
            int ct = ct0 + cc;
            f32x4_t acc = {0.f, 0.f, 0.f, 0.f};
            const unsigned short* bp = fW2T + (ct * 16 + mrow) * 128 + quad * 8;
            for (int kc = 0; kc < 4; ++kc)
                acc = __builtin_amdgcn_mfma_f32_16x16x32_bf16(a[kc], *(const bf16x8_t*)(bp + kc * 32), acc, 0, 0, 0);
            for (int r = 0; r < 4; ++r) {
                int row = rt * 16 + quad * 4 + r, f = ct * 16 + mrow;
                zout[(base + row) * 128 + f] = s_z[row][f] + acc[r] + s_fb2v[f];
            }
        }
    }
}

extern "C" void kernel_launch(void* const* d_in, const int* in_sizes, int n_in,
                              void* d_out, int out_size, void* d_ws, size_t ws_size,
                              hipStream_t stream) {
    const float* x     = (const float*)d_in[0];
    const float* z     = (const float*)d_in[1];
    const float* latent= (const float*)d_in[6];
    const float* Wq    = (const float*)d_in[7];
    const float* Wk    = (const float*)d_in[8];
    const float* Wv    = (const float*)d_in[9];
    const float* Wo    = (const float*)d_in[10];
    const float* bo    = (const float*)d_in[11];
    const float* kW1   = (const float*)d_in[12];
    const float* kb1   = (const float*)d_in[13];
    const float* kW2   = (const float*)d_in[14];
    const float* kb2   = (const float*)d_in[15];
    const float* lnq_g = (const float*)d_in[16];
    const float* lnq_b = (const float*)d_in[17];
    const float* lnk_g = (const float*)d_in[18];
    const float* lnk_b = (const float*)d_in[19];
    const float* ln2_g = (const float*)d_in[20];
    const float* ln2_b = (const float*)d_in[21];
    const float* fW1   = (const float*)d_in[22];
    const float* fb1   = (const float*)d_in[23];
    const float* fW2   = (const float*)d_in[24];
    const float* fb2   = (const float*)d_in[25];

    uint8_t* ws = (uint8_t*)d_ws;
    unsigned* mm  = (unsigned*)(ws + WS_MM);
    float* ws_d0  = (float*)(ws + WS_D0);
    float* ws_q   = (float*)(ws + WS_Q);
    float* ws_vg  = (float*)(ws + WS_VG);
    int* cnt      = (int*)(ws + WS_CNT);
    int* cell     = (int*)(ws + WS_CELL);
    int* ptIdx    = (int*)(ws + WS_PIDX);
    unsigned short* WkvT = (unsigned short*)(ws + WS_WKVT);
    unsigned short* WoT  = (unsigned short*)(ws + WS_WOT);
    unsigned short* fW1T = (unsigned short*)(ws + WS_FW1T);
    unsigned short* fW2T = (unsigned short*)(ws + WS_FW2T);
    unsigned short* outA = (unsigned short*)(ws + WS_OUTA);
    unsigned short* kv   = (unsigned short*)(ws + WS_KV);

    float* xout = (float*)d_out;            // [B,32,32,2]  = 16384
    float* zout = (float*)d_out + 16384;    // [B,32,32,128]

    k_setup <<<321,  256, 0, stream>>>(Wk, Wv, Wo, fW1, fW2, latent, Wq,
                                       lnq_g, lnq_b, lnk_g, lnk_b, kb1, kW2, kb2,
                                       cnt, mm, WkvT, WoT, fW1T, fW2T, ws_q, ws_vg, ws_d0);
    k_minmax<<<256,  256, 0, stream>>>(x, mm);
    k_bin   <<<256,  256, 0, stream>>>(x, mm, cell, cnt, ptIdx);
    k_fixup <<<128,  256, 0, stream>>>(cell, cnt, ptIdx);
    k_kv    <<<1024, 256, 0, stream>>>(z, lnk_g, lnk_b, WkvT, kv);
    k_attn  <<<2048, 256, 0, stream>>>(x, cnt, ptIdx, mm, kv, ws_q, ws_vg, ws_d0,
                                       kW1, kb1, kW2, kb2, outA, xout);
    k_ffn   <<<256,  256, 0, stream>>>(outA, latent, bo, ln2_g, ln2_b, fb1, fb2,
                                       WoT, fW1T, fW2T, zout);
}

// Round 4
// 253.874 us; speedup vs baseline: 1.2392x; 1.0534x over previous
//
#include <hip/hip_runtime.h>
#include <stdint.h>

// Problem constants (fixed by the harness)
#define NB 8
#define NN 8192
#define NE 128
#define NH 8
#define NHD 16
#define NKH 32
#define NFF 128
#define NG 32
#define NM 1024          // NG*NG
#define NP 32
#define NT 8192          // NB*NM
#define NPTS 65536       // NB*NN

typedef __attribute__((ext_vector_type(8))) short bf16x8_t;
typedef __attribute__((ext_vector_type(4))) float f32x4_t;

// ---- workspace layout (bytes) ----
#define WS_MM      0         // 4 x u32 ordered-encoded min/max (min0,min1,max0,max1)
#define WS_D0      64        // 8 f32: grid-token dots (q.kg/4 + kb0)
#define WS_Q       128       // 128 f32
#define WS_VG      640       // 128 f32
#define WS_CNT     2048      // 8192 i32
#define WS_CELL    34816     // 65536 i32
#define WS_PIDX    296960    // 8192*32 i32
#define WS_WKVT    1345536   // 256*128 ushort (bf16), [n][k], n<128 = Wk cols, else Wv
#define WS_WOT     1411072   // 128*128 ushort
#define WS_FW1T    1443840   // 128*128 ushort
#define WS_FW2T    1476608   // 128*128 ushort
#define WS_OUTA    1509376   // 8192*128 ushort (attention out, bf16 row-major)
#define WS_KV      3606528   // 65536*256 ushort ([point][0:128]=k,[128:256]=v)

__device__ __forceinline__ unsigned f2u_ord(float f) {
    unsigned u = __float_as_uint(f);
    return u ^ (unsigned)(((int)u >> 31) | 0x80000000);
}
__device__ __forceinline__ float u2f_ord(unsigned u) {
    unsigned b = (u & 0x80000000u) ? (u ^ 0x80000000u) : ~u;
    return __uint_as_float(b);
}
__device__ __forceinline__ unsigned short f2bf(float f) {  // RNE
    unsigned u = __float_as_uint(f);
    u += 0x7FFFu + ((u >> 16) & 1u);
    return (unsigned short)(u >> 16);
}
__device__ __forceinline__ float bf2f(unsigned short h) {
    return __uint_as_float(((unsigned)h) << 16);
}
__device__ __forceinline__ float bflo(unsigned w) { return __uint_as_float(w << 16); }
__device__ __forceinline__ float bfhi(unsigned w) { return __uint_as_float(w & 0xFFFF0000u); }

// ---------------- K1: exact global min/max of x per dim ----------------
__global__ __launch_bounds__(256) void k_minmax(const float* __restrict__ x, unsigned* mm) {
    int i = blockIdx.x * 256 + threadIdx.x;   // 65536 threads, one point each
    float a = x[i * 2], b = x[i * 2 + 1];
    float mn0 = a, mx0 = a, mn1 = b, mx1 = b;
    for (int m = 32; m > 0; m >>= 1) {
        mn0 = fminf(mn0, __shfl_xor(mn0, m));
        mx0 = fmaxf(mx0, __shfl_xor(mx0, m));
        mn1 = fminf(mn1, __shfl_xor(mn1, m));
        mx1 = fmaxf(mx1, __shfl_xor(mx1, m));
    }
    if ((threadIdx.x & 63) == 0) {
        atomicMin(&mm[0], f2u_ord(mn0));
        atomicMin(&mm[1], f2u_ord(mn1));
        atomicMax(&mm[2], f2u_ord(mx0));
        atomicMax(&mm[3], f2u_ord(mx1));
    }
}

// ---------------- K2: cell assignment + unordered binning ----------------
__global__ __launch_bounds__(256) void k_bin(const float* __restrict__ x,
        const unsigned* __restrict__ mm, int* __restrict__ cell,
        int* __restrict__ cnt, int* __restrict__ ptIdx) {
    int i = blockIdx.x * 256 + threadIdx.x;  // 65536
    float mn0 = u2f_ord(mm[0]), mn1 = u2f_ord(mm[1]);
    float mx0 = u2f_ord(mm[2]), mx1 = u2f_ord(mm[3]);
    float st0 = (mx0 - mn0) / 31.0f, st1 = (mx1 - mn1) / 31.0f;  // matches jnp exactly
    float a = x[i * 2], b = x[i * 2 + 1];
    int i0 = (int)rintf((a - mn0) / st0); i0 = min(max(i0, 0), 31);
    int i1 = (int)rintf((b - mn1) / st1); i1 = min(max(i1, 0), 31);
    int c = i0 * 32 + i1;
    cell[i] = c;
    int bb = i >> 13;
    int slot = atomicAdd(&cnt[bb * NM + c], 1);
    if (slot < NP) ptIdx[(bb * NM + c) * NP + slot] = i & (NN - 1);
}

// ---------------- K_setup: init + weight pack + shared precompute (merged) ----------------
__global__ __launch_bounds__(256) void k_setup(
        const float* __restrict__ Wk, const float* __restrict__ Wv, const float* __restrict__ Wo,
        const float* __restrict__ fW1, const float* __restrict__ fW2,
        const float* __restrict__ latent, const float* __restrict__ Wq,
        const float* __restrict__ lnq_g, const float* __restrict__ lnq_b,
        const float* __restrict__ lnk_g, const float* __restrict__ lnk_b,
        const float* __restrict__ kb1, const float* __restrict__ kW2, const float* __restrict__ kb2,
        int* __restrict__ cnt, unsigned* __restrict__ mm,
        unsigned short* __restrict__ WkvT, unsigned short* __restrict__ WoT,
        unsigned short* __restrict__ fW1T, unsigned short* __restrict__ fW2T,
        float* __restrict__ ws_q, float* __restrict__ ws_vg, float* __restrict__ ws_d0) {
    int blk = blockIdx.x;
    int t = threadIdx.x;
    if (blk < 320) {
        int idx = blk * 256 + t;   // 81920
        if (idx < NT) cnt[idx] = 0;
        if (idx < 2) mm[idx] = 0xFFFFFFFFu;
        else if (idx < 4) mm[idx] = 0u;
        if (idx < 32768) {
            int n = idx >> 7, k = idx & 127;
            float v = (n < 128) ? Wk[k * 128 + n] : Wv[k * 128 + (n - 128)];
            WkvT[idx] = f2bf(v);
        } else if (idx < 49152) {
            int j = idx - 32768; int n = j >> 7, k = j & 127;
            WoT[j] = f2bf(Wo[k * 128 + n]);
        } else if (idx < 65536) {
            int j = idx - 49152; int n = j >> 7, k = j & 127;
            fW1T[j] = f2bf(fW1[k * 128 + n]);
        } else {
            int j = idx - 65536; int n = j >> 7, k = j & 127;
            fW2T[j] = f2bf(fW2[k * 128 + n]);
        }
    } else {
        // shared precompute: q, kg, vg, dots0 (one block, first 128 threads)
        __shared__ float s_qn[128], s_kn[128], s_q[128], s_kg[128];
        __shared__ float s_mu, s_rstd;
        if (t < 64) {
            float v0 = latent[t], v1 = latent[t + 64];
            float s = v0 + v1;
            for (int m = 32; m > 0; m >>= 1) s += __shfl_xor(s, m);
            float mu = s * (1.0f / 128.0f);
            float d0 = v0 - mu, d1 = v1 - mu;
            float q = d0 * d0 + d1 * d1;
            for (int m = 32; m > 0; m >>= 1) q += __shfl_xor(q, m);
            if (t == 0) { s_mu = mu; s_rstd = rsqrtf(q * (1.0f / 128.0f) + 1e-5f); }
        }
        __syncthreads();
        if (t < 128) {
            float nv = (latent[t] - s_mu) * s_rstd;
            s_qn[t] = nv * lnq_g[t] + lnq_b[t];
            s_kn[t] = nv * lnk_g[t] + lnk_b[t];
        }
        __syncthreads();
        if (t < 128) {
            float aq = 0.f, ak = 0.f, av = 0.f;
            for (int e = 0; e < 128; ++e) {
                aq += s_qn[e] * Wq[e * 128 + t];
                ak += s_kn[e] * Wk[e * 128 + t];
                av += s_kn[e] * Wv[e * 128 + t];
            }
            s_q[t] = aq; s_kg[t] = ak;
            ws_q[t] = aq; ws_vg[t] = av;
        }
        __syncthreads();
        if (t < 8) {
            float acc = 0.f;
            for (int d = 0; d < 16; ++d) acc += s_q[t * 16 + d] * s_kg[t * 16 + d];
            float kb0 = kb2[t];
            for (int j = 0; j < 32; ++j) kb0 += fmaxf(kb1[j], 0.f) * kW2[j * 8 + t];
            ws_d0[t] = acc * 0.25f + kb0;
        }
    }
}

// ---------------- K6: LN(z) + K/V projection (transposed MFMA, direct global store)
//                    + overflow fixup merged (blocks >= 1024) ----------------
__global__ __launch_bounds__(256) void k_kvfix(const float* __restrict__ z,
        const float* __restrict__ lnk_g, const float* __restrict__ lnk_b,
        const unsigned short* __restrict__ WkvT, unsigned short* __restrict__ kv,
        const int* __restrict__ cell, int* __restrict__ cnt, int* __restrict__ ptIdx) {
    int t = threadIdx.x;
    if (blockIdx.x >= 1024) {
        // ---- fixup path: 128 blocks * 4 waves, each wave scans 16 (b,cell) slots ----
        int wave = (blockIdx.x - 1024) * 4 + (t >> 6);   // 0..511
        int lane = t & 63;
        int wbase = wave * 16;
        int cval = (lane < 16) ? cnt[wbase + lane] : 0;
        unsigned long long ovf = __ballot(cval > NP);
        while (ovf) {
            int s = __ffsll((long long)ovf) - 1;
            ovf &= ovf - 1;
            int wid = wbase + s;
            int b = wid >> 10, mycell = wid & 1023;
            const int* cb = cell + b * NN;
            int run = 0;
            for (int ch = 0; ch < NN / 64 && run < NP; ++ch) {
                int n = ch * 64 + lane;
                bool match = (cb[n] == mycell);
                unsigned long long mask = __ballot(match);
                if (match) {
                    int rank = run + __popcll(mask & ((1ull << lane) - 1ull));
                    if (rank < NP) ptIdx[wid * NP + rank] = n;
                }
                run += __popcll(mask);
            }
            if (lane == 0) cnt[wid] = NP;
        }
        return;
    }
    // ---- kv path: 64 tokens per block, 16 per wave, no barriers ----
    __shared__ unsigned short s_zn[64][136];
    int w = t >> 6, lane = t & 63;
    long base = (long)blockIdx.x * 64;
    // LN: 2 rows per iteration, 32 lanes per row, float4 per lane
    int sub = lane >> 5;         // which of the 2 rows
    int lq = lane & 31;          // lane within row; features lq*4..lq*4+3
    float4 g4 = ((const float4*)lnk_g)[lq];
    float4 b4 = ((const float4*)lnk_b)[lq];
    #pragma unroll
    for (int i = 0; i < 8; ++i) {
        int pl = w * 16 + i * 2 + sub;
        float4 v = ((const float4*)z)[(base + pl) * 32 + lq];
        float sum = v.x + v.y + v.z + v.w;
        float ssq = v.x * v.x + v.y * v.y + v.z * v.z + v.w * v.w;
        #pragma unroll
        for (int m = 1; m < 32; m <<= 1) {
            sum += __shfl_xor(sum, m);
            ssq += __shfl_xor(ssq, m);
        }
        float mu = sum * (1.0f / 128.0f);
        float var = fmaxf(ssq * (1.0f / 128.0f) - mu * mu, 0.0f);
        float rstd = rsqrtf(var + 1e-5f);
        float n0 = (v.x - mu) * rstd * g4.x + b4.x;
        float n1 = (v.y - mu) * rstd * g4.y + b4.y;
        float n2 = (v.z - mu) * rstd * g4.z + b4.z;
        float n3 = (v.w - mu) * rstd * g4.w + b4.w;
        unsigned d0 = (unsigned)f2bf(n0) | ((unsigned)f2bf(n1) << 16);
        unsigned d1 = (unsigned)f2bf(n2) | ((unsigned)f2bf(n3) << 16);
        *(uint2*)&s_zn[pl][lq * 4] = make_uint2(d0, d1);
    }
    // MFMA: A = WkvT (features = m), B = zn tokens (n). Wave w owns tokens w*16..+15.
    // No __syncthreads needed: wave reads exactly the LDS rows it wrote.
    int mrow = lane & 15, quad = lane >> 4;
    bf16x8_t bfrag[4];
    #pragma unroll
    for (int kc = 0; kc < 4; ++kc)
        bfrag[kc] = *(const bf16x8_t*)&s_zn[w * 16 + mrow][kc * 32 + quad * 8];
    long tk = base + w * 16 + mrow;        // token this lane's D column belongs to
    #pragma unroll
    for (int ft = 0; ft < 16; ++ft) {
        f32x4_t acc = {0.f, 0.f, 0.f, 0.f};
        const unsigned short* ap = WkvT + (ft * 16 + mrow) * 128 + quad * 8;
        #pragma unroll
        for (int kc = 0; kc < 4; ++kc) {
            bf16x8_t a = *(const bf16x8_t*)(ap + kc * 32);
            acc = __builtin_amdgcn_mfma_f32_16x16x32_bf16(a, bfrag[kc], acc, 0, 0, 0);
        }
        // lane holds features ft*16+quad*4 .. +3 of token tk (wait: D col = lane&15 = token-slot,
        // D row = quad*4+r = feature) -> but tk above used mrow... D col n = lane&15 indexes B's n-dim
        // = token w*16 + (lane&15); feature = ft*16 + quad*4 + r.
        unsigned d0 = (unsigned)f2bf(acc[0]) | ((unsigned)f2bf(acc[1]) << 16);
        unsigned d1 = (unsigned)f2bf(acc[2]) | ((unsigned)f2bf(acc[3]) << 16);
        int f0 = ft * 16 + quad * 4;
        *(uint2*)(kv + tk * 256 + f0) = make_uint2(d0, d1);
    }
}

// ---------------- K7: per-cell attention — wave-per-token, no LDS, no barriers ----------------
// Lane layout: lane l -> head h=l>>3, sub j'=l&7, features f=2l,2l+1 (h*16+2j' == 2l).
__global__ __launch_bounds__(256) void k_attn(const float* __restrict__ x,
        const int* __restrict__ cnt, const int* __restrict__ ptIdx,
        const unsigned* __restrict__ mm, const unsigned short* __restrict__ kv,
        const float* __restrict__ ws_q, const float* __restrict__ ws_vg,
        const float* __restrict__ ws_d0,
        const float* __restrict__ kW1, const float* __restrict__ kb1,
        const float* __restrict__ kW2, const float* __restrict__ kb2,
        unsigned short* __restrict__ outA, float* __restrict__ xout) {
    int t = threadIdx.x;
    int l = t & 63;
    int bm = blockIdx.x * 4 + (t >> 6);   // one wave per (b,cell) token
    int b = bm >> 10;
    int h = l >> 3, jp = l & 7;

    float mn0 = u2f_ord(mm[0]), mn1 = u2f_ord(mm[1]);
    float mx0 = u2f_ord(mm[2]), mx1 = u2f_ord(mm[3]);
    int i0 = (bm & 1023) >> 5, i1 = bm & 31;
    float st0 = (mx0 - mn0) / 31.0f, st1 = (mx1 - mn1) / 31.0f;
    float xg0 = (i0 == 31) ? mx0 : mn0 + i0 * st0;
    float xg1 = (i1 == 31) ? mx1 : mn1 + i1 * st1;
    int c = min(cnt[bm], NP);

    // per-lane constants
    float q0 = ws_q[2 * l] * 0.25f, q1 = ws_q[2 * l + 1] * 0.25f;  // fold 1/sqrt(hd)
    float vg0 = ws_vg[2 * l], vg1 = ws_vg[2 * l + 1];
    float ag = ws_d0[h];          // grid-token score (already scaled + kb)
    float kb2h = kb2[h];
    float w1a[4], w1b[4], b1v[4], w2v[4];
    #pragma unroll
    for (int m = 0; m < 4; ++m) {
        int j = jp + 8 * m;
        w1a[m] = kW1[j]; w1b[m] = kW1[32 + j]; b1v[m] = kb1[j]; w2v[m] = kW2[j * 8 + h];
    }

    // per-key lane-resident data (lane k holds key k's idx and coords)
    int idxreg = 0; float x0r = 0.f, x1r = 0.f;
    if (l < c) {
        idxreg = ptIdx[bm * NP + l];
        float2 xv = ((const float2*)x)[(size_t)b * NN + idxreg];
        x0r = xv.x; x1r = xv.y;
    }

    unsigned vreg[NP];
    float areg[4];
    #pragma unroll
    for (int k = 0; k < NP; ++k) vreg[k] = 0u;
    areg[0] = areg[1] = areg[2] = areg[3] = -1e30f;

    #pragma unroll
    for (int key = 0; key < NP; ++key) {
        if (key < c) {                       // wave-uniform branch
            int idxk = __shfl(idxreg, key);
            const unsigned* rowp = (const unsigned*)kv + ((size_t)(b * NN + idxk) << 7);
            unsigned kw = rowp[l];           // k features 2l,2l+1  (coalesced 256B)
            vreg[key] = rowp[64 + l];        // v features 2l,2l+1
            float d0 = __shfl(x0r, key) - xg0;
            float d1 = __shfl(x1r, key) - xg1;
            float part = q0 * bflo(kw) + q1 * bfhi(kw);
            #pragma unroll
            for (int m = 0; m < 4; ++m) {    // kernel-bias MLP partial (j = jp+8m)
                float hj = fmaf(d0, w1a[m], fmaf(d1, w1b[m], b1v[m]));
                hj = fmaxf(hj, 0.f);
                part = fmaf(hj, w2v[m], part);
            }
            part += __shfl_xor(part, 1);
            part += __shfl_xor(part, 2);
            part += __shfl_xor(part, 4);     // sum over j' -> full dot + kb
            float score = part + kb2h;
            if (jp == (key & 7)) areg[key >> 3] = score;
        }
    }

    // softmax over {grid, keys} per head (within 8-lane group)
    float mx = fmaxf(fmaxf(areg[0], areg[1]), fmaxf(areg[2], areg[3]));
    mx = fmaxf(mx, ag);
    mx = fmaxf(mx, __shfl_xor(mx, 1));
    mx = fmaxf(mx, __shfl_xor(mx, 2));
    mx = fmaxf(mx, __shfl_xor(mx, 4));
    float e0 = __expf(areg[0] - mx), e1 = __expf(areg[1] - mx);
    float e2 = __expf(areg[2] - mx), e3 = __expf(areg[3] - mx);
    float eg = __expf(ag - mx);
    float s = e0 + e1 + e2 + e3;
    s += __shfl_xor(s, 1);
    s += __shfl_xor(s, 2);
    s += __shfl_xor(s, 4);
    s += eg;                                  // eg uniform within group
    float inv = 1.0f / s;

    // out = A @ v   (lane owns features 2l,2l+1 of head h)
    float accA = eg * inv * vg0, accB = eg * inv * vg1;
    #pragma unroll
    for (int key = 0; key < NP; ++key) {
        if (key < c) {
            int src = (l & 56) | (key & 7);
            float em = (key >> 3) == 0 ? e0 : (key >> 3) == 1 ? e1 : (key >> 3) == 2 ? e2 : e3;
            float a = __shfl(em, src) * inv;
            unsigned vw = vreg[key];
            accA = fmaf(a, bflo(vw), accA);
            accB = fmaf(a, bfhi(vw), accB);
        }
    }
    unsigned ow = ((unsigned)f2bf(accB) << 16) | (unsigned)f2bf(accA);
    ((unsigned*)outA)[(size_t)bm * 64 + l] = ow;

    // x_new = mean_h(A) @ joint_x
    float s0 = e0 * inv, s1 = e1 * inv, s2 = e2 * inv, s3 = e3 * inv, sg = eg * inv;
    #pragma unroll
    for (int m = 8; m <= 32; m <<= 1) {       // reduce over heads
        s0 += __shfl_xor(s0, m); s1 += __shfl_xor(s1, m);
        s2 += __shfl_xor(s2, m); s3 += __shfl_xor(s3, m);
        sg += __shfl_xor(sg, m);
    }
    float px0 = 0.f, px1 = 0.f;
    {
        float xx0, xx1;
        xx0 = __shfl(x0r, jp);      xx1 = __shfl(x1r, jp);
        px0 = fmaf(s0, xx0, px0);   px1 = fmaf(s0, xx1, px1);
        xx0 = __shfl(x0r, jp + 8);  xx1 = __shfl(x1r, jp + 8);
        px0 = fmaf(s1, xx0, px0);   px1 = fmaf(s1, xx1, px1);
        xx0 = __shfl(x0r, jp + 16); xx1 = __shfl(x1r, jp + 16);
        px0 = fmaf(s2, xx0, px0);   px1 = fmaf(s2, xx1, px1);
        xx0 = __shfl(x0r, jp + 24); xx1 = __shfl(x1r, jp + 24);
        px0 = fmaf(s3, xx0, px0);   px1 = fmaf(s3, xx1, px1);
    }
    px0 += __shfl_xor(px0, 1); px1 += __shfl_xor(px1, 1);
    px0 += __shfl_xor(px0, 2); px1 += __shfl_xor(px1, 2);
    px0 += __shfl_xor(px0, 4); px1 += __shfl_xor(px1, 4);
    if (l == 0) {
        xout[bm * 2]     = (px0 + sg * xg0) * 0.125f;
        xout[bm * 2 + 1] = (px1 + sg * xg1) * 0.125f;
    }
}

// ---------------- K8: z_new = zq + out@Wo + bo; + FFN(LN2) ----------------
__global__ __launch_bounds__(256) void k_ffn(const unsigned short* __restrict__ outA,
        const float* __restrict__ latent, const float* __restrict__ bo,
        const float* __restrict__ ln2_g, const float* __restrict__ ln2_b,
        const float* __restrict__ fb1, const float* __restrict__ fb2,
        const unsigned short* __restrict__ WoT, const unsigned short* __restrict__ fW1T,
        const unsigned short* __restrict__ fW2T, float* __restrict__ zout) {
    __shared__ unsigned short s_a[32][136];
    __shared__ unsigned short s_a2[32][136];
    __shared__ float s_z[32][128];
    __shared__ float s_lat[128], s_g2[128], s_b2[128], s_fb1v[128], s_fb2v[128];
    int t = threadIdx.x;
    long base = (long)blockIdx.x * 32;
    if (t < 128) {
        s_lat[t] = latent[t] + bo[t];
        s_g2[t] = ln2_g[t]; s_b2[t] = ln2_b[t];
        s_fb1v[t] = fb1[t]; s_fb2v[t] = fb2[t];
    }
    {
        const uint4* src4 = (const uint4*)((const uint32_t*)outA + base * 64);
        for (int i = t; i < 512; i += 256) {
            int row = i >> 4, off = (i & 15) * 8;
            *(uint4*)&s_a[row][off] = src4[i];
        }
    }
    __syncthreads();
    int w = t >> 6, lane = t & 63;
    int mrow = lane & 15, quad = lane >> 4;
    int rt = w >> 1;
    int ct0 = (w & 1) * 4;
    { // GEMM1: out @ Wo  (+ latent + bo)
        bf16x8_t a[4];
        for (int kc = 0; kc < 4; ++kc)
            a[kc] = *(const bf16x8_t*)&s_a[rt * 16 + mrow][kc * 32 + quad * 8];
        for (int cc = 0; cc < 4; ++cc) {
            int ct = ct0 + cc;
            f32x4_t acc = {0.f, 0.f, 0.f, 0.f};
            const unsigned short* bp = WoT + (ct * 16 + mrow) * 128 + quad * 8;
            for (int kc = 0; kc < 4; ++kc)
                acc = __builtin_amdgcn_mfma_f32_16x16x32_bf16(a[kc], *(const bf16x8_t*)(bp + kc * 32), acc, 0, 0, 0);
            for (int r = 0; r < 4; ++r) {
                int row = rt * 16 + quad * 4 + r, f = ct * 16 + mrow;
                s_z[row][f] = acc[r] + s_lat[f];
            }
        }
    }
    __syncthreads();
    for (int i = 0; i < 8; ++i) {   // LN2 per row
        int row = w * 8 + i;
        float v0 = s_z[row][lane], v1 = s_z[row][lane + 64];
        float s = v0 + v1;
        for (int m = 32; m > 0; m >>= 1) s += __shfl_xor(s, m);
        float mu = s * (1.0f / 128.0f);
        float d0 = v0 - mu, d1 = v1 - mu;
        float q = d0 * d0 + d1 * d1;
        for (int m = 32; m > 0; m >>= 1) q += __shfl_xor(q, m);
        float rstd = rsqrtf(q * (1.0f / 128.0f) + 1e-5f);
        s_a2[row][lane]      = f2bf(d0 * rstd * s_g2[lane] + s_b2[lane]);
        s_a2[row][lane + 64] = f2bf(d1 * rstd * s_g2[lane + 64] + s_b2[lane + 64]);
    }
    __syncthreads();
    { // GEMM2: relu(LN2 @ fW1 + fb1) -> s_a (reuse)
        bf16x8_t a[4];
        for (int kc = 0; kc < 4; ++kc)
            a[kc] = *(const bf16x8_t*)&s_a2[rt * 16 + mrow][kc * 32 + quad * 8];
        for (int cc = 0; cc < 4; ++cc) {
            int ct = ct0 + cc;
            f32x4_t acc = {0.f, 0.f, 0.f, 0.f};
            const unsigned short* bp = fW1T + (ct * 16 + mrow) * 128 + quad * 8;
            for (int kc = 0; kc < 4; ++kc)
                acc = __builtin_amdgcn_mfma_f32_16x16x32_bf16(a[kc], *(const bf16x8_t*)(bp + kc * 32), acc, 0, 0, 0);
            for (int r = 0; r < 4; ++r) {
                int row = rt * 16 + quad * 4 + r, f = ct * 16 + mrow;
                s_a[row][f] = f2bf(fmaxf(acc[r] + s_fb1v[f], 0.f));
            }
        }
    }
    __syncthreads();
    { // GEMM3: z + h1 @ fW2 + fb2 -> d_out
        bf16x8_t a[4];
        for (int kc = 0; kc < 4; ++kc)
            a[kc] = *(const bf16x8_t*)&s_a[rt * 16 + mrow][kc * 32 + quad * 8];
        for (int cc = 0; cc < 4; ++cc) {
            int ct = ct0 + cc;
            f32x4_t acc = {0.f, 0.f, 0.f, 0.f};
            const unsigned short* bp = fW2T + (ct * 16 + mrow) * 128 + quad * 8;
            for (int kc = 0; kc < 4; ++kc)
                acc = __builtin_amdgcn_mfma_f32_16x16x32_bf16(a[kc], *(const bf16x8_t*)(bp + kc * 32), acc, 0, 0, 0);
            for (int r = 0; r < 4; ++r) {
                int row = rt * 16 + quad * 4 + r, f = ct * 16 + mrow;
                zout[(base + row) * 128 + f] = s_z[row][f] + acc[r] + s_fb2v[f];
            }
        }
    }
}

extern "C" void kernel_launch(void* const* d_in, const int* in_sizes, int n_in,
                              void* d_out, int out_size, void* d_ws, size_t ws_size,
                              hipStream_t stream) {
    const float* x     = (const float*)d_in[0];
    const float* z     = (const float*)d_in[1];
    const float* latent= (const float*)d_in[6];
    const float* Wq    = (const float*)d_in[7];
    const float* Wk    = (const float*)d_in[8];
    const float* Wv    = (const float*)d_in[9];
    const float* Wo    = (const float*)d_in[10];
    const float* bo    = (const float*)d_in[11];
    const float* kW1   = (const float*)d_in[12];
    const float* kb1   = (const float*)d_in[13];
    const float* kW2   = (const float*)d_in[14];
    const float* kb2   = (const float*)d_in[15];
    const float* lnq_g = (const float*)d_in[16];
    const float* lnq_b = (const float*)d_in[17];
    const float* lnk_g = (const float*)d_in[18];
    const float* lnk_b = (const float*)d_in[19];
    const float* ln2_g = (const float*)d_in[20];
    const float* ln2_b = (const float*)d_in[21];
    const float* fW1   = (const float*)d_in[22];
    const float* fb1   = (const float*)d_in[23];
    const float* fW2   = (const float*)d_in[24];
    const float* fb2   = (const float*)d_in[25];

    uint8_t* ws = (uint8_t*)d_ws;
    unsigned* mm  = (unsigned*)(ws + WS_MM);
    float* ws_d0  = (float*)(ws + WS_D0);
    float* ws_q   = (float*)(ws + WS_Q);
    float* ws_vg  = (float*)(ws + WS_VG);
    int* cnt      = (int*)(ws + WS_CNT);
    int* cell     = (int*)(ws + WS_CELL);
    int* ptIdx    = (int*)(ws + WS_PIDX);
    unsigned short* WkvT = (unsigned short*)(ws + WS_WKVT);
    unsigned short* WoT  = (unsigned short*)(ws + WS_WOT);
    unsigned short* fW1T = (unsigned short*)(ws + WS_FW1T);
    unsigned short* fW2T = (unsigned short*)(ws + WS_FW2T);
    unsigned short* outA = (unsigned short*)(ws + WS_OUTA);
    unsigned short* kv   = (unsigned short*)(ws + WS_KV);

    float* xout = (float*)d_out;            // [B,32,32,2]  = 16384
    float* zout = (float*)d_out + 16384;    // [B,32,32,128]

    k_setup <<<321,  256, 0, stream>>>(Wk, Wv, Wo, fW1, fW2, latent, Wq,
                                       lnq_g, lnq_b, lnk_g, lnk_b, kb1, kW2, kb2,
                                       cnt, mm, WkvT, WoT, fW1T, fW2T, ws_q, ws_vg, ws_d0);
    k_minmax<<<256,  256, 0, stream>>>(x, mm);
    k_bin   <<<256,  256, 0, stream>>>(x, mm, cell, cnt, ptIdx);
    k_kvfix <<<1152, 256, 0, stream>>>(z, lnk_g, lnk_b, WkvT, kv, cell, cnt, ptIdx);
    k_attn  <<<2048, 256, 0, stream>>>(x, cnt, ptIdx, mm, kv, ws_q, ws_vg, ws_d0,
                                       kW1, kb1, kW2, kb2, outA, xout);
    k_ffn   <<<256,  256, 0, stream>>>(outA, latent, bo, ln2_g, ln2_b, fb1, fb2,
                                       WoT, fW1T, fW2T, zout);
}

// Round 5
// 205.925 us; speedup vs baseline: 1.5277x; 1.2328x over previous
//
#include <hip/hip_runtime.h>
#include <stdint.h>

// Problem constants (fixed by the harness)
#define NB 8
#define NN 8192
#define NE 128
#define NH 8
#define NHD 16
#define NKH 32
#define NFF 128
#define NG 32
#define NM 1024          // NG*NG
#define NP 32
#define NT 8192          // NB*NM
#define NPTS 65536       // NB*NN

typedef __attribute__((ext_vector_type(8))) short bf16x8_t;
typedef __attribute__((ext_vector_type(4))) float f32x4_t;

// ---- workspace layout (bytes) ----
#define WS_MM      0         // 4 f32 (mn0,mn1,mx0,mx1) written by k_bin block 0
#define WS_D0      64        // 8 f32: grid-token dots (q.kg/4 + kb0)
#define WS_Q       128       // 128 f32
#define WS_VG      640       // 128 f32
#define WS_PART    1152      // 32 x float4 min/max partials (512 B, ends 1664 < 2048)
#define WS_CNT     2048      // 8192 i32
#define WS_CELL    34816     // 65536 i32
#define WS_PIDX    296960    // 8192*32 i32
#define WS_WKVT    1345536   // 256*128 ushort (bf16), [n][k], n<128 = Wk cols, else Wv
#define WS_WOT     1411072   // 128*128 ushort
#define WS_FW1T    1443840   // 128*128 ushort
#define WS_FW2T    1476608   // 128*128 ushort
#define WS_OUTA    1509376   // 8192*128 ushort (attention out, bf16 row-major)
#define WS_KV      3606528   // 65536*256 ushort ([point][0:128]=k,[128:256]=v)

__device__ __forceinline__ unsigned short f2bf(float f) {  // RNE
    unsigned u = __float_as_uint(f);
    u += 0x7FFFu + ((u >> 16) & 1u);
    return (unsigned short)(u >> 16);
}
__device__ __forceinline__ float bf2f(unsigned short h) {
    return __uint_as_float(((unsigned)h) << 16);
}
__device__ __forceinline__ float bflo(unsigned w) { return __uint_as_float(w << 16); }
__device__ __forceinline__ float bfhi(unsigned w) { return __uint_as_float(w & 0xFFFF0000u); }

// ---------------- K_setup: init + weight pack + precompute + minmax partials ----------------
__global__ __launch_bounds__(256) void k_setup(
        const float* __restrict__ x,
        const float* __restrict__ Wk, const float* __restrict__ Wv, const float* __restrict__ Wo,
        const float* __restrict__ fW1, const float* __restrict__ fW2,
        const float* __restrict__ latent, const float* __restrict__ Wq,
        const float* __restrict__ lnq_g, const float* __restrict__ lnq_b,
        const float* __restrict__ lnk_g, const float* __restrict__ lnk_b,
        const float* __restrict__ kb1, const float* __restrict__ kW2, const float* __restrict__ kb2,
        int* __restrict__ cnt,
        unsigned short* __restrict__ WkvT, unsigned short* __restrict__ WoT,
        unsigned short* __restrict__ fW1T, unsigned short* __restrict__ fW2T,
        float* __restrict__ ws_q, float* __restrict__ ws_vg, float* __restrict__ ws_d0,
        float4* __restrict__ part) {
    int blk = blockIdx.x;
    int t = threadIdx.x;
    if (blk < 320) {
        int idx = blk * 256 + t;   // 81920
        if (idx < NT) cnt[idx] = 0;
        if (idx < 32768) {
            int n = idx >> 7, k = idx & 127;
            float v = (n < 128) ? Wk[k * 128 + n] : Wv[k * 128 + (n - 128)];
            WkvT[idx] = f2bf(v);
        } else if (idx < 49152) {
            int j = idx - 32768; int n = j >> 7, k = j & 127;
            WoT[j] = f2bf(Wo[k * 128 + n]);
        } else if (idx < 65536) {
            int j = idx - 49152; int n = j >> 7, k = j & 127;
            fW1T[j] = f2bf(fW1[k * 128 + n]);
        } else {
            int j = idx - 65536; int n = j >> 7, k = j & 127;
            fW2T[j] = f2bf(fW2[k * 128 + n]);
        }
    } else if (blk == 320) {
        // shared precompute: q, kg, vg, dots0 (one block, first 128 threads)
        __shared__ float s_qn[128], s_kn[128], s_q[128], s_kg[128];
        __shared__ float s_mu, s_rstd;
        if (t < 64) {
            float v0 = latent[t], v1 = latent[t + 64];
            float s = v0 + v1;
            for (int m = 32; m > 0; m >>= 1) s += __shfl_xor(s, m);
            float mu = s * (1.0f / 128.0f);
            float d0 = v0 - mu, d1 = v1 - mu;
            float q = d0 * d0 + d1 * d1;
            for (int m = 32; m > 0; m >>= 1) q += __shfl_xor(q, m);
            if (t == 0) { s_mu = mu; s_rstd = rsqrtf(q * (1.0f / 128.0f) + 1e-5f); }
        }
        __syncthreads();
        if (t < 128) {
            float nv = (latent[t] - s_mu) * s_rstd;
            s_qn[t] = nv * lnq_g[t] + lnq_b[t];
            s_kn[t] = nv * lnk_g[t] + lnk_b[t];
        }
        __syncthreads();
        if (t < 128) {
            float aq = 0.f, ak = 0.f, av = 0.f;
            for (int e = 0; e < 128; ++e) {
                aq += s_qn[e] * Wq[e * 128 + t];
                ak += s_kn[e] * Wk[e * 128 + t];
                av += s_kn[e] * Wv[e * 128 + t];
            }
            s_q[t] = aq; s_kg[t] = ak;
            ws_q[t] = aq; ws_vg[t] = av;
        }
        __syncthreads();
        if (t < 8) {
            float acc = 0.f;
            for (int d = 0; d < 16; ++d) acc += s_q[t * 16 + d] * s_kg[t * 16 + d];
            float kb0 = kb2[t];
            for (int j = 0; j < 32; ++j) kb0 += fmaxf(kb1[j], 0.f) * kW2[j * 8 + t];
            ws_d0[t] = acc * 0.25f + kb0;
        }
    } else {
        // min/max partials: 32 blocks, 2048 points (1024 float4) each; NO atomics.
        __shared__ float s_red[4][4];
        int pb = blk - 321;                 // 0..31
        const float4* xp = (const float4*)x + pb * 1024;
        float mn0 = 1e30f, mx0 = -1e30f, mn1 = 1e30f, mx1 = -1e30f;
        #pragma unroll
        for (int it = 0; it < 4; ++it) {
            float4 v = xp[it * 256 + t];    // two points: (x,y),(z,w)
            mn0 = fminf(mn0, fminf(v.x, v.z)); mx0 = fmaxf(mx0, fmaxf(v.x, v.z));
            mn1 = fminf(mn1, fminf(v.y, v.w)); mx1 = fmaxf(mx1, fmaxf(v.y, v.w));
        }
        #pragma unroll
        for (int m = 32; m > 0; m >>= 1) {
            mn0 = fminf(mn0, __shfl_xor(mn0, m)); mx0 = fmaxf(mx0, __shfl_xor(mx0, m));
            mn1 = fminf(mn1, __shfl_xor(mn1, m)); mx1 = fmaxf(mx1, __shfl_xor(mx1, m));
        }
        int w = t >> 6;
        if ((t & 63) == 0) {
            s_red[w][0] = mn0; s_red[w][1] = mn1; s_red[w][2] = mx0; s_red[w][3] = mx1;
        }
        __syncthreads();
        if (t == 0) {
            float a0 = fminf(fminf(s_red[0][0], s_red[1][0]), fminf(s_red[2][0], s_red[3][0]));
            float a1 = fminf(fminf(s_red[0][1], s_red[1][1]), fminf(s_red[2][1], s_red[3][1]));
            float b0 = fmaxf(fmaxf(s_red[0][2], s_red[1][2]), fmaxf(s_red[2][2], s_red[3][2]));
            float b1 = fmaxf(fmaxf(s_red[0][3], s_red[1][3]), fmaxf(s_red[2][3], s_red[3][3]));
            part[pb] = make_float4(a0, a1, b0, b1);
        }
    }
}

// ---------------- K2: cell assignment + unordered binning (+ mm publish) ----------------
__global__ __launch_bounds__(256) void k_bin(const float* __restrict__ x,
        const float4* __restrict__ part, float* __restrict__ mm,
        int* __restrict__ cell, int* __restrict__ cnt, int* __restrict__ ptIdx) {
    int t = threadIdx.x;
    int l = t & 63;
    // reduce 32 partials (every wave redundantly; lanes>=32 neutral)
    float mn0 = 1e30f, mn1 = 1e30f, mx0 = -1e30f, mx1 = -1e30f;
    if (l < 32) { float4 p = part[l]; mn0 = p.x; mn1 = p.y; mx0 = p.z; mx1 = p.w; }
    #pragma unroll
    for (int m = 32; m > 0; m >>= 1) {
        mn0 = fminf(mn0, __shfl_xor(mn0, m)); mx0 = fmaxf(mx0, __shfl_xor(mx0, m));
        mn1 = fminf(mn1, __shfl_xor(mn1, m)); mx1 = fmaxf(mx1, __shfl_xor(mx1, m));
    }
    if (blockIdx.x == 0 && t == 0) {
        mm[0] = mn0; mm[1] = mn1; mm[2] = mx0; mm[3] = mx1;
    }
    int i = blockIdx.x * 256 + t;  // 65536
    float st0 = (mx0 - mn0) / 31.0f, st1 = (mx1 - mn1) / 31.0f;  // matches jnp exactly
    float2 xv = ((const float2*)x)[i];
    int i0 = (int)rintf((xv.x - mn0) / st0); i0 = min(max(i0, 0), 31);
    int i1 = (int)rintf((xv.y - mn1) / st1); i1 = min(max(i1, 0), 31);
    int c = i0 * 32 + i1;
    cell[i] = c;
    int bb = i >> 13;
    int slot = atomicAdd(&cnt[bb * NM + c], 1);
    if (slot < NP) ptIdx[(bb * NM + c) * NP + slot] = i & (NN - 1);
}

// ---------------- K6: LN(z) + K/V projection (transposed MFMA, direct global store)
//                    + overflow fixup merged (blocks >= 1024) ----------------
__global__ __launch_bounds__(256) void k_kvfix(const float* __restrict__ z,
        const float* __restrict__ lnk_g, const float* __restrict__ lnk_b,
        const unsigned short* __restrict__ WkvT, unsigned short* __restrict__ kv,
        const int* __restrict__ cell, int* __restrict__ cnt, int* __restrict__ ptIdx) {
    int t = threadIdx.x;
    if (blockIdx.x >= 1024) {
        // ---- fixup path: 128 blocks * 4 waves, each wave scans 16 (b,cell) slots ----
        int wave = (blockIdx.x - 1024) * 4 + (t >> 6);   // 0..511
        int lane = t & 63;
        int wbase = wave * 16;
        int cval = (lane < 16) ? cnt[wbase + lane] : 0;
        unsigned long long ovf = __ballot(cval > NP);
        while (ovf) {
            int s = __ffsll((long long)ovf) - 1;
            ovf &= ovf - 1;
            int wid = wbase + s;
            int b = wid >> 10, mycell = wid & 1023;
            const int* cb = cell + b * NN;
            int run = 0;
            for (int ch = 0; ch < NN / 64 && run < NP; ++ch) {
                int n = ch * 64 + lane;
                bool match = (cb[n] == mycell);
                unsigned long long mask = __ballot(match);
                if (match) {
                    int rank = run + __popcll(mask & ((1ull << lane) - 1ull));
                    if (rank < NP) ptIdx[wid * NP + rank] = n;
                }
                run += __popcll(mask);
            }
            if (lane == 0) cnt[wid] = NP;
        }
        return;
    }
    // ---- kv path: 64 tokens per block, 16 per wave, no barriers ----
    __shared__ unsigned short s_zn[64][136];
    int w = t >> 6, lane = t & 63;
    long base = (long)blockIdx.x * 64;
    // LN: 2 rows per iteration, 32 lanes per row, float4 per lane
    int sub = lane >> 5;         // which of the 2 rows
    int lq = lane & 31;          // lane within row; features lq*4..lq*4+3
    float4 g4 = ((const float4*)lnk_g)[lq];
    float4 b4 = ((const float4*)lnk_b)[lq];
    #pragma unroll
    for (int i = 0; i < 8; ++i) {
        int pl = w * 16 + i * 2 + sub;
        float4 v = ((const float4*)z)[(base + pl) * 32 + lq];
        float sum = v.x + v.y + v.z + v.w;
        float ssq = v.x * v.x + v.y * v.y + v.z * v.z + v.w * v.w;
        #pragma unroll
        for (int m = 1; m < 32; m <<= 1) {
            sum += __shfl_xor(sum, m);
            ssq += __shfl_xor(ssq, m);
        }
        float mu = sum * (1.0f / 128.0f);
        float var = fmaxf(ssq * (1.0f / 128.0f) - mu * mu, 0.0f);
        float rstd = rsqrtf(var + 1e-5f);
        float n0 = (v.x - mu) * rstd * g4.x + b4.x;
        float n1 = (v.y - mu) * rstd * g4.y + b4.y;
        float n2 = (v.z - mu) * rstd * g4.z + b4.z;
        float n3 = (v.w - mu) * rstd * g4.w + b4.w;
        unsigned d0 = (unsigned)f2bf(n0) | ((unsigned)f2bf(n1) << 16);
        unsigned d1 = (unsigned)f2bf(n2) | ((unsigned)f2bf(n3) << 16);
        *(uint2*)&s_zn[pl][lq * 4] = make_uint2(d0, d1);
    }
    // MFMA: A = WkvT (features = m), B = zn tokens (n). Wave w owns tokens w*16..+15.
    // No __syncthreads needed: wave reads exactly the LDS rows it wrote.
    int mrow = lane & 15, quad = lane >> 4;
    bf16x8_t bfrag[4];
    #pragma unroll
    for (int kc = 0; kc < 4; ++kc)
        bfrag[kc] = *(const bf16x8_t*)&s_zn[w * 16 + mrow][kc * 32 + quad * 8];
    long tk = base + w * 16 + mrow;        // D col n = lane&15 -> token; D row = feature
    #pragma unroll
    for (int ft = 0; ft < 16; ++ft) {
        f32x4_t acc = {0.f, 0.f, 0.f, 0.f};
        const unsigned short* ap = WkvT + (ft * 16 + mrow) * 128 + quad * 8;
        #pragma unroll
        for (int kc = 0; kc < 4; ++kc) {
            bf16x8_t a = *(const bf16x8_t*)(ap + kc * 32);
            acc = __builtin_amdgcn_mfma_f32_16x16x32_bf16(a, bfrag[kc], acc, 0, 0, 0);
        }
        unsigned d0 = (unsigned)f2bf(acc[0]) | ((unsigned)f2bf(acc[1]) << 16);
        unsigned d1 = (unsigned)f2bf(acc[2]) | ((unsigned)f2bf(acc[3]) << 16);
        int f0 = ft * 16 + quad * 4;
        *(uint2*)(kv + tk * 256 + f0) = make_uint2(d0, d1);
    }
}

// ---------------- K7: per-cell attention — wave-per-token, no LDS, no barriers ----------------
// Lane layout: lane l -> head h=l>>3, sub j'=l&7, features f=2l,2l+1 (h*16+2j' == 2l).
__global__ __launch_bounds__(256) void k_attn(const float* __restrict__ x,
        const int* __restrict__ cnt, const int* __restrict__ ptIdx,
        const float* __restrict__ mm, const unsigned short* __restrict__ kv,
        const float* __restrict__ ws_q, const float* __restrict__ ws_vg,
        const float* __restrict__ ws_d0,
        const float* __restrict__ kW1, const float* __restrict__ kb1,
        const float* __restrict__ kW2, const float* __restrict__ kb2,
        unsigned short* __restrict__ outA, float* __restrict__ xout) {
    int t = threadIdx.x;
    int l = t & 63;
    int bm = blockIdx.x * 4 + (t >> 6);   // one wave per (b,cell) token
    int b = bm >> 10;
    int h = l >> 3, jp = l & 7;

    float mn0 = mm[0], mn1 = mm[1], mx0 = mm[2], mx1 = mm[3];
    int i0 = (bm & 1023) >> 5, i1 = bm & 31;
    float st0 = (mx0 - mn0) / 31.0f, st1 = (mx1 - mn1) / 31.0f;
    float xg0 = (i0 == 31) ? mx0 : mn0 + i0 * st0;
    float xg1 = (i1 == 31) ? mx1 : mn1 + i1 * st1;
    int c = min(cnt[bm], NP);

    // per-lane constants
    float q0 = ws_q[2 * l] * 0.25f, q1 = ws_q[2 * l + 1] * 0.25f;  // fold 1/sqrt(hd)
    float vg0 = ws_vg[2 * l], vg1 = ws_vg[2 * l + 1];
    float ag = ws_d0[h];          // grid-token score (already scaled + kb)
    float kb2h = kb2[h];
    float w1a[4], w1b[4], b1v[4], w2v[4];
    #pragma unroll
    for (int m = 0; m < 4; ++m) {
        int j = jp + 8 * m;
        w1a[m] = kW1[j]; w1b[m] = kW1[32 + j]; b1v[m] = kb1[j]; w2v[m] = kW2[j * 8 + h];
    }

    // per-key lane-resident data (lane k holds key k's idx and coords)
    int idxreg = 0; float x0r = 0.f, x1r = 0.f;
    if (l < c) {
        idxreg = ptIdx[bm * NP + l];
        float2 xv = ((const float2*)x)[(size_t)b * NN + idxreg];
        x0r = xv.x; x1r = xv.y;
    }

    unsigned vreg[NP];
    float areg[4];
    #pragma unroll
    for (int k = 0; k < NP; ++k) vreg[k] = 0u;
    areg[0] = areg[1] = areg[2] = areg[3] = -1e30f;

    #pragma unroll
    for (int key = 0; key < NP; ++key) {
        if (key < c) {                       // wave-uniform branch
            int idxk = __shfl(idxreg, key);
            const unsigned* rowp = (const unsigned*)kv + ((size_t)(b * NN + idxk) << 7);
            unsigned kw = rowp[l];           // k features 2l,2l+1  (coalesced 256B)
            vreg[key] = rowp[64 + l];        // v features 2l,2l+1
            float d0 = __shfl(x0r, key) - xg0;
            float d1 = __shfl(x1r, key) - xg1;
            float part = q0 * bflo(kw) + q1 * bfhi(kw);
            #pragma unroll
            for (int m = 0; m < 4; ++m) {    // kernel-bias MLP partial (j = jp+8m)
                float hj = fmaf(d0, w1a[m], fmaf(d1, w1b[m], b1v[m]));
                hj = fmaxf(hj, 0.f);
                part = fmaf(hj, w2v[m], part);
            }
            part += __shfl_xor(part, 1);
            part += __shfl_xor(part, 2);
            part += __shfl_xor(part, 4);     // sum over j' -> full dot + kb
            float score = part + kb2h;
            if (jp == (key & 7)) areg[key >> 3] = score;
        }
    }

    // softmax over {grid, keys} per head (within 8-lane group)
    float mx = fmaxf(fmaxf(areg[0], areg[1]), fmaxf(areg[2], areg[3]));
    mx = fmaxf(mx, ag);
    mx = fmaxf(mx, __shfl_xor(mx, 1));
    mx = fmaxf(mx, __shfl_xor(mx, 2));
    mx = fmaxf(mx, __shfl_xor(mx, 4));
    float e0 = __expf(areg[0] - mx), e1 = __expf(areg[1] - mx);
    float e2 = __expf(areg[2] - mx), e3 = __expf(areg[3] - mx);
    float eg = __expf(ag - mx);
    float s = e0 + e1 + e2 + e3;
    s += __shfl_xor(s, 1);
    s += __shfl_xor(s, 2);
    s += __shfl_xor(s, 4);
    s += eg;                                  // eg uniform within group
    float inv = 1.0f / s;

    // out = A @ v   (lane owns features 2l,2l+1 of head h)
    float accA = eg * inv * vg0, accB = eg * inv * vg1;
    #pragma unroll
    for (int key = 0; key < NP; ++key) {
        if (key < c) {
            int src = (l & 56) | (key & 7);
            float em = (key >> 3) == 0 ? e0 : (key >> 3) == 1 ? e1 : (key >> 3) == 2 ? e2 : e3;
            float a = __shfl(em, src) * inv;
            unsigned vw = vreg[key];
            accA = fmaf(a, bflo(vw), accA);
            accB = fmaf(a, bfhi(vw), accB);
        }
    }
    unsigned ow = ((unsigned)f2bf(accB) << 16) | (unsigned)f2bf(accA);
    ((unsigned*)outA)[(size_t)bm * 64 + l] = ow;

    // x_new = mean_h(A) @ joint_x
    float s0 = e0 * inv, s1 = e1 * inv, s2 = e2 * inv, s3 = e3 * inv, sg = eg * inv;
    #pragma unroll
    for (int m = 8; m <= 32; m <<= 1) {       // reduce over heads
        s0 += __shfl_xor(s0, m); s1 += __shfl_xor(s1, m);
        s2 += __shfl_xor(s2, m); s3 += __shfl_xor(s3, m);
        sg += __shfl_xor(sg, m);
    }
    float px0 = 0.f, px1 = 0.f;
    {
        float xx0, xx1;
        xx0 = __shfl(x0r, jp);      xx1 = __shfl(x1r, jp);
        px0 = fmaf(s0, xx0, px0);   px1 = fmaf(s0, xx1, px1);
        xx0 = __shfl(x0r, jp + 8);  xx1 = __shfl(x1r, jp + 8);
        px0 = fmaf(s1, xx0, px0);   px1 = fmaf(s1, xx1, px1);
        xx0 = __shfl(x0r, jp + 16); xx1 = __shfl(x1r, jp + 16);
        px0 = fmaf(s2, xx0, px0);   px1 = fmaf(s2, xx1, px1);
        xx0 = __shfl(x0r, jp + 24); xx1 = __shfl(x1r, jp + 24);
        px0 = fmaf(s3, xx0, px0);   px1 = fmaf(s3, xx1, px1);
    }
    px0 += __shfl_xor(px0, 1); px1 += __shfl_xor(px1, 1);
    px0 += __shfl_xor(px0, 2); px1 += __shfl_xor(px1, 2);
    px0 += __shfl_xor(px0, 4); px1 += __shfl_xor(px1, 4);
    if (l == 0) {
        xout[bm * 2]     = (px0 + sg * xg0) * 0.125f;
        xout[bm * 2 + 1] = (px1 + sg * xg1) * 0.125f;
    }
}

// ---------------- K8: z_new = zq + out@Wo + bo; + FFN(LN2) ----------------
__global__ __launch_bounds__(256) void k_ffn(const unsigned short* __restrict__ outA,
        const float* __restrict__ latent, const float* __restrict__ bo,
        const float* __restrict__ ln2_g, const float* __restrict__ ln2_b,
        const float* __restrict__ fb1, const float* __restrict__ fb2,
        const unsigned short* __restrict__ WoT, const unsigned short* __restrict__ fW1T,
        const unsigned short* __restrict__ fW2T, float* __restrict__ zout) {
    __shared__ unsigned short s_a[32][136];
    __shared__ unsigned short s_a2[32][136];
    __shared__ float s_z[32][128];
    __shared__ float s_lat[128], s_g2[128], s_b2[128], s_fb1v[128], s_fb2v[128];
    int t = threadIdx.x;
    long base = (long)blockIdx.x * 32;
    if (t < 128) {
        s_lat[t] = latent[t] + bo[t];
        s_g2[t] = ln2_g[t]; s_b2[t] = ln2_b[t];
        s_fb1v[t] = fb1[t]; s_fb2v[t] = fb2[t];
    }
    {
        const uint4* src4 = (const uint4*)((const uint32_t*)outA + base * 64);
        for (int i = t; i < 512; i += 256) {
            int row = i >> 4, off = (i & 15) * 8;
            *(uint4*)&s_a[row][off] = src4[i];
        }
    }
    __syncthreads();
    int w = t >> 6, lane = t & 63;
    int mrow = lane & 15, quad = lane >> 4;
    int rt = w >> 1;
    int ct0 = (w & 1) * 4;
    { // GEMM1: out @ Wo  (+ latent + bo)
        bf16x8_t a[4];
        for (int kc = 0; kc < 4; ++kc)
            a[kc] = *(const bf16x8_t*)&s_a[rt * 16 + mrow][kc * 32 + quad * 8];
        for (int cc = 0; cc < 4; ++cc) {
            int ct = ct0 + cc;
            f32x4_t acc = {0.f, 0.f, 0.f, 0.f};
            const unsigned short* bp = WoT + (ct * 16 + mrow) * 128 + quad * 8;
            for (int kc = 0; kc < 4; ++kc)
                acc = __builtin_amdgcn_mfma_f32_16x16x32_bf16(a[kc], *(const bf16x8_t*)(bp + kc * 32), acc, 0, 0, 0);
            for (int r = 0; r < 4; ++r) {
                int row = rt * 16 + quad * 4 + r, f = ct * 16 + mrow;
                s_z[row][f] = acc[r] + s_lat[f];
            }
        }
    }
    __syncthreads();
    for (int i = 0; i < 8; ++i) {   // LN2 per row
        int row = w * 8 + i;
        float v0 = s_z[row][lane], v1 = s_z[row][lane + 64];
        float s = v0 + v1;
        for (int m = 32; m > 0; m >>= 1) s += __shfl_xor(s, m);
        float mu = s * (1.0f / 128.0f);
        float d0 = v0 - mu, d1 = v1 - mu;
        float q = d0 * d0 + d1 * d1;
        for (int m = 32; m > 0; m >>= 1) q += __shfl_xor(q, m);
        float rstd = rsqrtf(q * (1.0f / 128.0f) + 1e-5f);
        s_a2[row][lane]      = f2bf(d0 * rstd * s_g2[lane] + s_b2[lane]);
        s_a2[row][lane + 64] = f2bf(d1 * rstd * s_g2[lane + 64] + s_b2[lane + 64]);
    }
    __syncthreads();
    { // GEMM2: relu(LN2 @ fW1 + fb1) -> s_a (reuse)
        bf16x8_t a[4];
        for (int kc = 0; kc < 4; ++kc)
            a[kc] = *(const bf16x8_t*)&s_a2[rt * 16 + mrow][kc * 32 + quad * 8];
        for (int cc = 0; cc < 4; ++cc) {
            int ct = ct0 + cc;
            f32x4_t acc = {0.f, 0.f, 0.f, 0.f};
            const unsigned short* bp = fW1T + (ct * 16 + mrow) * 128 + quad * 8;
            for (int kc = 0; kc < 4; ++kc)
                acc = __builtin_amdgcn_mfma_f32_16x16x32_bf16(a[kc], *(const bf16x8_t*)(bp + kc * 32), acc, 0, 0, 0);
            for (int r = 0; r < 4; ++r) {
                int row = rt * 16 + quad * 4 + r, f = ct * 16 + mrow;
                s_a[row][f] = f2bf(fmaxf(acc[r] + s_fb1v[f], 0.f));
            }
        }
    }
    __syncthreads();
    { // GEMM3: z + h1 @ fW2 + fb2 -> d_out
        bf16x8_t a[4];
        for (int kc = 0; kc < 4; ++kc)
            a[kc] = *(const bf16x8_t*)&s_a[rt * 16 + mrow][kc * 32 + quad * 8];
        for (int cc = 0; cc < 4; ++cc) {
            int ct = ct0 + cc;
            f32x4_t acc = {0.f, 0.f, 0.f, 0.f};
            const unsigned short* bp = fW2T + (ct * 16 + mrow) * 128 + quad * 8;
            for (int kc = 0; kc < 4; ++kc)
                acc = __builtin_amdgcn_mfma_f32_16x16x32_bf16(a[kc], *(const bf16x8_t*)(bp + kc * 32), acc, 0, 0, 0);
            for (int r = 0; r < 4; ++r) {
                int row = rt * 16 + quad * 4 + r, f = ct * 16 + mrow;
                zout[(base + row) * 128 + f] = s_z[row][f] + acc[r] + s_fb2v[f];
            }
        }
    }
}

extern "C" void kernel_launch(void* const* d_in, const int* in_sizes, int n_in,
                              void* d_out, int out_size, void* d_ws, size_t ws_size,
                              hipStream_t stream) {
    const float* x     = (const float*)d_in[0];
    const float* z     = (const float*)d_in[1];
    const float* latent= (const float*)d_in[6];
    const float* Wq    = (const float*)d_in[7];
    const float* Wk    = (const float*)d_in[8];
    const float* Wv    = (const float*)d_in[9];
    const float* Wo    = (const float*)d_in[10];
    const float* bo    = (const float*)d_in[11];
    const float* kW1   = (const float*)d_in[12];
    const float* kb1   = (const float*)d_in[13];
    const float* kW2   = (const float*)d_in[14];
    const float* kb2   = (const float*)d_in[15];
    const float* lnq_g = (const float*)d_in[16];
    const float* lnq_b = (const float*)d_in[17];
    const float* lnk_g = (const float*)d_in[18];
    const float* lnk_b = (const float*)d_in[19];
    const float* ln2_g = (const float*)d_in[20];
    const float* ln2_b = (const float*)d_in[21];
    const float* fW1   = (const float*)d_in[22];
    const float* fb1   = (const float*)d_in[23];
    const float* fW2   = (const float*)d_in[24];
    const float* fb2   = (const float*)d_in[25];

    uint8_t* ws = (uint8_t*)d_ws;
    float* mm     = (float*)(ws + WS_MM);
    float* ws_d0  = (float*)(ws + WS_D0);
    float* ws_q   = (float*)(ws + WS_Q);
    float* ws_vg  = (float*)(ws + WS_VG);
    float4* part  = (float4*)(ws + WS_PART);
    int* cnt      = (int*)(ws + WS_CNT);
    int* cell     = (int*)(ws + WS_CELL);
    int* ptIdx    = (int*)(ws + WS_PIDX);
    unsigned short* WkvT = (unsigned short*)(ws + WS_WKVT);
    unsigned short* WoT  = (unsigned short*)(ws + WS_WOT);
    unsigned short* fW1T = (unsigned short*)(ws + WS_FW1T);
    unsigned short* fW2T = (unsigned short*)(ws + WS_FW2T);
    unsigned short* outA = (unsigned short*)(ws + WS_OUTA);
    unsigned short* kv   = (unsigned short*)(ws + WS_KV);

    float* xout = (float*)d_out;            // [B,32,32,2]  = 16384
    float* zout = (float*)d_out + 16384;    // [B,32,32,128]

    k_setup <<<353,  256, 0, stream>>>(x, Wk, Wv, Wo, fW1, fW2, latent, Wq,
                                       lnq_g, lnq_b, lnk_g, lnk_b, kb1, kW2, kb2,
                                       cnt, WkvT, WoT, fW1T, fW2T, ws_q, ws_vg, ws_d0, part);
    k_bin   <<<256,  256, 0, stream>>>(x, part, mm, cell, cnt, ptIdx);
    k_kvfix <<<1152, 256, 0, stream>>>(z, lnk_g, lnk_b, WkvT, kv, cell, cnt, ptIdx);
    k_attn  <<<2048, 256, 0, stream>>>(x, cnt, ptIdx, mm, kv, ws_q, ws_vg, ws_d0,
                                       kW1, kb1, kW2, kb2, outA, xout);
    k_ffn   <<<256,  256, 0, stream>>>(outA, latent, bo, ln2_g, ln2_b, fb1, fb2,
                                       WoT, fW1T, fW2T, zout);
}

// Round 6
// 202.051 us; speedup vs baseline: 1.5570x; 1.0192x over previous
//
#include <hip/hip_runtime.h>
#include <stdint.h>

// Problem constants (fixed by the harness)
#define NB 8
#define NN 8192
#define NE 128
#define NH 8
#define NHD 16
#define NKH 32
#define NFF 128
#define NG 32
#define NM 1024          // NG*NG
#define NP 32
#define NT 8192          // NB*NM
#define NPTS 65536       // NB*NN

typedef __attribute__((ext_vector_type(8))) short bf16x8_t;
typedef __attribute__((ext_vector_type(4))) float f32x4_t;

// ---- workspace layout (bytes) ----
#define WS_MM      0         // 4 f32 (mn0,mn1,mx0,mx1) written by k_bin block 0
#define WS_D0      64        // 8 f32: grid-token dots (q.kg/4 + kb0)
#define WS_Q       128       // 128 f32
#define WS_VG      640       // 128 f32
#define WS_PART    1152      // 32 x float4 min/max partials
#define WS_CNT     2048      // 8192 i32
#define WS_CELL    34816     // 65536 i32
#define WS_PIDX    296960    // 8192*32 i32
#define WS_WKVT    1345536   // 256*128 ushort (bf16), [n][k], n<128 = Wk cols, else Wv
#define WS_WOT     1411072   // 128*128 ushort
#define WS_FW1T    1443840   // 128*128 ushort
#define WS_FW2T    1476608   // 128*128 ushort
#define WS_OUTA    1509376   // 8192*128 ushort (attention out, bf16 row-major)
#define WS_KV      3606528   // 65536*256 ushort ([point][0:128]=k,[128:256]=v)

__device__ __forceinline__ unsigned short f2bf(float f) {  // RNE
    unsigned u = __float_as_uint(f);
    u += 0x7FFFu + ((u >> 16) & 1u);
    return (unsigned short)(u >> 16);
}
__device__ __forceinline__ float bf2f(unsigned short h) {
    return __uint_as_float(((unsigned)h) << 16);
}
__device__ __forceinline__ float bflo(unsigned w) { return __uint_as_float(w << 16); }
__device__ __forceinline__ float bfhi(unsigned w) { return __uint_as_float(w & 0xFFFF0000u); }

// ---------------- K_setup: tile-transpose pack + init + precompute + minmax ----------------
// blocks 0..19: 64x64 LDS tile transposes (coalesced both sides)
// blocks 20..51: cnt zero-init
// block 52: shared precompute
// blocks 53..84: minmax partials
__global__ __launch_bounds__(256) void k_setup(
        const float* __restrict__ x,
        const float* __restrict__ Wk, const float* __restrict__ Wv, const float* __restrict__ Wo,
        const float* __restrict__ fW1, const float* __restrict__ fW2,
        const float* __restrict__ latent, const float* __restrict__ Wq,
        const float* __restrict__ lnq_g, const float* __restrict__ lnq_b,
        const float* __restrict__ lnk_g, const float* __restrict__ lnk_b,
        const float* __restrict__ kb1, const float* __restrict__ kW2, const float* __restrict__ kb2,
        int* __restrict__ cnt,
        unsigned short* __restrict__ WkvT, unsigned short* __restrict__ WoT,
        unsigned short* __restrict__ fW1T, unsigned short* __restrict__ fW2T,
        float* __restrict__ ws_q, float* __restrict__ ws_vg, float* __restrict__ ws_d0,
        float4* __restrict__ part) {
    int blk = blockIdx.x;
    int t = threadIdx.x;
    if (blk < 20) {
        __shared__ float s_t[64][65];
        const float* src; unsigned short* dst;
        int n0, k0, srcN0;
        if (blk < 8) {
            int tn = blk >> 1, tk = blk & 1;
            n0 = tn * 64; k0 = tk * 64;
            dst = WkvT;
            if (n0 < 128) { src = Wk; srcN0 = n0; }
            else          { src = Wv; srcN0 = n0 - 128; }
        } else {
            int m = (blk - 8) >> 2, s4 = (blk - 8) & 3;
            int tn = s4 >> 1, tk = s4 & 1;
            n0 = tn * 64; k0 = tk * 64; srcN0 = n0;
            src = (m == 0) ? Wo : (m == 1) ? fW1 : fW2;
            dst = (m == 0) ? WoT : (m == 1) ? fW1T : fW2T;
        }
        int tx = t & 63, ty = t >> 6;
        #pragma unroll
        for (int r = 0; r < 16; ++r) {
            int kr = r * 4 + ty;
            s_t[kr][tx] = src[(k0 + kr) * 128 + srcN0 + tx];
        }
        __syncthreads();
        #pragma unroll
        for (int r = 0; r < 16; ++r) {
            int nr = r * 4 + ty;
            dst[(n0 + nr) * 128 + k0 + tx] = f2bf(s_t[tx][nr]);
        }
    } else if (blk < 52) {
        int idx = (blk - 20) * 256 + t;   // exactly 8192
        cnt[idx] = 0;
    } else if (blk == 52) {
        // shared precompute: q, kg, vg, dots0 (first 128 threads)
        __shared__ float s_qn[128], s_kn[128], s_q[128], s_kg[128];
        __shared__ float s_mu, s_rstd;
        if (t < 64) {
            float v0 = latent[t], v1 = latent[t + 64];
            float s = v0 + v1;
            for (int m = 32; m > 0; m >>= 1) s += __shfl_xor(s, m);
            float mu = s * (1.0f / 128.0f);
            float d0 = v0 - mu, d1 = v1 - mu;
            float q = d0 * d0 + d1 * d1;
            for (int m = 32; m > 0; m >>= 1) q += __shfl_xor(q, m);
            if (t == 0) { s_mu = mu; s_rstd = rsqrtf(q * (1.0f / 128.0f) + 1e-5f); }
        }
        __syncthreads();
        if (t < 128) {
            float nv = (latent[t] - s_mu) * s_rstd;
            s_qn[t] = nv * lnq_g[t] + lnq_b[t];
            s_kn[t] = nv * lnk_g[t] + lnk_b[t];
        }
        __syncthreads();
        if (t < 128) {
            float aq = 0.f, ak = 0.f, av = 0.f;
            for (int e = 0; e < 128; ++e) {
                aq += s_qn[e] * Wq[e * 128 + t];
                ak += s_kn[e] * Wk[e * 128 + t];
                av += s_kn[e] * Wv[e * 128 + t];
            }
            s_q[t] = aq; s_kg[t] = ak;
            ws_q[t] = aq; ws_vg[t] = av;
        }
        __syncthreads();
        if (t < 8) {
            float acc = 0.f;
            for (int d = 0; d < 16; ++d) acc += s_q[t * 16 + d] * s_kg[t * 16 + d];
            float kb0 = kb2[t];
            for (int j = 0; j < 32; ++j) kb0 += fmaxf(kb1[j], 0.f) * kW2[j * 8 + t];
            ws_d0[t] = acc * 0.25f + kb0;
        }
    } else {
        // min/max partials: 32 blocks, 2048 points (1024 float4) each; NO atomics.
        __shared__ float s_red[4][4];
        int pb = blk - 53;                 // 0..31
        const float4* xp = (const float4*)x + pb * 1024;
        float mn0 = 1e30f, mx0 = -1e30f, mn1 = 1e30f, mx1 = -1e30f;
        #pragma unroll
        for (int it = 0; it < 4; ++it) {
            float4 v = xp[it * 256 + t];    // two points: (x,y),(z,w)
            mn0 = fminf(mn0, fminf(v.x, v.z)); mx0 = fmaxf(mx0, fmaxf(v.x, v.z));
            mn1 = fminf(mn1, fminf(v.y, v.w)); mx1 = fmaxf(mx1, fmaxf(v.y, v.w));
        }
        #pragma unroll
        for (int m = 32; m > 0; m >>= 1) {
            mn0 = fminf(mn0, __shfl_xor(mn0, m)); mx0 = fmaxf(mx0, __shfl_xor(mx0, m));
            mn1 = fminf(mn1, __shfl_xor(mn1, m)); mx1 = fmaxf(mx1, __shfl_xor(mx1, m));
        }
        int w = t >> 6;
        if ((t & 63) == 0) {
            s_red[w][0] = mn0; s_red[w][1] = mn1; s_red[w][2] = mx0; s_red[w][3] = mx1;
        }
        __syncthreads();
        if (t == 0) {
            float a0 = fminf(fminf(s_red[0][0], s_red[1][0]), fminf(s_red[2][0], s_red[3][0]));
            float a1 = fminf(fminf(s_red[0][1], s_red[1][1]), fminf(s_red[2][1], s_red[3][1]));
            float b0 = fmaxf(fmaxf(s_red[0][2], s_red[1][2]), fmaxf(s_red[2][2], s_red[3][2]));
            float b1 = fmaxf(fmaxf(s_red[0][3], s_red[1][3]), fmaxf(s_red[2][3], s_red[3][3]));
            part[pb] = make_float4(a0, a1, b0, b1);
        }
    }
}

// ---------------- K2: cell assignment + unordered binning (+ mm publish) ----------------
__global__ __launch_bounds__(256) void k_bin(const float* __restrict__ x,
        const float4* __restrict__ part, float* __restrict__ mm,
        int* __restrict__ cell, int* __restrict__ cnt, int* __restrict__ ptIdx) {
    int t = threadIdx.x;
    int l = t & 63;
    // reduce 32 partials (every wave redundantly; lanes>=32 neutral)
    float mn0 = 1e30f, mn1 = 1e30f, mx0 = -1e30f, mx1 = -1e30f;
    if (l < 32) { float4 p = part[l]; mn0 = p.x; mn1 = p.y; mx0 = p.z; mx1 = p.w; }
    #pragma unroll
    for (int m = 32; m > 0; m >>= 1) {
        mn0 = fminf(mn0, __shfl_xor(mn0, m)); mx0 = fmaxf(mx0, __shfl_xor(mx0, m));
        mn1 = fminf(mn1, __shfl_xor(mn1, m)); mx1 = fmaxf(mx1, __shfl_xor(mx1, m));
    }
    if (blockIdx.x == 0 && t == 0) {
        mm[0] = mn0; mm[1] = mn1; mm[2] = mx0; mm[3] = mx1;
    }
    int i = blockIdx.x * 256 + t;  // 65536
    float st0 = (mx0 - mn0) / 31.0f, st1 = (mx1 - mn1) / 31.0f;  // matches jnp exactly
    float2 xv = ((const float2*)x)[i];
    int i0 = (int)rintf((xv.x - mn0) / st0); i0 = min(max(i0, 0), 31);
    int i1 = (int)rintf((xv.y - mn1) / st1); i1 = min(max(i1, 0), 31);
    int c = i0 * 32 + i1;
    cell[i] = c;
    int bb = i >> 13;
    int slot = atomicAdd(&cnt[bb * NM + c], 1);
    if (slot < NP) ptIdx[(bb * NM + c) * NP + slot] = i & (NN - 1);
}

// ---------------- K6: LN(z) + K/V projection (transposed MFMA, direct global store)
//                    + overflow fixup merged (blocks >= 1024) ----------------
__global__ __launch_bounds__(256) void k_kvfix(const float* __restrict__ z,
        const float* __restrict__ lnk_g, const float* __restrict__ lnk_b,
        const unsigned short* __restrict__ WkvT, unsigned short* __restrict__ kv,
        const int* __restrict__ cell, int* __restrict__ cnt, int* __restrict__ ptIdx) {
    int t = threadIdx.x;
    if (blockIdx.x >= 1024) {
        // ---- fixup path: 128 blocks * 4 waves, each wave scans 16 (b,cell) slots ----
        int wave = (blockIdx.x - 1024) * 4 + (t >> 6);   // 0..511
        int lane = t & 63;
        int wbase = wave * 16;
        int cval = (lane < 16) ? cnt[wbase + lane] : 0;
        unsigned long long ovf = __ballot(cval > NP);
        while (ovf) {
            int s = __ffsll((long long)ovf) - 1;
            ovf &= ovf - 1;
            int wid = wbase + s;
            int b = wid >> 10, mycell = wid & 1023;
            const int* cb = cell + b * NN;
            int run = 0;
            for (int ch = 0; ch < NN / 64 && run < NP; ++ch) {
                int n = ch * 64 + lane;
                bool match = (cb[n] == mycell);
                unsigned long long mask = __ballot(match);
                if (match) {
                    int rank = run + __popcll(mask & ((1ull << lane) - 1ull));
                    if (rank < NP) ptIdx[wid * NP + rank] = n;
                }
                run += __popcll(mask);
            }
            if (lane == 0) cnt[wid] = NP;
        }
        return;
    }
    // ---- kv path: 64 tokens per block, 16 per wave, no barriers ----
    __shared__ unsigned short s_zn[64][136];
    int w = t >> 6, lane = t & 63;
    long base = (long)blockIdx.x * 64;
    int sub = lane >> 5;         // which of the 2 rows
    int lq = lane & 31;          // lane within row; features lq*4..lq*4+3
    float4 g4 = ((const float4*)lnk_g)[lq];
    float4 b4 = ((const float4*)lnk_b)[lq];
    // hoist ALL 8 loads first: 8 outstanding HBM loads, then 8 independent
    // reduction chains interleave (ILP). Prev version serialized (VGPR=24).
    float4 v[8];
    #pragma unroll
    for (int i = 0; i < 8; ++i) {
        int pl = w * 16 + i * 2 + sub;
        v[i] = ((const float4*)z)[(base + pl) * 32 + lq];
    }
    #pragma unroll
    for (int i = 0; i < 8; ++i) {
        int pl = w * 16 + i * 2 + sub;
        float sum = v[i].x + v[i].y + v[i].z + v[i].w;
        float ssq = v[i].x * v[i].x + v[i].y * v[i].y + v[i].z * v[i].z + v[i].w * v[i].w;
        #pragma unroll
        for (int m = 1; m < 32; m <<= 1) {
            sum += __shfl_xor(sum, m);
            ssq += __shfl_xor(ssq, m);
        }
        float mu = sum * (1.0f / 128.0f);
        float var = fmaxf(ssq * (1.0f / 128.0f) - mu * mu, 0.0f);
        float rstd = rsqrtf(var + 1e-5f);
        float n0 = (v[i].x - mu) * rstd * g4.x + b4.x;
        float n1 = (v[i].y - mu) * rstd * g4.y + b4.y;
        float n2 = (v[i].z - mu) * rstd * g4.z + b4.z;
        float n3 = (v[i].w - mu) * rstd * g4.w + b4.w;
        unsigned d0 = (unsigned)f2bf(n0) | ((unsigned)f2bf(n1) << 16);
        unsigned d1 = (unsigned)f2bf(n2) | ((unsigned)f2bf(n3) << 16);
        *(uint2*)&s_zn[pl][lq * 4] = make_uint2(d0, d1);
    }
    // MFMA: A = WkvT (features = m), B = zn tokens (n). Wave w owns tokens w*16..+15.
    // No __syncthreads needed: wave reads exactly the LDS rows it wrote.
    int mrow = lane & 15, quad = lane >> 4;
    bf16x8_t bfrag[4];
    #pragma unroll
    for (int kc = 0; kc < 4; ++kc)
        bfrag[kc] = *(const bf16x8_t*)&s_zn[w * 16 + mrow][kc * 32 + quad * 8];
    long tk = base + w * 16 + mrow;        // D col n = lane&15 -> token; D row = feature
    #pragma unroll
    for (int ft = 0; ft < 16; ++ft) {
        f32x4_t acc = {0.f, 0.f, 0.f, 0.f};
        const unsigned short* ap = WkvT + (ft * 16 + mrow) * 128 + quad * 8;
        #pragma unroll
        for (int kc = 0; kc < 4; ++kc) {
            bf16x8_t a = *(const bf16x8_t*)(ap + kc * 32);
            acc = __builtin_amdgcn_mfma_f32_16x16x32_bf16(a, bfrag[kc], acc, 0, 0, 0);
        }
        unsigned d0 = (unsigned)f2bf(acc[0]) | ((unsigned)f2bf(acc[1]) << 16);
        unsigned d1 = (unsigned)f2bf(acc[2]) | ((unsigned)f2bf(acc[3]) << 16);
        int f0 = ft * 16 + quad * 4;
        *(uint2*)(kv + tk * 256 + f0) = make_uint2(d0, d1);
    }
}

// ---------------- K7: per-cell attention — wave-per-token, no LDS, no barriers ----------------
// Lane layout: lane l -> head h=l>>3, sub j'=l&7, features f=2l,2l+1 (h*16+2j' == 2l).
__global__ __launch_bounds__(256) void k_attn(const float* __restrict__ x,
        const int* __restrict__ cnt, const int* __restrict__ ptIdx,
        const float* __restrict__ mm, const unsigned short* __restrict__ kv,
        const float* __restrict__ ws_q, const float* __restrict__ ws_vg,
        const float* __restrict__ ws_d0,
        const float* __restrict__ kW1, const float* __restrict__ kb1,
        const float* __restrict__ kW2, const float* __restrict__ kb2,
        unsigned short* __restrict__ outA, float* __restrict__ xout) {
    int t = threadIdx.x;
    int l = t & 63;
    int bm = blockIdx.x * 4 + (t >> 6);   // one wave per (b,cell) token
    int b = bm >> 10;
    int h = l >> 3, jp = l & 7;

    float mn0 = mm[0], mn1 = mm[1], mx0 = mm[2], mx1 = mm[3];
    int i0 = (bm & 1023) >> 5, i1 = bm & 31;
    float st0 = (mx0 - mn0) / 31.0f, st1 = (mx1 - mn1) / 31.0f;
    float xg0 = (i0 == 31) ? mx0 : mn0 + i0 * st0;
    float xg1 = (i1 == 31) ? mx1 : mn1 + i1 * st1;
    int c = min(cnt[bm], NP);

    // per-lane constants
    float q0 = ws_q[2 * l] * 0.25f, q1 = ws_q[2 * l + 1] * 0.25f;  // fold 1/sqrt(hd)
    float vg0 = ws_vg[2 * l], vg1 = ws_vg[2 * l + 1];
    float ag = ws_d0[h];          // grid-token score (already scaled + kb)
    float kb2h = kb2[h];
    float w1a[4], w1b[4], b1v[4], w2v[4];
    #pragma unroll
    for (int m = 0; m < 4; ++m) {
        int j = jp + 8 * m;
        w1a[m] = kW1[j]; w1b[m] = kW1[32 + j]; b1v[m] = kb1[j]; w2v[m] = kW2[j * 8 + h];
    }

    // per-key lane-resident data (lane k holds key k's idx and coords)
    int idxreg = 0; float x0r = 0.f, x1r = 0.f;
    if (l < c) {
        idxreg = ptIdx[bm * NP + l];
        float2 xv = ((const float2*)x)[(size_t)b * NN + idxreg];
        x0r = xv.x; x1r = xv.y;
    }

    unsigned vreg[NP];
    float areg[4];
    #pragma unroll
    for (int k = 0; k < NP; ++k) vreg[k] = 0u;
    areg[0] = areg[1] = areg[2] = areg[3] = -1e30f;

    #pragma unroll
    for (int key = 0; key < NP; ++key) {
        if (key < c) {                       // wave-uniform branch
            int idxk = __shfl(idxreg, key);
            const unsigned* rowp = (const unsigned*)kv + ((size_t)(b * NN + idxk) << 7);
            unsigned kw = rowp[l];           // k features 2l,2l+1  (coalesced 256B)
            vreg[key] = rowp[64 + l];        // v features 2l,2l+1
            float d0 = __shfl(x0r, key) - xg0;
            float d1 = __shfl(x1r, key) - xg1;
            float part = q0 * bflo(kw) + q1 * bfhi(kw);
            #pragma unroll
            for (int m = 0; m < 4; ++m) {    // kernel-bias MLP partial (j = jp+8m)
                float hj = fmaf(d0, w1a[m], fmaf(d1, w1b[m], b1v[m]));
                hj = fmaxf(hj, 0.f);
                part = fmaf(hj, w2v[m], part);
            }
            part += __shfl_xor(part, 1);
            part += __shfl_xor(part, 2);
            part += __shfl_xor(part, 4);     // sum over j' -> full dot + kb
            float score = part + kb2h;
            if (jp == (key & 7)) areg[key >> 3] = score;
        }
    }

    // softmax over {grid, keys} per head (within 8-lane group)
    float mx = fmaxf(fmaxf(areg[0], areg[1]), fmaxf(areg[2], areg[3]));
    mx = fmaxf(mx, ag);
    mx = fmaxf(mx, __shfl_xor(mx, 1));
    mx = fmaxf(mx, __shfl_xor(mx, 2));
    mx = fmaxf(mx, __shfl_xor(mx, 4));
    float e0 = __expf(areg[0] - mx), e1 = __expf(areg[1] - mx);
    float e2 = __expf(areg[2] - mx), e3 = __expf(areg[3] - mx);
    float eg = __expf(ag - mx);
    float s = e0 + e1 + e2 + e3;
    s += __shfl_xor(s, 1);
    s += __shfl_xor(s, 2);
    s += __shfl_xor(s, 4);
    s += eg;                                  // eg uniform within group
    float inv = 1.0f / s;

    // out = A @ v   (lane owns features 2l,2l+1 of head h)
    float accA = eg * inv * vg0, accB = eg * inv * vg1;
    #pragma unroll
    for (int key = 0; key < NP; ++key) {
        if (key < c) {
            int src = (l & 56) | (key & 7);
            float em = (key >> 3) == 0 ? e0 : (key >> 3) == 1 ? e1 : (key >> 3) == 2 ? e2 : e3;
            float a = __shfl(em, src) * inv;
            unsigned vw = vreg[key];
            accA = fmaf(a, bflo(vw), accA);
            accB = fmaf(a, bfhi(vw), accB);
        }
    }
    unsigned ow = ((unsigned)f2bf(accB) << 16) | (unsigned)f2bf(accA);
    ((unsigned*)outA)[(size_t)bm * 64 + l] = ow;

    // x_new = mean_h(A) @ joint_x
    float s0 = e0 * inv, s1 = e1 * inv, s2 = e2 * inv, s3 = e3 * inv, sg = eg * inv;
    #pragma unroll
    for (int m = 8; m <= 32; m <<= 1) {       // reduce over heads
        s0 += __shfl_xor(s0, m); s1 += __shfl_xor(s1, m);
        s2 += __shfl_xor(s2, m); s3 += __shfl_xor(s3, m);
        sg += __shfl_xor(sg, m);
    }
    float px0 = 0.f, px1 = 0.f;
    {
        float xx0, xx1;
        xx0 = __shfl(x0r, jp);      xx1 = __shfl(x1r, jp);
        px0 = fmaf(s0, xx0, px0);   px1 = fmaf(s0, xx1, px1);
        xx0 = __shfl(x0r, jp + 8);  xx1 = __shfl(x1r, jp + 8);
        px0 = fmaf(s1, xx0, px0);   px1 = fmaf(s1, xx1, px1);
        xx0 = __shfl(x0r, jp + 16); xx1 = __shfl(x1r, jp + 16);
        px0 = fmaf(s2, xx0, px0);   px1 = fmaf(s2, xx1, px1);
        xx0 = __shfl(x0r, jp + 24); xx1 = __shfl(x1r, jp + 24);
        px0 = fmaf(s3, xx0, px0);   px1 = fmaf(s3, xx1, px1);
    }
    px0 += __shfl_xor(px0, 1); px1 += __shfl_xor(px1, 1);
    px0 += __shfl_xor(px0, 2); px1 += __shfl_xor(px1, 2);
    px0 += __shfl_xor(px0, 4); px1 += __shfl_xor(px1, 4);
    if (l == 0) {
        xout[bm * 2]     = (px0 + sg * xg0) * 0.125f;
        xout[bm * 2 + 1] = (px1 + sg * xg1) * 0.125f;
    }
}

// ---------------- K8: z_new = zq + out@Wo + bo; + FFN(LN2) ----------------
__global__ __launch_bounds__(256) void k_ffn(const unsigned short* __restrict__ outA,
        const float* __restrict__ latent, const float* __restrict__ bo,
        const float* __restrict__ ln2_g, const float* __restrict__ ln2_b,
        const float* __restrict__ fb1, const float* __restrict__ fb2,
        const unsigned short* __restrict__ WoT, const unsigned short* __restrict__ fW1T,
        const unsigned short* __restrict__ fW2T, float* __restrict__ zout) {
    __shared__ unsigned short s_a[32][136];
    __shared__ unsigned short s_a2[32][136];
    __shared__ float s_z[32][128];
    __shared__ float s_lat[128], s_g2[128], s_b2[128], s_fb1v[128], s_fb2v[128];
    int t = threadIdx.x;
    long base = (long)blockIdx.x * 32;
    if (t < 128) {
        s_lat[t] = latent[t] + bo[t];
        s_g2[t] = ln2_g[t]; s_b2[t] = ln2_b[t];
        s_fb1v[t] = fb1[t]; s_fb2v[t] = fb2[t];
    }
    {
        const uint4* src4 = (const uint4*)((const uint32_t*)outA + base * 64);
        for (int i = t; i < 512; i += 256) {
            int row = i >> 4, off = (i & 15) * 8;
            *(uint4*)&s_a[row][off] = src4[i];
        }
    }
    __syncthreads();
    int w = t >> 6, lane = t & 63;
    int mrow = lane & 15, quad = lane >> 4;
    int rt = w >> 1;
    int ct0 = (w & 1) * 4;
    { // GEMM1: out @ Wo  (+ latent + bo)
        bf16x8_t a[4];
        for (int kc = 0; kc < 4; ++kc)
            a[kc] = *(const bf16x8_t*)&s_a[rt * 16 + mrow][kc * 32 + quad * 8];
        for (int cc = 0; cc < 4; ++cc) {
            int ct = ct0 + cc;
            f32x4_t acc = {0.f, 0.f, 0.f, 0.f};
            const unsigned short* bp = WoT + (ct * 16 + mrow) * 128 + quad * 8;
            for (int kc = 0; kc < 4; ++kc)
                acc = __builtin_amdgcn_mfma_f32_16x16x32_bf16(a[kc], *(const bf16x8_t*)(bp + kc * 32), acc, 0, 0, 0);
            for (int r = 0; r < 4; ++r) {
                int row = rt * 16 + quad * 4 + r, f = ct * 16 + mrow;
                s_z[row][f] = acc[r] + s_lat[f];
            }
        }
    }
    __syncthreads();
    for (int i = 0; i < 8; ++i) {   // LN2 per row
        int row = w * 8 + i;
        float v0 = s_z[row][lane], v1 = s_z[row][lane + 64];
        float s = v0 + v1;
        for (int m = 32; m > 0; m >>= 1) s += __shfl_xor(s, m);
        float mu = s * (1.0f / 128.0f);
        float d0 = v0 - mu, d1 = v1 - mu;
        float q = d0 * d0 + d1 * d1;
        for (int m = 32; m > 0; m >>= 1) q += __shfl_xor(q, m);
        float rstd = rsqrtf(q * (1.0f / 128.0f) + 1e-5f);
        s_a2[row][lane]      = f2bf(d0 * rstd * s_g2[lane] + s_b2[lane]);
        s_a2[row][lane + 64] = f2bf(d1 * rstd * s_g2[lane + 64] + s_b2[lane + 64]);
    }
    __syncthreads();
    { // GEMM2: relu(LN2 @ fW1 + fb1) -> s_a (reuse)
        bf16x8_t a[4];
        for (int kc = 0; kc < 4; ++kc)
            a[kc] = *(const bf16x8_t*)&s_a2[rt * 16 + mrow][kc * 32 + quad * 8];
        for (int cc = 0; cc < 4; ++cc) {
            int ct = ct0 + cc;
            f32x4_t acc = {0.f, 0.f, 0.f, 0.f};
            const unsigned short* bp = fW1T + (ct * 16 + mrow) * 128 + quad * 8;
            for (int kc = 0; kc < 4; ++kc)
                acc = __builtin_amdgcn_mfma_f32_16x16x32_bf16(a[kc], *(const bf16x8_t*)(bp + kc * 32), acc, 0, 0, 0);
            for (int r = 0; r < 4; ++r) {
                int row = rt * 16 + quad * 4 + r, f = ct * 16 + mrow;
                s_a[row][f] = f2bf(fmaxf(acc[r] + s_fb1v[f], 0.f));
            }
        }
    }
    __syncthreads();
    { // GEMM3: z + h1 @ fW2 + fb2 -> d_out
        bf16x8_t a[4];
        for (int kc = 0; kc < 4; ++kc)
            a[kc] = *(const bf16x8_t*)&s_a[rt * 16 + mrow][kc * 32 + quad * 8];
        for (int cc = 0; cc < 4; ++cc) {
            int ct = ct0 + cc;
            f32x4_t acc = {0.f, 0.f, 0.f, 0.f};
            const unsigned short* bp = fW2T + (ct * 16 + mrow) * 128 + quad * 8;
            for (int kc = 0; kc < 4; ++kc)
                acc = __builtin_amdgcn_mfma_f32_16x16x32_bf16(a[kc], *(const bf16x8_t*)(bp + kc * 32), acc, 0, 0, 0);
            for (int r = 0; r < 4; ++r) {
                int row = rt * 16 + quad * 4 + r, f = ct * 16 + mrow;
                zout[(base + row) * 128 + f] = s_z[row][f] + acc[r] + s_fb2v[f];
            }
        }
    }
}

extern "C" void kernel_launch(void* const* d_in, const int* in_sizes, int n_in,
                              void* d_out, int out_size, void* d_ws, size_t ws_size,
                              hipStream_t stream) {
    const float* x     = (const float*)d_in[0];
    const float* z     = (const float*)d_in[1];
    const float* latent= (const float*)d_in[6];
    const float* Wq    = (const float*)d_in[7];
    const float* Wk    = (const float*)d_in[8];
    const float* Wv    = (const float*)d_in[9];
    const float* Wo    = (const float*)d_in[10];
    const float* bo    = (const float*)d_in[11];
    const float* kW1   = (const float*)d_in[12];
    const float* kb1   = (const float*)d_in[13];
    const float* kW2   = (const float*)d_in[14];
    const float* kb2   = (const float*)d_in[15];
    const float* lnq_g = (const float*)d_in[16];
    const float* lnq_b = (const float*)d_in[17];
    const float* lnk_g = (const float*)d_in[18];
    const float* lnk_b = (const float*)d_in[19];
    const float* ln2_g = (const float*)d_in[20];
    const float* ln2_b = (const float*)d_in[21];
    const float* fW1   = (const float*)d_in[22];
    const float* fb1   = (const float*)d_in[23];
    const float* fW2   = (const float*)d_in[24];
    const float* fb2   = (const float*)d_in[25];

    uint8_t* ws = (uint8_t*)d_ws;
    float* mm     = (float*)(ws + WS_MM);
    float* ws_d0  = (float*)(ws + WS_D0);
    float* ws_q   = (float*)(ws + WS_Q);
    float* ws_vg  = (float*)(ws + WS_VG);
    float4* part  = (float4*)(ws + WS_PART);
    int* cnt      = (int*)(ws + WS_CNT);
    int* cell     = (int*)(ws + WS_CELL);
    int* ptIdx    = (int*)(ws + WS_PIDX);
    unsigned short* WkvT = (unsigned short*)(ws + WS_WKVT);
    unsigned short* WoT  = (unsigned short*)(ws + WS_WOT);
    unsigned short* fW1T = (unsigned short*)(ws + WS_FW1T);
    unsigned short* fW2T = (unsigned short*)(ws + WS_FW2T);
    unsigned short* outA = (unsigned short*)(ws + WS_OUTA);
    unsigned short* kv   = (unsigned short*)(ws + WS_KV);

    float* xout = (float*)d_out;            // [B,32,32,2]  = 16384
    float* zout = (float*)d_out + 16384;    // [B,32,32,128]

    k_setup <<<85,   256, 0, stream>>>(x, Wk, Wv, Wo, fW1, fW2, latent, Wq,
                                       lnq_g, lnq_b, lnk_g, lnk_b, kb1, kW2, kb2,
                                       cnt, WkvT, WoT, fW1T, fW2T, ws_q, ws_vg, ws_d0, part);
    k_bin   <<<256,  256, 0, stream>>>(x, part, mm, cell, cnt, ptIdx);
    k_kvfix <<<1152, 256, 0, stream>>>(z, lnk_g, lnk_b, WkvT, kv, cell, cnt, ptIdx);
    k_attn  <<<2048, 256, 0, stream>>>(x, cnt, ptIdx, mm, kv, ws_q, ws_vg, ws_d0,
                                       kW1, kb1, kW2, kb2, outA, xout);
    k_ffn   <<<256,  256, 0, stream>>>(outA, latent, bo, ln2_g, ln2_b, fb1, fb2,
                                       WoT, fW1T, fW2T, zout);
}

// Round 7
// 183.279 us; speedup vs baseline: 1.7165x; 1.1024x over previous
//
#include <hip/hip_runtime.h>
#include <stdint.h>

// Problem constants (fixed by the harness)
#define NB 8
#define NN 8192
#define NE 128
#define NH 8
#define NHD 16
#define NKH 32
#define NFF 128
#define NG 32
#define NM 1024          // NG*NG
#define NP 32
#define NT 8192          // NB*NM
#define NPTS 65536       // NB*NN

typedef __attribute__((ext_vector_type(8))) short bf16x8_t;
typedef __attribute__((ext_vector_type(4))) float f32x4_t;

// ---- workspace layout (bytes) ----
#define WS_MM      0         // 4 f32 (mn0,mn1,mx0,mx1) written by k_bin block 0
#define WS_D0      64        // 8 f32: grid-token dots (q.kg/4 + kb0)
#define WS_Q       128       // 128 f32
#define WS_VG      640       // 128 f32
#define WS_PART    1152      // 32 x float4 min/max partials
#define WS_CNT     2048      // 8192 i32
#define WS_CELL    34816     // 65536 i32
#define WS_PIDX    296960    // 8192*32 i32
#define WS_WKVT    1345536   // 256*128 ushort (bf16), [n][k], n<128 = Wk cols, else Wv
#define WS_WOT     1411072   // 128*128 ushort
#define WS_FW1T    1443840   // 128*128 ushort
#define WS_FW2T    1476608   // 128*128 ushort
#define WS_OUTA    1509376   // 8192*128 ushort (attention out, bf16 row-major)
#define WS_KV      3606528   // 65536*256 ushort ([point][0:128]=k,[128:256]=v)

__device__ __forceinline__ unsigned short f2bf(float f) {  // RNE
    unsigned u = __float_as_uint(f);
    u += 0x7FFFu + ((u >> 16) & 1u);
    return (unsigned short)(u >> 16);
}
__device__ __forceinline__ float bf2f(unsigned short h) {
    return __uint_as_float(((unsigned)h) << 16);
}
__device__ __forceinline__ float bflo(unsigned w) { return __uint_as_float(w << 16); }
__device__ __forceinline__ float bfhi(unsigned w) { return __uint_as_float(w & 0xFFFF0000u); }

// ---------------- K_setup: tile-transpose pack + init + precompute + minmax ----------------
__global__ __launch_bounds__(256) void k_setup(
        const float* __restrict__ x,
        const float* __restrict__ Wk, const float* __restrict__ Wv, const float* __restrict__ Wo,
        const float* __restrict__ fW1, const float* __restrict__ fW2,
        const float* __restrict__ latent, const float* __restrict__ Wq,
        const float* __restrict__ lnq_g, const float* __restrict__ lnq_b,
        const float* __restrict__ lnk_g, const float* __restrict__ lnk_b,
        const float* __restrict__ kb1, const float* __restrict__ kW2, const float* __restrict__ kb2,
        int* __restrict__ cnt,
        unsigned short* __restrict__ WkvT, unsigned short* __restrict__ WoT,
        unsigned short* __restrict__ fW1T, unsigned short* __restrict__ fW2T,
        float* __restrict__ ws_q, float* __restrict__ ws_vg, float* __restrict__ ws_d0,
        float4* __restrict__ part) {
    int blk = blockIdx.x;
    int t = threadIdx.x;
    if (blk < 20) {
        __shared__ float s_t[64][65];
        const float* src; unsigned short* dst;
        int n0, k0, srcN0;
        if (blk < 8) {
            int tn = blk >> 1, tk = blk & 1;
            n0 = tn * 64; k0 = tk * 64;
            dst = WkvT;
            if (n0 < 128) { src = Wk; srcN0 = n0; }
            else          { src = Wv; srcN0 = n0 - 128; }
        } else {
            int m = (blk - 8) >> 2, s4 = (blk - 8) & 3;
            int tn = s4 >> 1, tk = s4 & 1;
            n0 = tn * 64; k0 = tk * 64; srcN0 = n0;
            src = (m == 0) ? Wo : (m == 1) ? fW1 : fW2;
            dst = (m == 0) ? WoT : (m == 1) ? fW1T : fW2T;
        }
        int tx = t & 63, ty = t >> 6;
        #pragma unroll
        for (int r = 0; r < 16; ++r) {
            int kr = r * 4 + ty;
            s_t[kr][tx] = src[(k0 + kr) * 128 + srcN0 + tx];
        }
        __syncthreads();
        #pragma unroll
        for (int r = 0; r < 16; ++r) {
            int nr = r * 4 + ty;
            dst[(n0 + nr) * 128 + k0 + tx] = f2bf(s_t[tx][nr]);
        }
    } else if (blk < 52) {
        int idx = (blk - 20) * 256 + t;   // exactly 8192
        cnt[idx] = 0;
    } else if (blk == 52) {
        __shared__ float s_qn[128], s_kn[128], s_q[128], s_kg[128];
        __shared__ float s_mu, s_rstd;
        if (t < 64) {
            float v0 = latent[t], v1 = latent[t + 64];
            float s = v0 + v1;
            for (int m = 32; m > 0; m >>= 1) s += __shfl_xor(s, m);
            float mu = s * (1.0f / 128.0f);
            float d0 = v0 - mu, d1 = v1 - mu;
            float q = d0 * d0 + d1 * d1;
            for (int m = 32; m > 0; m >>= 1) q += __shfl_xor(q, m);
            if (t == 0) { s_mu = mu; s_rstd = rsqrtf(q * (1.0f / 128.0f) + 1e-5f); }
        }
        __syncthreads();
        if (t < 128) {
            float nv = (latent[t] - s_mu) * s_rstd;
            s_qn[t] = nv * lnq_g[t] + lnq_b[t];
            s_kn[t] = nv * lnk_g[t] + lnk_b[t];
        }
        __syncthreads();
        if (t < 128) {
            float aq = 0.f, ak = 0.f, av = 0.f;
            for (int e = 0; e < 128; ++e) {
                aq += s_qn[e] * Wq[e * 128 + t];
                ak += s_kn[e] * Wk[e * 128 + t];
                av += s_kn[e] * Wv[e * 128 + t];
            }
            s_q[t] = aq; s_kg[t] = ak;
            ws_q[t] = aq; ws_vg[t] = av;
        }
        __syncthreads();
        if (t < 8) {
            float acc = 0.f;
            for (int d = 0; d < 16; ++d) acc += s_q[t * 16 + d] * s_kg[t * 16 + d];
            float kb0 = kb2[t];
            for (int j = 0; j < 32; ++j) kb0 += fmaxf(kb1[j], 0.f) * kW2[j * 8 + t];
            ws_d0[t] = acc * 0.25f + kb0;
        }
    } else {
        __shared__ float s_red[4][4];
        int pb = blk - 53;                 // 0..31
        const float4* xp = (const float4*)x + pb * 1024;
        float mn0 = 1e30f, mx0 = -1e30f, mn1 = 1e30f, mx1 = -1e30f;
        #pragma unroll
        for (int it = 0; it < 4; ++it) {
            float4 v = xp[it * 256 + t];    // two points: (x,y),(z,w)
            mn0 = fminf(mn0, fminf(v.x, v.z)); mx0 = fmaxf(mx0, fmaxf(v.x, v.z));
            mn1 = fminf(mn1, fminf(v.y, v.w)); mx1 = fmaxf(mx1, fmaxf(v.y, v.w));
        }
        #pragma unroll
        for (int m = 32; m > 0; m >>= 1) {
            mn0 = fminf(mn0, __shfl_xor(mn0, m)); mx0 = fmaxf(mx0, __shfl_xor(mx0, m));
            mn1 = fminf(mn1, __shfl_xor(mn1, m)); mx1 = fmaxf(mx1, __shfl_xor(mx1, m));
        }
        int w = t >> 6;
        if ((t & 63) == 0) {
            s_red[w][0] = mn0; s_red[w][1] = mn1; s_red[w][2] = mx0; s_red[w][3] = mx1;
        }
        __syncthreads();
        if (t == 0) {
            float a0 = fminf(fminf(s_red[0][0], s_red[1][0]), fminf(s_red[2][0], s_red[3][0]));
            float a1 = fminf(fminf(s_red[0][1], s_red[1][1]), fminf(s_red[2][1], s_red[3][1]));
            float b0 = fmaxf(fmaxf(s_red[0][2], s_red[1][2]), fmaxf(s_red[2][2], s_red[3][2]));
            float b1 = fmaxf(fmaxf(s_red[0][3], s_red[1][3]), fmaxf(s_red[2][3], s_red[3][3]));
            part[pb] = make_float4(a0, a1, b0, b1);
        }
    }
}

// ---------------- K2: cell assignment + unordered binning (+ mm publish) ----------------
__global__ __launch_bounds__(256) void k_bin(const float* __restrict__ x,
        const float4* __restrict__ part, float* __restrict__ mm,
        int* __restrict__ cell, int* __restrict__ cnt, int* __restrict__ ptIdx) {
    int t = threadIdx.x;
    int l = t & 63;
    float mn0 = 1e30f, mn1 = 1e30f, mx0 = -1e30f, mx1 = -1e30f;
    if (l < 32) { float4 p = part[l]; mn0 = p.x; mn1 = p.y; mx0 = p.z; mx1 = p.w; }
    #pragma unroll
    for (int m = 32; m > 0; m >>= 1) {
        mn0 = fminf(mn0, __shfl_xor(mn0, m)); mx0 = fmaxf(mx0, __shfl_xor(mx0, m));
        mn1 = fminf(mn1, __shfl_xor(mn1, m)); mx1 = fmaxf(mx1, __shfl_xor(mx1, m));
    }
    if (blockIdx.x == 0 && t == 0) {
        mm[0] = mn0; mm[1] = mn1; mm[2] = mx0; mm[3] = mx1;
    }
    int i = blockIdx.x * 256 + t;  // 65536
    float st0 = (mx0 - mn0) / 31.0f, st1 = (mx1 - mn1) / 31.0f;  // matches jnp exactly
    float2 xv = ((const float2*)x)[i];
    int i0 = (int)rintf((xv.x - mn0) / st0); i0 = min(max(i0, 0), 31);
    int i1 = (int)rintf((xv.y - mn1) / st1); i1 = min(max(i1, 0), 31);
    int c = i0 * 32 + i1;
    cell[i] = c;
    int bb = i >> 13;
    int slot = atomicAdd(&cnt[bb * NM + c], 1);
    if (slot < NP) ptIdx[(bb * NM + c) * NP + slot] = i & (NN - 1);
}

// ---------------- K6: LN(z) + K/V projection; W-fragments register-cached ----------------
// + overflow fixup merged (blocks >= 1024)
__global__ __launch_bounds__(256) void k_kvfix(const float* __restrict__ z,
        const float* __restrict__ lnk_g, const float* __restrict__ lnk_b,
        const unsigned short* __restrict__ WkvT, unsigned short* __restrict__ kv,
        const int* __restrict__ cell, int* __restrict__ cnt, int* __restrict__ ptIdx) {
    int t = threadIdx.x;
    if (blockIdx.x >= 1024) {
        int wave = (blockIdx.x - 1024) * 4 + (t >> 6);   // 0..511
        int lane = t & 63;
        int wbase = wave * 16;
        int cval = (lane < 16) ? cnt[wbase + lane] : 0;
        unsigned long long ovf = __ballot(cval > NP);
        while (ovf) {
            int s = __ffsll((long long)ovf) - 1;
            ovf &= ovf - 1;
            int wid = wbase + s;
            int b = wid >> 10, mycell = wid & 1023;
            const int* cb = cell + b * NN;
            int run = 0;
            for (int ch = 0; ch < NN / 64 && run < NP; ++ch) {
                int n = ch * 64 + lane;
                bool match = (cb[n] == mycell);
                unsigned long long mask = __ballot(match);
                if (match) {
                    int rank = run + __popcll(mask & ((1ull << lane) - 1ull));
                    if (rank < NP) ptIdx[wid * NP + rank] = n;
                }
                run += __popcll(mask);
            }
            if (lane == 0) cnt[wid] = NP;
        }
        return;
    }
    // ---- kv path: 64 tokens per block ----
    __shared__ unsigned short s_zn[64][136];
    int w = t >> 6, lane = t & 63;
    long base = (long)blockIdx.x * 64;
    int sub = lane >> 5;
    int lq = lane & 31;
    int mrow = lane & 15, quad = lane >> 4;

    // Prefetch this wave's W-fragments FIRST (independent of LDS): ft = w*4+j.
    // 16 frags x 4 VGPR = 64 VGPRs, loaded once per block instead of once per
    // token-tile (cuts WkvT L2 traffic 4x; this was the invariant 44us term).
    bf16x8_t afrag[4][4];
    #pragma unroll
    for (int j = 0; j < 4; ++j) {
        int ft = w * 4 + j;
        const unsigned short* ap = WkvT + (ft * 16 + mrow) * 128 + quad * 8;
        #pragma unroll
        for (int kc = 0; kc < 4; ++kc)
            afrag[j][kc] = *(const bf16x8_t*)(ap + kc * 32);
    }

    // LN: 2 rows/iter, 32 lanes/row, hoisted loads
    float4 g4 = ((const float4*)lnk_g)[lq];
    float4 b4 = ((const float4*)lnk_b)[lq];
    float4 v[8];
    #pragma unroll
    for (int i = 0; i < 8; ++i) {
        int pl = w * 16 + i * 2 + sub;
        v[i] = ((const float4*)z)[(base + pl) * 32 + lq];
    }
    #pragma unroll
    for (int i = 0; i < 8; ++i) {
        int pl = w * 16 + i * 2 + sub;
        float sum = v[i].x + v[i].y + v[i].z + v[i].w;
        float ssq = v[i].x * v[i].x + v[i].y * v[i].y + v[i].z * v[i].z + v[i].w * v[i].w;
        #pragma unroll
        for (int m = 1; m < 32; m <<= 1) {
            sum += __shfl_xor(sum, m);
            ssq += __shfl_xor(ssq, m);
        }
        float mu = sum * (1.0f / 128.0f);
        float var = fmaxf(ssq * (1.0f / 128.0f) - mu * mu, 0.0f);
        float rstd = rsqrtf(var + 1e-5f);
        float n0 = (v[i].x - mu) * rstd * g4.x + b4.x;
        float n1 = (v[i].y - mu) * rstd * g4.y + b4.y;
        float n2 = (v[i].z - mu) * rstd * g4.z + b4.z;
        float n3 = (v[i].w - mu) * rstd * g4.w + b4.w;
        unsigned d0 = (unsigned)f2bf(n0) | ((unsigned)f2bf(n1) << 16);
        unsigned d1 = (unsigned)f2bf(n2) | ((unsigned)f2bf(n3) << 16);
        *(uint2*)&s_zn[pl][lq * 4] = make_uint2(d0, d1);
    }
    __syncthreads();   // waves now consume all rows

    // Loop over 4 token-tiles; wave covers its 64 features for all 64 tokens.
    #pragma unroll
    for (int tau = 0; tau < 4; ++tau) {
        bf16x8_t bfrag[4];
        #pragma unroll
        for (int kc = 0; kc < 4; ++kc)
            bfrag[kc] = *(const bf16x8_t*)&s_zn[tau * 16 + mrow][kc * 32 + quad * 8];
        long tk = base + tau * 16 + mrow;   // D col n = lane&15 -> token
        #pragma unroll
        for (int j = 0; j < 4; ++j) {
            int ft = w * 4 + j;
            f32x4_t acc = {0.f, 0.f, 0.f, 0.f};
            #pragma unroll
            for (int kc = 0; kc < 4; ++kc)
                acc = __builtin_amdgcn_mfma_f32_16x16x32_bf16(afrag[j][kc], bfrag[kc], acc, 0, 0, 0);
            unsigned d0 = (unsigned)f2bf(acc[0]) | ((unsigned)f2bf(acc[1]) << 16);
            unsigned d1 = (unsigned)f2bf(acc[2]) | ((unsigned)f2bf(acc[3]) << 16);
            *(uint2*)(kv + tk * 256 + ft * 16 + quad * 4) = make_uint2(d0, d1);
        }
    }
}

// ---------------- K7: per-cell attention — wave-per-token, no LDS, no barriers ----------------
__global__ __launch_bounds__(256) void k_attn(const float* __restrict__ x,
        const int* __restrict__ cnt, const int* __restrict__ ptIdx,
        const float* __restrict__ mm, const unsigned short* __restrict__ kv,
        const float* __restrict__ ws_q, const float* __restrict__ ws_vg,
        const float* __restrict__ ws_d0,
        const float* __restrict__ kW1, const float* __restrict__ kb1,
        const float* __restrict__ kW2, const float* __restrict__ kb2,
        unsigned short* __restrict__ outA, float* __restrict__ xout) {
    int t = threadIdx.x;
    int l = t & 63;
    int bm = blockIdx.x * 4 + (t >> 6);   // one wave per (b,cell) token
    int b = bm >> 10;
    int h = l >> 3, jp = l & 7;

    float mn0 = mm[0], mn1 = mm[1], mx0 = mm[2], mx1 = mm[3];
    int i0 = (bm & 1023) >> 5, i1 = bm & 31;
    float st0 = (mx0 - mn0) / 31.0f, st1 = (mx1 - mn1) / 31.0f;
    float xg0 = (i0 == 31) ? mx0 : mn0 + i0 * st0;
    float xg1 = (i1 == 31) ? mx1 : mn1 + i1 * st1;
    int c = min(cnt[bm], NP);

    float q0 = ws_q[2 * l] * 0.25f, q1 = ws_q[2 * l + 1] * 0.25f;
    float vg0 = ws_vg[2 * l], vg1 = ws_vg[2 * l + 1];
    float ag = ws_d0[h];
    float kb2h = kb2[h];
    float w1a[4], w1b[4], b1v[4], w2v[4];
    #pragma unroll
    for (int m = 0; m < 4; ++m) {
        int j = jp + 8 * m;
        w1a[m] = kW1[j]; w1b[m] = kW1[32 + j]; b1v[m] = kb1[j]; w2v[m] = kW2[j * 8 + h];
    }

    int idxreg = 0; float x0r = 0.f, x1r = 0.f;
    if (l < c) {
        idxreg = ptIdx[bm * NP + l];
        float2 xv = ((const float2*)x)[(size_t)b * NN + idxreg];
        x0r = xv.x; x1r = xv.y;
    }

    unsigned vreg[NP];
    float areg[4];
    #pragma unroll
    for (int k = 0; k < NP; ++k) vreg[k] = 0u;
    areg[0] = areg[1] = areg[2] = areg[3] = -1e30f;

    #pragma unroll
    for (int key = 0; key < NP; ++key) {
        if (key < c) {
            int idxk = __shfl(idxreg, key);
            const unsigned* rowp = (const unsigned*)kv + ((size_t)(b * NN + idxk) << 7);
            unsigned kw = rowp[l];
            vreg[key] = rowp[64 + l];
            float d0 = __shfl(x0r, key) - xg0;
            float d1 = __shfl(x1r, key) - xg1;
            float part = q0 * bflo(kw) + q1 * bfhi(kw);
            #pragma unroll
            for (int m = 0; m < 4; ++m) {
                float hj = fmaf(d0, w1a[m], fmaf(d1, w1b[m], b1v[m]));
                hj = fmaxf(hj, 0.f);
                part = fmaf(hj, w2v[m], part);
            }
            part += __shfl_xor(part, 1);
            part += __shfl_xor(part, 2);
            part += __shfl_xor(part, 4);
            float score = part + kb2h;
            if (jp == (key & 7)) areg[key >> 3] = score;
        }
    }

    float mx = fmaxf(fmaxf(areg[0], areg[1]), fmaxf(areg[2], areg[3]));
    mx = fmaxf(mx, ag);
    mx = fmaxf(mx, __shfl_xor(mx, 1));
    mx = fmaxf(mx, __shfl_xor(mx, 2));
    mx = fmaxf(mx, __shfl_xor(mx, 4));
    float e0 = __expf(areg[0] - mx), e1 = __expf(areg[1] - mx);
    float e2 = __expf(areg[2] - mx), e3 = __expf(areg[3] - mx);
    float eg = __expf(ag - mx);
    float s = e0 + e1 + e2 + e3;
    s += __shfl_xor(s, 1);
    s += __shfl_xor(s, 2);
    s += __shfl_xor(s, 4);
    s += eg;
    float inv = 1.0f / s;

    float accA = eg * inv * vg0, accB = eg * inv * vg1;
    #pragma unroll
    for (int key = 0; key < NP; ++key) {
        if (key < c) {
            int src = (l & 56) | (key & 7);
            float em = (key >> 3) == 0 ? e0 : (key >> 3) == 1 ? e1 : (key >> 3) == 2 ? e2 : e3;
            float a = __shfl(em, src) * inv;
            unsigned vw = vreg[key];
            accA = fmaf(a, bflo(vw), accA);
            accB = fmaf(a, bfhi(vw), accB);
        }
    }
    unsigned ow = ((unsigned)f2bf(accB) << 16) | (unsigned)f2bf(accA);
    ((unsigned*)outA)[(size_t)bm * 64 + l] = ow;

    float s0 = e0 * inv, s1 = e1 * inv, s2 = e2 * inv, s3 = e3 * inv, sg = eg * inv;
    #pragma unroll
    for (int m = 8; m <= 32; m <<= 1) {
        s0 += __shfl_xor(s0, m); s1 += __shfl_xor(s1, m);
        s2 += __shfl_xor(s2, m); s3 += __shfl_xor(s3, m);
        sg += __shfl_xor(sg, m);
    }
    float px0 = 0.f, px1 = 0.f;
    {
        float xx0, xx1;
        xx0 = __shfl(x0r, jp);      xx1 = __shfl(x1r, jp);
        px0 = fmaf(s0, xx0, px0);   px1 = fmaf(s0, xx1, px1);
        xx0 = __shfl(x0r, jp + 8);  xx1 = __shfl(x1r, jp + 8);
        px0 = fmaf(s1, xx0, px0);   px1 = fmaf(s1, xx1, px1);
        xx0 = __shfl(x0r, jp + 16); xx1 = __shfl(x1r, jp + 16);
        px0 = fmaf(s2, xx0, px0);   px1 = fmaf(s2, xx1, px1);
        xx0 = __shfl(x0r, jp + 24); xx1 = __shfl(x1r, jp + 24);
        px0 = fmaf(s3, xx0, px0);   px1 = fmaf(s3, xx1, px1);
    }
    px0 += __shfl_xor(px0, 1); px1 += __shfl_xor(px1, 1);
    px0 += __shfl_xor(px0, 2); px1 += __shfl_xor(px1, 2);
    px0 += __shfl_xor(px0, 4); px1 += __shfl_xor(px1, 4);
    if (l == 0) {
        xout[bm * 2]     = (px0 + sg * xg0) * 0.125f;
        xout[bm * 2 + 1] = (px1 + sg * xg1) * 0.125f;
    }
}

// ---------------- K8: z_new = zq + out@Wo + bo; + FFN(LN2) ----------------
__global__ __launch_bounds__(256) void k_ffn(const unsigned short* __restrict__ outA,
        const float* __restrict__ latent, const float* __restrict__ bo,
        const float* __restrict__ ln2_g, const float* __restrict__ ln2_b,
        const float* __restrict__ fb1, const float* __restrict__ fb2,
        const unsigned short* __restrict__ WoT, const unsigned short* __restrict__ fW1T,
        const unsigned short* __restrict__ fW2T, float* __restrict__ zout) {
    __shared__ unsigned short s_a[32][136];
    __shared__ unsigned short s_a2[32][136];
    __shared__ float s_z[32][128];
    __shared__ float s_lat[128], s_g2[128], s_b2[128], s_fb1v[128], s_fb2v[128];
    int t = threadIdx.x;
    long base = (long)blockIdx.x * 32;
    if (t < 128) {
        s_lat[t] = latent[t] + bo[t];
        s_g2[t] = ln2_g[t]; s_b2[t] = ln2_b[t];
        s_fb1v[t] = fb1[t]; s_fb2v[t] = fb2[t];
    }
    {
        const uint4* src4 = (const uint4*)((const uint32_t*)outA + base * 64);
        for (int i = t; i < 512; i += 256) {
            int row = i >> 4, off = (i & 15) * 8;
            *(uint4*)&s_a[row][off] = src4[i];
        }
    }
    __syncthreads();
    int w = t >> 6, lane = t & 63;
    int mrow = lane & 15, quad = lane >> 4;
    int rt = w >> 1;
    int ct0 = (w & 1) * 4;
    { // GEMM1: out @ Wo  (+ latent + bo)
        bf16x8_t a[4];
        for (int kc = 0; kc < 4; ++kc)
            a[kc] = *(const bf16x8_t*)&s_a[rt * 16 + mrow][kc * 32 + quad * 8];
        for (int cc = 0; cc < 4; ++cc) {
            int ct = ct0 + cc;
            f32x4_t acc = {0.f, 0.f, 0.f, 0.f};
            const unsigned short* bp = WoT + (ct * 16 + mrow) * 128 + quad * 8;
            for (int kc = 0; kc < 4; ++kc)
                acc = __builtin_amdgcn_mfma_f32_16x16x32_bf16(a[kc], *(const bf16x8_t*)(bp + kc * 32), acc, 0, 0, 0);
            for (int r = 0; r < 4; ++r) {
                int row = rt * 16 + quad * 4 + r, f = ct * 16 + mrow;
                s_z[row][f] = acc[r] + s_lat[f];
            }
        }
    }
    __syncthreads();
    for (int i = 0; i < 8; ++i) {   // LN2 per row
        int row = w * 8 + i;
        float v0 = s_z[row][lane], v1 = s_z[row][lane + 64];
        float s = v0 + v1;
        for (int m = 32; m > 0; m >>= 1) s += __shfl_xor(s, m);
        float mu = s * (1.0f / 128.0f);
        float d0 = v0 - mu, d1 = v1 - mu;
        float q = d0 * d0 + d1 * d1;
        for (int m = 32; m > 0; m >>= 1) q += __shfl_xor(q, m);
        float rstd = rsqrtf(q * (1.0f / 128.0f) + 1e-5f);
        s_a2[row][lane]      = f2bf(d0 * rstd * s_g2[lane] + s_b2[lane]);
        s_a2[row][lane + 64] = f2bf(d1 * rstd * s_g2[lane + 64] + s_b2[lane + 64]);
    }
    __syncthreads();
    { // GEMM2: relu(LN2 @ fW1 + fb1) -> s_a (reuse)
        bf16x8_t a[4];
        for (int kc = 0; kc < 4; ++kc)
            a[kc] = *(const bf16x8_t*)&s_a2[rt * 16 + mrow][kc * 32 + quad * 8];
        for (int cc = 0; cc < 4; ++cc) {
            int ct = ct0 + cc;
            f32x4_t acc = {0.f, 0.f, 0.f, 0.f};
            const unsigned short* bp = fW1T + (ct * 16 + mrow) * 128 + quad * 8;
            for (int kc = 0; kc < 4; ++kc)
                acc = __builtin_amdgcn_mfma_f32_16x16x32_bf16(a[kc], *(const bf16x8_t*)(bp + kc * 32), acc, 0, 0, 0);
            for (int r = 0; r < 4; ++r) {
                int row = rt * 16 + quad * 4 + r, f = ct * 16 + mrow;
                s_a[row][f] = f2bf(fmaxf(acc[r] + s_fb1v[f], 0.f));
            }
        }
    }
    __syncthreads();
    { // GEMM3: z + h1 @ fW2 + fb2 -> d_out
        bf16x8_t a[4];
        for (int kc = 0; kc < 4; ++kc)
            a[kc] = *(const bf16x8_t*)&s_a[rt * 16 + mrow][kc * 32 + quad * 8];
        for (int cc = 0; cc < 4; ++cc) {
            int ct = ct0 + cc;
            f32x4_t acc = {0.f, 0.f, 0.f, 0.f};
            const unsigned short* bp = fW2T + (ct * 16 + mrow) * 128 + quad * 8;
            for (int kc = 0; kc < 4; ++kc)
                acc = __builtin_amdgcn_mfma_f32_16x16x32_bf16(a[kc], *(const bf16x8_t*)(bp + kc * 32), acc, 0, 0, 0);
            for (int r = 0; r < 4; ++r) {
                int row = rt * 16 + quad * 4 + r, f = ct * 16 + mrow;
                zout[(base + row) * 128 + f] = s_z[row][f] + acc[r] + s_fb2v[f];
            }
        }
    }
}

extern "C" void kernel_launch(void* const* d_in, const int* in_sizes, int n_in,
                              void* d_out, int out_size, void* d_ws, size_t ws_size,
                              hipStream_t stream) {
    const float* x     = (const float*)d_in[0];
    const float* z     = (const float*)d_in[1];
    const float* latent= (const float*)d_in[6];
    const float* Wq    = (const float*)d_in[7];
    const float* Wk    = (const float*)d_in[8];
    const float* Wv    = (const float*)d_in[9];
    const float* Wo    = (const float*)d_in[10];
    const float* bo    = (const float*)d_in[11];
    const float* kW1   = (const float*)d_in[12];
    const float* kb1   = (const float*)d_in[13];
    const float* kW2   = (const float*)d_in[14];
    const float* kb2   = (const float*)d_in[15];
    const float* lnq_g = (const float*)d_in[16];
    const float* lnq_b = (const float*)d_in[17];
    const float* lnk_g = (const float*)d_in[18];
    const float* lnk_b = (const float*)d_in[19];
    const float* ln2_g = (const float*)d_in[20];
    const float* ln2_b = (const float*)d_in[21];
    const float* fW1   = (const float*)d_in[22];
    const float* fb1   = (const float*)d_in[23];
    const float* fW2   = (const float*)d_in[24];
    const float* fb2   = (const float*)d_in[25];

    uint8_t* ws = (uint8_t*)d_ws;
    float* mm     = (float*)(ws + WS_MM);
    float* ws_d0  = (float*)(ws + WS_D0);
    float* ws_q   = (float*)(ws + WS_Q);
    float* ws_vg  = (float*)(ws + WS_VG);
    float4* part  = (float4*)(ws + WS_PART);
    int* cnt      = (int*)(ws + WS_CNT);
    int* cell     = (int*)(ws + WS_CELL);
    int* ptIdx    = (int*)(ws + WS_PIDX);
    unsigned short* WkvT = (unsigned short*)(ws + WS_WKVT);
    unsigned short* WoT  = (unsigned short*)(ws + WS_WOT);
    unsigned short* fW1T = (unsigned short*)(ws + WS_FW1T);
    unsigned short* fW2T = (unsigned short*)(ws + WS_FW2T);
    unsigned short* outA = (unsigned short*)(ws + WS_OUTA);
    unsigned short* kv   = (unsigned short*)(ws + WS_KV);

    float* xout = (float*)d_out;            // [B,32,32,2]  = 16384
    float* zout = (float*)d_out + 16384;    // [B,32,32,128]

    k_setup <<<85,   256, 0, stream>>>(x, Wk, Wv, Wo, fW1, fW2, latent, Wq,
                                       lnq_g, lnq_b, lnk_g, lnk_b, kb1, kW2, kb2,
                                       cnt, WkvT, WoT, fW1T, fW2T, ws_q, ws_vg, ws_d0, part);
    k_bin   <<<256,  256, 0, stream>>>(x, part, mm, cell, cnt, ptIdx);
    k_kvfix <<<1152, 256, 0, stream>>>(z, lnk_g, lnk_b, WkvT, kv, cell, cnt, ptIdx);
    k_attn  <<<2048, 256, 0, stream>>>(x, cnt, ptIdx, mm, kv, ws_q, ws_vg, ws_d0,
                                       kW1, kb1, kW2, kb2, outA, xout);
    k_ffn   <<<256,  256, 0, stream>>>(outA, latent, bo, ln2_g, ln2_b, fb1, fb2,
                                       WoT, fW1T, fW2T, zout);
}

// Round 8
// 177.674 us; speedup vs baseline: 1.7706x; 1.0315x over previous
//
#include <hip/hip_runtime.h>
#include <stdint.h>

// Problem constants (fixed by the harness)
#define NB 8
#define NN 8192
#define NE 128
#define NH 8
#define NHD 16
#define NKH 32
#define NFF 128
#define NG 32
#define NM 1024          // NG*NG
#define NP 32
#define NT 8192          // NB*NM
#define NPTS 65536       // NB*NN

typedef __attribute__((ext_vector_type(8))) short bf16x8_t;
typedef __attribute__((ext_vector_type(4))) float f32x4_t;

// ---- workspace layout (bytes) ----
#define WS_MM      0         // 4 f32 (mn0,mn1,mx0,mx1) written by k_bin block 0
#define WS_D0      64        // 8 f32: grid-token dots (q.kg/4 + kb0)
#define WS_Q       128       // 128 f32
#define WS_VG      640       // 128 f32
#define WS_PART    1152      // 32 x float4 min/max partials
#define WS_CNT     2048      // 8192 i32
#define WS_CELL    34816     // 65536 i32
#define WS_PIDX    296960    // 8192*32 i32
#define WS_WKVT    1345536   // 256*128 ushort (bf16), [n][k], n<128 = Wk cols, else Wv
#define WS_WOT     1411072   // 128*128 ushort
#define WS_FW1T    1443840   // 128*128 ushort
#define WS_FW2T    1476608   // 128*128 ushort
#define WS_OUTA    1509376   // 8192*128 ushort (attention out, bf16 row-major)
#define WS_KV      3606528   // 65536*256 ushort ([point][0:128]=k,[128:256]=v)

__device__ __forceinline__ unsigned short f2bf(float f) {  // RNE
    unsigned u = __float_as_uint(f);
    u += 0x7FFFu + ((u >> 16) & 1u);
    return (unsigned short)(u >> 16);
}
__device__ __forceinline__ float bf2f(unsigned short h) {
    return __uint_as_float(((unsigned)h) << 16);
}
__device__ __forceinline__ float bflo(unsigned w) { return __uint_as_float(w << 16); }
__device__ __forceinline__ float bfhi(unsigned w) { return __uint_as_float(w & 0xFFFF0000u); }

// ---------------- K_setup: tile-transpose pack + init + precompute + minmax ----------------
__global__ __launch_bounds__(256) void k_setup(
        const float* __restrict__ x,
        const float* __restrict__ Wk, const float* __restrict__ Wv, const float* __restrict__ Wo,
        const float* __restrict__ fW1, const float* __restrict__ fW2,
        const float* __restrict__ latent, const float* __restrict__ Wq,
        const float* __restrict__ lnq_g, const float* __restrict__ lnq_b,
        const float* __restrict__ lnk_g, const float* __restrict__ lnk_b,
        const float* __restrict__ kb1, const float* __restrict__ kW2, const float* __restrict__ kb2,
        int* __restrict__ cnt,
        unsigned short* __restrict__ WkvT, unsigned short* __restrict__ WoT,
        unsigned short* __restrict__ fW1T, unsigned short* __restrict__ fW2T,
        float* __restrict__ ws_q, float* __restrict__ ws_vg, float* __restrict__ ws_d0,
        float4* __restrict__ part) {
    int blk = blockIdx.x;
    int t = threadIdx.x;
    if (blk < 20) {
        __shared__ float s_t[64][65];
        const float* src; unsigned short* dst;
        int n0, k0, srcN0;
        if (blk < 8) {
            int tn = blk >> 1, tk = blk & 1;
            n0 = tn * 64; k0 = tk * 64;
            dst = WkvT;
            if (n0 < 128) { src = Wk; srcN0 = n0; }
            else          { src = Wv; srcN0 = n0 - 128; }
        } else {
            int m = (blk - 8) >> 2, s4 = (blk - 8) & 3;
            int tn = s4 >> 1, tk = s4 & 1;
            n0 = tn * 64; k0 = tk * 64; srcN0 = n0;
            src = (m == 0) ? Wo : (m == 1) ? fW1 : fW2;
            dst = (m == 0) ? WoT : (m == 1) ? fW1T : fW2T;
        }
        int tx = t & 63, ty = t >> 6;
        #pragma unroll
        for (int r = 0; r < 16; ++r) {
            int kr = r * 4 + ty;
            s_t[kr][tx] = src[(k0 + kr) * 128 + srcN0 + tx];
        }
        __syncthreads();
        #pragma unroll
        for (int r = 0; r < 16; ++r) {
            int nr = r * 4 + ty;
            dst[(n0 + nr) * 128 + k0 + tx] = f2bf(s_t[tx][nr]);
        }
    } else if (blk < 52) {
        int idx = (blk - 20) * 256 + t;   // exactly 8192
        cnt[idx] = 0;
    } else if (blk == 52) {
        __shared__ float s_qn[128], s_kn[128], s_q[128], s_kg[128];
        __shared__ float s_mu, s_rstd;
        if (t < 64) {
            float v0 = latent[t], v1 = latent[t + 64];
            float s = v0 + v1;
            for (int m = 32; m > 0; m >>= 1) s += __shfl_xor(s, m);
            float mu = s * (1.0f / 128.0f);
            float d0 = v0 - mu, d1 = v1 - mu;
            float q = d0 * d0 + d1 * d1;
            for (int m = 32; m > 0; m >>= 1) q += __shfl_xor(q, m);
            if (t == 0) { s_mu = mu; s_rstd = rsqrtf(q * (1.0f / 128.0f) + 1e-5f); }
        }
        __syncthreads();
        if (t < 128) {
            float nv = (latent[t] - s_mu) * s_rstd;
            s_qn[t] = nv * lnq_g[t] + lnq_b[t];
            s_kn[t] = nv * lnk_g[t] + lnk_b[t];
        }
        __syncthreads();
        if (t < 128) {
            float aq = 0.f, ak = 0.f, av = 0.f;
            for (int e = 0; e < 128; ++e) {
                aq += s_qn[e] * Wq[e * 128 + t];
                ak += s_kn[e] * Wk[e * 128 + t];
                av += s_kn[e] * Wv[e * 128 + t];
            }
            s_q[t] = aq; s_kg[t] = ak;
            ws_q[t] = aq; ws_vg[t] = av;
        }
        __syncthreads();
        if (t < 8) {
            float acc = 0.f;
            for (int d = 0; d < 16; ++d) acc += s_q[t * 16 + d] * s_kg[t * 16 + d];
            float kb0 = kb2[t];
            for (int j = 0; j < 32; ++j) kb0 += fmaxf(kb1[j], 0.f) * kW2[j * 8 + t];
            ws_d0[t] = acc * 0.25f + kb0;
        }
    } else {
        __shared__ float s_red[4][4];
        int pb = blk - 53;                 // 0..31
        const float4* xp = (const float4*)x + pb * 1024;
        float mn0 = 1e30f, mx0 = -1e30f, mn1 = 1e30f, mx1 = -1e30f;
        #pragma unroll
        for (int it = 0; it < 4; ++it) {
            float4 v = xp[it * 256 + t];    // two points: (x,y),(z,w)
            mn0 = fminf(mn0, fminf(v.x, v.z)); mx0 = fmaxf(mx0, fmaxf(v.x, v.z));
            mn1 = fminf(mn1, fminf(v.y, v.w)); mx1 = fmaxf(mx1, fmaxf(v.y, v.w));
        }
        #pragma unroll
        for (int m = 32; m > 0; m >>= 1) {
            mn0 = fminf(mn0, __shfl_xor(mn0, m)); mx0 = fmaxf(mx0, __shfl_xor(mx0, m));
            mn1 = fminf(mn1, __shfl_xor(mn1, m)); mx1 = fmaxf(mx1, __shfl_xor(mx1, m));
        }
        int w = t >> 6;
        if ((t & 63) == 0) {
            s_red[w][0] = mn0; s_red[w][1] = mn1; s_red[w][2] = mx0; s_red[w][3] = mx1;
        }
        __syncthreads();
        if (t == 0) {
            float a0 = fminf(fminf(s_red[0][0], s_red[1][0]), fminf(s_red[2][0], s_red[3][0]));
            float a1 = fminf(fminf(s_red[0][1], s_red[1][1]), fminf(s_red[2][1], s_red[3][1]));
            float b0 = fmaxf(fmaxf(s_red[0][2], s_red[1][2]), fmaxf(s_red[2][2], s_red[3][2]));
            float b1 = fmaxf(fmaxf(s_red[0][3], s_red[1][3]), fmaxf(s_red[2][3], s_red[3][3]));
            part[pb] = make_float4(a0, a1, b0, b1);
        }
    }
}

// ---------------- K2: cell assignment + unordered binning (+ mm publish) ----------------
__global__ __launch_bounds__(256) void k_bin(const float* __restrict__ x,
        const float4* __restrict__ part, float* __restrict__ mm,
        int* __restrict__ cell, int* __restrict__ cnt, int* __restrict__ ptIdx) {
    int t = threadIdx.x;
    int l = t & 63;
    float mn0 = 1e30f, mn1 = 1e30f, mx0 = -1e30f, mx1 = -1e30f;
    if (l < 32) { float4 p = part[l]; mn0 = p.x; mn1 = p.y; mx0 = p.z; mx1 = p.w; }
    #pragma unroll
    for (int m = 32; m > 0; m >>= 1) {
        mn0 = fminf(mn0, __shfl_xor(mn0, m)); mx0 = fmaxf(mx0, __shfl_xor(mx0, m));
        mn1 = fminf(mn1, __shfl_xor(mn1, m)); mx1 = fmaxf(mx1, __shfl_xor(mx1, m));
    }
    if (blockIdx.x == 0 && t == 0) {
        mm[0] = mn0; mm[1] = mn1; mm[2] = mx0; mm[3] = mx1;
    }
    int i = blockIdx.x * 256 + t;  // 65536
    float st0 = (mx0 - mn0) / 31.0f, st1 = (mx1 - mn1) / 31.0f;  // matches jnp exactly
    float2 xv = ((const float2*)x)[i];
    int i0 = (int)rintf((xv.x - mn0) / st0); i0 = min(max(i0, 0), 31);
    int i1 = (int)rintf((xv.y - mn1) / st1); i1 = min(max(i1, 0), 31);
    int c = i0 * 32 + i1;
    cell[i] = c;
    int bb = i >> 13;
    int slot = atomicAdd(&cnt[bb * NM + c], 1);
    if (slot < NP) ptIdx[(bb * NM + c) * NP + slot] = i & (NN - 1);
}

// ---------------- K6: LN(z) + K/V projection; W-frags in regs, LDS-staged coalesced stores
// + overflow fixup merged (blocks >= 1024)
__global__ __launch_bounds__(256) void k_kvfix(const float* __restrict__ z,
        const float* __restrict__ lnk_g, const float* __restrict__ lnk_b,
        const unsigned short* __restrict__ WkvT, unsigned short* __restrict__ kv,
        const int* __restrict__ cell, int* __restrict__ cnt, int* __restrict__ ptIdx) {
    int t = threadIdx.x;
    if (blockIdx.x >= 1024) {
        int wave = (blockIdx.x - 1024) * 4 + (t >> 6);   // 0..511
        int lane = t & 63;
        int wbase = wave * 16;
        int cval = (lane < 16) ? cnt[wbase + lane] : 0;
        unsigned long long ovf = __ballot(cval > NP);
        while (ovf) {
            int s = __ffsll((long long)ovf) - 1;
            ovf &= ovf - 1;
            int wid = wbase + s;
            int b = wid >> 10, mycell = wid & 1023;
            const int* cb = cell + b * NN;
            int run = 0;
            for (int ch = 0; ch < NN / 64 && run < NP; ++ch) {
                int n = ch * 64 + lane;
                bool match = (cb[n] == mycell);
                unsigned long long mask = __ballot(match);
                if (match) {
                    int rank = run + __popcll(mask & ((1ull << lane) - 1ull));
                    if (rank < NP) ptIdx[wid * NP + rank] = n;
                }
                run += __popcll(mask);
            }
            if (lane == 0) cnt[wid] = NP;
        }
        return;
    }
    // ---- kv path: 64 tokens per block ----
    __shared__ unsigned short s_zn[64][136];
    __shared__ unsigned short s_stage[4][16][68];   // per-wave 16-token x 64-feature staging
    int w = t >> 6, lane = t & 63;
    long base = (long)blockIdx.x * 64;
    int sub = lane >> 5;
    int lq = lane & 31;
    int mrow = lane & 15, quad = lane >> 4;

    // Prefetch this wave's W-fragments (64 VGPRs, once per block).
    bf16x8_t afrag[4][4];
    #pragma unroll
    for (int j = 0; j < 4; ++j) {
        int ft = w * 4 + j;
        const unsigned short* ap = WkvT + (ft * 16 + mrow) * 128 + quad * 8;
        #pragma unroll
        for (int kc = 0; kc < 4; ++kc)
            afrag[j][kc] = *(const bf16x8_t*)(ap + kc * 32);
    }

    // LN: 2 rows/iter, 32 lanes/row, hoisted loads
    float4 g4 = ((const float4*)lnk_g)[lq];
    float4 b4 = ((const float4*)lnk_b)[lq];
    float4 v[8];
    #pragma unroll
    for (int i = 0; i < 8; ++i) {
        int pl = w * 16 + i * 2 + sub;
        v[i] = ((const float4*)z)[(base + pl) * 32 + lq];
    }
    #pragma unroll
    for (int i = 0; i < 8; ++i) {
        int pl = w * 16 + i * 2 + sub;
        float sum = v[i].x + v[i].y + v[i].z + v[i].w;
        float ssq = v[i].x * v[i].x + v[i].y * v[i].y + v[i].z * v[i].z + v[i].w * v[i].w;
        #pragma unroll
        for (int m = 1; m < 32; m <<= 1) {
            sum += __shfl_xor(sum, m);
            ssq += __shfl_xor(ssq, m);
        }
        float mu = sum * (1.0f / 128.0f);
        float var = fmaxf(ssq * (1.0f / 128.0f) - mu * mu, 0.0f);
        float rstd = rsqrtf(var + 1e-5f);
        float n0 = (v[i].x - mu) * rstd * g4.x + b4.x;
        float n1 = (v[i].y - mu) * rstd * g4.y + b4.y;
        float n2 = (v[i].z - mu) * rstd * g4.z + b4.z;
        float n3 = (v[i].w - mu) * rstd * g4.w + b4.w;
        unsigned d0 = (unsigned)f2bf(n0) | ((unsigned)f2bf(n1) << 16);
        unsigned d1 = (unsigned)f2bf(n2) | ((unsigned)f2bf(n3) << 16);
        *(uint2*)&s_zn[pl][lq * 4] = make_uint2(d0, d1);
    }
    __syncthreads();   // waves now consume all rows

    // 4 token-tiles; wave covers its 64 features for all 64 tokens.
    // Store path: stage result tile in per-wave LDS, then 2 dwordx4 bursts
    // (8 lanes cover one token's contiguous 128B chunk -> 8 segments/inst
    //  instead of 16x32B segments per uint2 direct store).
    #pragma unroll
    for (int tau = 0; tau < 4; ++tau) {
        bf16x8_t bfrag[4];
        #pragma unroll
        for (int kc = 0; kc < 4; ++kc)
            bfrag[kc] = *(const bf16x8_t*)&s_zn[tau * 16 + mrow][kc * 32 + quad * 8];
        #pragma unroll
        for (int j = 0; j < 4; ++j) {
            f32x4_t acc = {0.f, 0.f, 0.f, 0.f};
            #pragma unroll
            for (int kc = 0; kc < 4; ++kc)
                acc = __builtin_amdgcn_mfma_f32_16x16x32_bf16(afrag[j][kc], bfrag[kc], acc, 0, 0, 0);
            unsigned d0 = (unsigned)f2bf(acc[0]) | ((unsigned)f2bf(acc[1]) << 16);
            unsigned d1 = (unsigned)f2bf(acc[2]) | ((unsigned)f2bf(acc[3]) << 16);
            // token = mrow (D col), local feature = j*16 + quad*4
            *(uint2*)&s_stage[w][mrow][j * 16 + quad * 4] = make_uint2(d0, d1);
        }
        // burst out: lane l -> token (l>>3) [+8], bytes (l&7)*16 of this wave's 128B chunk
        int tok = lane >> 3, u = lane & 7;
        long tk0 = base + tau * 16;
        uint4 ra = *(const uint4*)&s_stage[w][tok][u * 8];
        *(uint4*)(kv + (tk0 + tok) * 256 + w * 64 + u * 8) = ra;
        uint4 rb = *(const uint4*)&s_stage[w][tok + 8][u * 8];
        *(uint4*)(kv + (tk0 + tok + 8) * 256 + w * 64 + u * 8) = rb;
    }
}

// ---------------- K7: per-cell attention — wave-per-token, no LDS, no barriers ----------------
__global__ __launch_bounds__(256) void k_attn(const float* __restrict__ x,
        const int* __restrict__ cnt, const int* __restrict__ ptIdx,
        const float* __restrict__ mm, const unsigned short* __restrict__ kv,
        const float* __restrict__ ws_q, const float* __restrict__ ws_vg,
        const float* __restrict__ ws_d0,
        const float* __restrict__ kW1, const float* __restrict__ kb1,
        const float* __restrict__ kW2, const float* __restrict__ kb2,
        unsigned short* __restrict__ outA, float* __restrict__ xout) {
    int t = threadIdx.x;
    int l = t & 63;
    int bm = blockIdx.x * 4 + (t >> 6);   // one wave per (b,cell) token
    int b = bm >> 10;
    int h = l >> 3, jp = l & 7;

    float mn0 = mm[0], mn1 = mm[1], mx0 = mm[2], mx1 = mm[3];
    int i0 = (bm & 1023) >> 5, i1 = bm & 31;
    float st0 = (mx0 - mn0) / 31.0f, st1 = (mx1 - mn1) / 31.0f;
    float xg0 = (i0 == 31) ? mx0 : mn0 + i0 * st0;
    float xg1 = (i1 == 31) ? mx1 : mn1 + i1 * st1;
    int c = min(cnt[bm], NP);

    float q0 = ws_q[2 * l] * 0.25f, q1 = ws_q[2 * l + 1] * 0.25f;
    float vg0 = ws_vg[2 * l], vg1 = ws_vg[2 * l + 1];
    float ag = ws_d0[h];
    float kb2h = kb2[h];
    float w1a[4], w1b[4], b1v[4], w2v[4];
    #pragma unroll
    for (int m = 0; m < 4; ++m) {
        int j = jp + 8 * m;
        w1a[m] = kW1[j]; w1b[m] = kW1[32 + j]; b1v[m] = kb1[j]; w2v[m] = kW2[j * 8 + h];
    }

    int idxreg = 0; float x0r = 0.f, x1r = 0.f;
    if (l < c) {
        idxreg = ptIdx[bm * NP + l];
        float2 xv = ((const float2*)x)[(size_t)b * NN + idxreg];
        x0r = xv.x; x1r = xv.y;
    }

    unsigned vreg[NP];
    float areg[4];
    #pragma unroll
    for (int k = 0; k < NP; ++k) vreg[k] = 0u;
    areg[0] = areg[1] = areg[2] = areg[3] = -1e30f;

    #pragma unroll
    for (int key = 0; key < NP; ++key) {
        if (key < c) {
            int idxk = __shfl(idxreg, key);
            const unsigned* rowp = (const unsigned*)kv + ((size_t)(b * NN + idxk) << 7);
            unsigned kw = rowp[l];
            vreg[key] = rowp[64 + l];
            float d0 = __shfl(x0r, key) - xg0;
            float d1 = __shfl(x1r, key) - xg1;
            float part = q0 * bflo(kw) + q1 * bfhi(kw);
            #pragma unroll
            for (int m = 0; m < 4; ++m) {
                float hj = fmaf(d0, w1a[m], fmaf(d1, w1b[m], b1v[m]));
                hj = fmaxf(hj, 0.f);
                part = fmaf(hj, w2v[m], part);
            }
            part += __shfl_xor(part, 1);
            part += __shfl_xor(part, 2);
            part += __shfl_xor(part, 4);
            float score = part + kb2h;
            if (jp == (key & 7)) areg[key >> 3] = score;
        }
    }

    float mx = fmaxf(fmaxf(areg[0], areg[1]), fmaxf(areg[2], areg[3]));
    mx = fmaxf(mx, ag);
    mx = fmaxf(mx, __shfl_xor(mx, 1));
    mx = fmaxf(mx, __shfl_xor(mx, 2));
    mx = fmaxf(mx, __shfl_xor(mx, 4));
    float e0 = __expf(areg[0] - mx), e1 = __expf(areg[1] - mx);
    float e2 = __expf(areg[2] - mx), e3 = __expf(areg[3] - mx);
    float eg = __expf(ag - mx);
    float s = e0 + e1 + e2 + e3;
    s += __shfl_xor(s, 1);
    s += __shfl_xor(s, 2);
    s += __shfl_xor(s, 4);
    s += eg;
    float inv = 1.0f / s;

    float accA = eg * inv * vg0, accB = eg * inv * vg1;
    #pragma unroll
    for (int key = 0; key < NP; ++key) {
        if (key < c) {
            int src = (l & 56) | (key & 7);
            float em = (key >> 3) == 0 ? e0 : (key >> 3) == 1 ? e1 : (key >> 3) == 2 ? e2 : e3;
            float a = __shfl(em, src) * inv;
            unsigned vw = vreg[key];
            accA = fmaf(a, bflo(vw), accA);
            accB = fmaf(a, bfhi(vw), accB);
        }
    }
    unsigned ow = ((unsigned)f2bf(accB) << 16) | (unsigned)f2bf(accA);
    ((unsigned*)outA)[(size_t)bm * 64 + l] = ow;

    float s0 = e0 * inv, s1 = e1 * inv, s2 = e2 * inv, s3 = e3 * inv, sg = eg * inv;
    #pragma unroll
    for (int m = 8; m <= 32; m <<= 1) {
        s0 += __shfl_xor(s0, m); s1 += __shfl_xor(s1, m);
        s2 += __shfl_xor(s2, m); s3 += __shfl_xor(s3, m);
        sg += __shfl_xor(sg, m);
    }
    float px0 = 0.f, px1 = 0.f;
    {
        float xx0, xx1;
        xx0 = __shfl(x0r, jp);      xx1 = __shfl(x1r, jp);
        px0 = fmaf(s0, xx0, px0);   px1 = fmaf(s0, xx1, px1);
        xx0 = __shfl(x0r, jp + 8);  xx1 = __shfl(x1r, jp + 8);
        px0 = fmaf(s1, xx0, px0);   px1 = fmaf(s1, xx1, px1);
        xx0 = __shfl(x0r, jp + 16); xx1 = __shfl(x1r, jp + 16);
        px0 = fmaf(s2, xx0, px0);   px1 = fmaf(s2, xx1, px1);
        xx0 = __shfl(x0r, jp + 24); xx1 = __shfl(x1r, jp + 24);
        px0 = fmaf(s3, xx0, px0);   px1 = fmaf(s3, xx1, px1);
    }
    px0 += __shfl_xor(px0, 1); px1 += __shfl_xor(px1, 1);
    px0 += __shfl_xor(px0, 2); px1 += __shfl_xor(px1, 2);
    px0 += __shfl_xor(px0, 4); px1 += __shfl_xor(px1, 4);
    if (l == 0) {
        xout[bm * 2]     = (px0 + sg * xg0) * 0.125f;
        xout[bm * 2 + 1] = (px1 + sg * xg1) * 0.125f;
    }
}

// ---------------- K8: z_new = zq + out@Wo + bo; + FFN(LN2) ----------------
__global__ __launch_bounds__(256) void k_ffn(const unsigned short* __restrict__ outA,
        const float* __restrict__ latent, const float* __restrict__ bo,
        const float* __restrict__ ln2_g, const float* __restrict__ ln2_b,
        const float* __restrict__ fb1, const float* __restrict__ fb2,
        const unsigned short* __restrict__ WoT, const unsigned short* __restrict__ fW1T,
        const unsigned short* __restrict__ fW2T, float* __restrict__ zout) {
    __shared__ unsigned short s_a[32][136];
    __shared__ unsigned short s_a2[32][136];
    __shared__ float s_z[32][128];
    __shared__ float s_lat[128], s_g2[128], s_b2[128], s_fb1v[128], s_fb2v[128];
    int t = threadIdx.x;
    long base = (long)blockIdx.x * 32;
    if (t < 128) {
        s_lat[t] = latent[t] + bo[t];
        s_g2[t] = ln2_g[t]; s_b2[t] = ln2_b[t];
        s_fb1v[t] = fb1[t]; s_fb2v[t] = fb2[t];
    }
    {
        const uint4* src4 = (const uint4*)((const uint32_t*)outA + base * 64);
        for (int i = t; i < 512; i += 256) {
            int row = i >> 4, off = (i & 15) * 8;
            *(uint4*)&s_a[row][off] = src4[i];
        }
    }
    __syncthreads();
    int w = t >> 6, lane = t & 63;
    int mrow = lane & 15, quad = lane >> 4;
    int rt = w >> 1;
    int ct0 = (w & 1) * 4;
    { // GEMM1: out @ Wo  (+ latent + bo)
        bf16x8_t a[4];
        for (int kc = 0; kc < 4; ++kc)
            a[kc] = *(const bf16x8_t*)&s_a[rt * 16 + mrow][kc * 32 + quad * 8];
        for (int cc = 0; cc < 4; ++cc) {
            int ct = ct0 + cc;
            f32x4_t acc = {0.f, 0.f, 0.f, 0.f};
            const unsigned short* bp = WoT + (ct * 16 + mrow) * 128 + quad * 8;
            for (int kc = 0; kc < 4; ++kc)
                acc = __builtin_amdgcn_mfma_f32_16x16x32_bf16(a[kc], *(const bf16x8_t*)(bp + kc * 32), acc, 0, 0, 0);
            for (int r = 0; r < 4; ++r) {
                int row = rt * 16 + quad * 4 + r, f = ct * 16 + mrow;
                s_z[row][f] = acc[r] + s_lat[f];
            }
        }
    }
    __syncthreads();
    for (int i = 0; i < 8; ++i) {   // LN2 per row
        int row = w * 8 + i;
        float v0 = s_z[row][lane], v1 = s_z[row][lane + 64];
        float s = v0 + v1;
        for (int m = 32; m > 0; m >>= 1) s += __shfl_xor(s, m);
        float mu = s * (1.0f / 128.0f);
        float d0 = v0 - mu, d1 = v1 - mu;
        float q = d0 * d0 + d1 * d1;
        for (int m = 32; m > 0; m >>= 1) q += __shfl_xor(q, m);
        float rstd = rsqrtf(q * (1.0f / 128.0f) + 1e-5f);
        s_a2[row][lane]      = f2bf(d0 * rstd * s_g2[lane] + s_b2[lane]);
        s_a2[row][lane + 64] = f2bf(d1 * rstd * s_g2[lane + 64] + s_b2[lane + 64]);
    }
    __syncthreads();
    { // GEMM2: relu(LN2 @ fW1 + fb1) -> s_a (reuse)
        bf16x8_t a[4];
        for (int kc = 0; kc < 4; ++kc)
            a[kc] = *(const bf16x8_t*)&s_a2[rt * 16 + mrow][kc * 32 + quad * 8];
        for (int cc = 0; cc < 4; ++cc) {
            int ct = ct0 + cc;
            f32x4_t acc = {0.f, 0.f, 0.f, 0.f};
            const unsigned short* bp = fW1T + (ct * 16 + mrow) * 128 + quad * 8;
            for (int kc = 0; kc < 4; ++kc)
                acc = __builtin_amdgcn_mfma_f32_16x16x32_bf16(a[kc], *(const bf16x8_t*)(bp + kc * 32), acc, 0, 0, 0);
            for (int r = 0; r < 4; ++r) {
                int row = rt * 16 + quad * 4 + r, f = ct * 16 + mrow;
                s_a[row][f] = f2bf(fmaxf(acc[r] + s_fb1v[f], 0.f));
            }
        }
    }
    __syncthreads();
    { // GEMM3: z + h1 @ fW2 + fb2 -> d_out
        bf16x8_t a[4];
        for (int kc = 0; kc < 4; ++kc)
            a[kc] = *(const bf16x8_t*)&s_a[rt * 16 + mrow][kc * 32 + quad * 8];
        for (int cc = 0; cc < 4; ++cc) {
            int ct = ct0 + cc;
            f32x4_t acc = {0.f, 0.f, 0.f, 0.f};
            const unsigned short* bp = fW2T + (ct * 16 + mrow) * 128 + quad * 8;
            for (int kc = 0; kc < 4; ++kc)
                acc = __builtin_amdgcn_mfma_f32_16x16x32_bf16(a[kc], *(const bf16x8_t*)(bp + kc * 32), acc, 0, 0, 0);
            for (int r = 0; r < 4; ++r) {
                int row = rt * 16 + quad * 4 + r, f = ct * 16 + mrow;
                zout[(base + row) * 128 + f] = s_z[row][f] + acc[r] + s_fb2v[f];
            }
        }
    }
}

extern "C" void kernel_launch(void* const* d_in, const int* in_sizes, int n_in,
                              void* d_out, int out_size, void* d_ws, size_t ws_size,
                              hipStream_t stream) {
    const float* x     = (const float*)d_in[0];
    const float* z     = (const float*)d_in[1];
    const float* latent= (const float*)d_in[6];
    const float* Wq    = (const float*)d_in[7];
    const float* Wk    = (const float*)d_in[8];
    const float* Wv    = (const float*)d_in[9];
    const float* Wo    = (const float*)d_in[10];
    const float* bo    = (const float*)d_in[11];
    const float* kW1   = (const float*)d_in[12];
    const float* kb1   = (const float*)d_in[13];
    const float* kW2   = (const float*)d_in[14];
    const float* kb2   = (const float*)d_in[15];
    const float* lnq_g = (const float*)d_in[16];
    const float* lnq_b = (const float*)d_in[17];
    const float* lnk_g = (const float*)d_in[18];
    const float* lnk_b = (const float*)d_in[19];
    const float* ln2_g = (const float*)d_in[20];
    const float* ln2_b = (const float*)d_in[21];
    const float* fW1   = (const float*)d_in[22];
    const float* fb1   = (const float*)d_in[23];
    const float* fW2   = (const float*)d_in[24];
    const float* fb2   = (const float*)d_in[25];

    uint8_t* ws = (uint8_t*)d_ws;
    float* mm     = (float*)(ws + WS_MM);
    float* ws_d0  = (float*)(ws + WS_D0);
    float* ws_q   = (float*)(ws + WS_Q);
    float* ws_vg  = (float*)(ws + WS_VG);
    float4* part  = (float4*)(ws + WS_PART);
    int* cnt      = (int*)(ws + WS_CNT);
    int* cell     = (int*)(ws + WS_CELL);
    int* ptIdx    = (int*)(ws + WS_PIDX);
    unsigned short* WkvT = (unsigned short*)(ws + WS_WKVT);
    unsigned short* WoT  = (unsigned short*)(ws + WS_WOT);
    unsigned short* fW1T = (unsigned short*)(ws + WS_FW1T);
    unsigned short* fW2T = (unsigned short*)(ws + WS_FW2T);
    unsigned short* outA = (unsigned short*)(ws + WS_OUTA);
    unsigned short* kv   = (unsigned short*)(ws + WS_KV);

    float* xout = (float*)d_out;            // [B,32,32,2]  = 16384
    float* zout = (float*)d_out + 16384;    // [B,32,32,128]

    k_setup <<<85,   256, 0, stream>>>(x, Wk, Wv, Wo, fW1, fW2, latent, Wq,
                                       lnq_g, lnq_b, lnk_g, lnk_b, kb1, kW2, kb2,
                                       cnt, WkvT, WoT, fW1T, fW2T, ws_q, ws_vg, ws_d0, part);
    k_bin   <<<256,  256, 0, stream>>>(x, part, mm, cell, cnt, ptIdx);
    k_kvfix <<<1152, 256, 0, stream>>>(z, lnk_g, lnk_b, WkvT, kv, cell, cnt, ptIdx);
    k_attn  <<<2048, 256, 0, stream>>>(x, cnt, ptIdx, mm, kv, ws_q, ws_vg, ws_d0,
                                       kW1, kb1, kW2, kb2, outA, xout);
    k_ffn   <<<256,  256, 0, stream>>>(outA, latent, bo, ln2_g, ln2_b, fb1, fb2,
                                       WoT, fW1T, fW2T, zout);
}